// Round 6
// baseline (520.948 us; speedup 1.0000x reference)
//
#include <hip/hip_runtime.h>
#include <math.h>

#define HW 21025        // 145*145
#define Hdim 145
#define Wdim 145
#define NBANDS 200
#define CONVH 147
#define CONVHW 21609    // 147*147
#define QC 64
#define NCH 329         // ceil(21025/64)
#define DTP 21056       // padded L for transposed dt
#define SP 72           // short stride for [.][64-k] MFMA tiles

typedef __attribute__((ext_vector_type(4))) float fv4;
typedef __attribute__((ext_vector_type(8))) short short8;

// ---------------- workspace layout (float offsets) ----------------
#define OFF_XN   ((size_t)0)           // 4,205,000  xn; later pr, cls0
#define OFF_F1   ((size_t)4205000)     // 5,382,400  f1; later y (L x 256)
#define OFF_COMB ((size_t)9587400)     // 4,036,800  comb L x 192; later mo + cls2
#define OFF_P    ((size_t)13624200)    // 2,691,200  p; later cls1
#define OFF_ZX   ((size_t)16315400)    // 16,231,300 zxbcdt L x 772
#define OFF_XBC  ((size_t)32546700)    // 10,764,800 c1h+c2h first, then xbc L x 512
#define OFF_S    ((size_t)43311500)    // 10,780,672 S^T
#define OFF_DT   ((size_t)54092172)    // 84,224 (dt transposed [4][DTP])
#define OFF_CT   ((size_t)54176396)    // 1,316
#define OFF_W    ((size_t)54177712)    // 82,944: packed conv weights (bf16 hi/lo)

__device__ __forceinline__ float gelu_f(float x){
    return 0.5f * x * (1.0f + erff(x * 0.70710678118654752440f));
}
__device__ __forceinline__ float silu_f(float x){
    return x / (1.0f + expf(-x));
}

__device__ __forceinline__ void bf16_split(float x, unsigned short& hs, unsigned short& ls){
    unsigned u = __float_as_uint(x);
    hs = (unsigned short)(u >> 16);
    float hif = __uint_as_float(u & 0xFFFF0000u);
    float lof = x - hif;
    ls = (unsigned short)(__float_as_uint(lof) >> 16);
}
__device__ __forceinline__ unsigned pack2(unsigned short a, unsigned short b){
    return (unsigned)a | ((unsigned)b << 16);
}
// load 8 consecutive f32 from global, split into hi/lo short8
__device__ __forceinline__ void split8g(const float* p, short8& h8, short8& l8){
    fv4 v0 = *reinterpret_cast<const fv4*>(p);
    fv4 v1 = *reinterpret_cast<const fv4*>(p + 4);
    unsigned short hs, ls;
    #pragma unroll
    for (int j = 0; j < 4; j++){
        bf16_split(v0[j], hs, ls); h8[j] = (short)hs; l8[j] = (short)ls;
        bf16_split(v1[j], hs, ls); h8[4 + j] = (short)hs; l8[4 + j] = (short)ls;
    }
}

// ---------------- LayerNorm (+ optional GELU) ----------------
template<int ACT>
__global__ void ln_kernel(const float* __restrict__ in, const float* __restrict__ g,
                          const float* __restrict__ b, float* __restrict__ out, int D){
    int row = blockIdx.x, tid = threadIdx.x;
    const float* r = in + (size_t)row * D;
    float s = 0.f, s2 = 0.f;
    for (int i = tid; i < D; i += 256){ float v = r[i]; s += v; s2 += v*v; }
    __shared__ float r1[4], r2[4];
    #pragma unroll
    for (int o = 32; o > 0; o >>= 1){ s += __shfl_down(s, o); s2 += __shfl_down(s2, o); }
    if ((tid & 63) == 0){ r1[tid >> 6] = s; r2[tid >> 6] = s2; }
    __syncthreads();
    float S = r1[0] + r1[1] + r1[2] + r1[3];
    float S2 = r2[0] + r2[1] + r2[2] + r2[3];
    float mean = S / (float)D;
    float var = S2 / (float)D - mean * mean;
    float rs = rsqrtf(fmaxf(var, 0.f) + 1e-5f);
    float* o_ = out + (size_t)row * D;
    for (int i = tid; i < D; i += 256){
        float v = (r[i] - mean) * rs * g[i] + b[i];
        if (ACT == 1) v = gelu_f(v);
        o_[i] = v;
    }
}

// ---------------- split-bf16 MFMA GEMM: C = act(A@B + bias) ----------------
template<int ACT>
__global__ __launch_bounds__(256) void gemm_mfma(const float* __restrict__ A, int lda,
                                                 const float* __restrict__ B,
                                                 const float* __restrict__ bias,
                                                 float* __restrict__ C, int ldc,
                                                 int M, int N, int K){
    const int SA = 40;
    __shared__ __align__(16) unsigned short Ah[128 * SA], Al[128 * SA];
    __shared__ __align__(16) unsigned short Bh[64 * SA],  Bl[64 * SA];
    int tid = threadIdx.x;
    int lane = tid & 63, wid = tid >> 6;
    int wy = wid >> 1, wx = wid & 1;
    int bm = blockIdx.y * 128, bn = blockIdx.x * 64;
    int l15 = lane & 15, g = lane >> 4;

    fv4 acc[4][2];
    #pragma unroll
    for (int i = 0; i < 4; i++)
        #pragma unroll
        for (int j = 0; j < 2; j++) acc[i][j] = (fv4){0.f,0.f,0.f,0.f};

    int am = tid >> 1;
    int aq = (tid & 1) * 4;
    bool arow_ok = (bm + am) < M;
    int bn_t = tid & 63;
    int bk8 = (tid >> 6) * 8;
    bool bcol_ok = (bn + bn_t) < N;

    int nK = (K + 31) / 32;
    for (int ks = 0; ks < nK; ks++){
        int k0 = ks * 32;
        const float* Ap = A + (size_t)(bm + am) * lda + k0;
        #pragma unroll
        for (int f = 0; f < 4; f++){
            int kq = aq + f;
            fv4 v = (fv4){0.f,0.f,0.f,0.f};
            if (arow_ok && (k0 + kq * 4 + 4) <= K)
                v = *reinterpret_cast<const fv4*>(Ap + kq * 4);
            unsigned short hs[4], ls[4];
            #pragma unroll
            for (int j = 0; j < 4; j++) bf16_split(v[j], hs[j], ls[j]);
            unsigned off = am * SA + kq * 4;
            *reinterpret_cast<uint2*>(&Ah[off]) = make_uint2(pack2(hs[0],hs[1]), pack2(hs[2],hs[3]));
            *reinterpret_cast<uint2*>(&Al[off]) = make_uint2(pack2(ls[0],ls[1]), pack2(ls[2],ls[3]));
        }
        {
            unsigned short hs[8], ls[8];
            #pragma unroll
            for (int j = 0; j < 8; j++){
                int kk = k0 + bk8 + j;
                float v = (bcol_ok && kk < K) ? B[(size_t)kk * N + bn + bn_t] : 0.f;
                bf16_split(v, hs[j], ls[j]);
            }
            unsigned off = bn_t * SA + bk8;
            *reinterpret_cast<uint4*>(&Bh[off]) = make_uint4(pack2(hs[0],hs[1]), pack2(hs[2],hs[3]),
                                                             pack2(hs[4],hs[5]), pack2(hs[6],hs[7]));
            *reinterpret_cast<uint4*>(&Bl[off]) = make_uint4(pack2(ls[0],ls[1]), pack2(ls[2],ls[3]),
                                                             pack2(ls[4],ls[5]), pack2(ls[6],ls[7]));
        }
        __syncthreads();
        short8 afh[4], afl[4], bfh[2], bfl[2];
        #pragma unroll
        for (int mi = 0; mi < 4; mi++){
            unsigned off = (wy * 64 + mi * 16 + l15) * SA + g * 8;
            afh[mi] = *reinterpret_cast<const short8*>(&Ah[off]);
            afl[mi] = *reinterpret_cast<const short8*>(&Al[off]);
        }
        #pragma unroll
        for (int ni = 0; ni < 2; ni++){
            unsigned off = (wx * 32 + ni * 16 + l15) * SA + g * 8;
            bfh[ni] = *reinterpret_cast<const short8*>(&Bh[off]);
            bfl[ni] = *reinterpret_cast<const short8*>(&Bl[off]);
        }
        #pragma unroll
        for (int mi = 0; mi < 4; mi++)
            #pragma unroll
            for (int ni = 0; ni < 2; ni++){
                acc[mi][ni] = __builtin_amdgcn_mfma_f32_16x16x32_bf16(afh[mi], bfh[ni], acc[mi][ni], 0, 0, 0);
                acc[mi][ni] = __builtin_amdgcn_mfma_f32_16x16x32_bf16(afh[mi], bfl[ni], acc[mi][ni], 0, 0, 0);
                acc[mi][ni] = __builtin_amdgcn_mfma_f32_16x16x32_bf16(afl[mi], bfh[ni], acc[mi][ni], 0, 0, 0);
            }
        __syncthreads();
    }
    #pragma unroll
    for (int mi = 0; mi < 4; mi++){
        #pragma unroll
        for (int ni = 0; ni < 2; ni++){
            int cc = bn + wx * 32 + ni * 16 + l15;
            if (cc >= N) continue;
            float bv = bias ? bias[cc] : 0.f;
            #pragma unroll
            for (int j = 0; j < 4; j++){
                int rr = bm + wy * 64 + mi * 16 + g * 4 + j;
                if (rr >= M) continue;
                float v = acc[mi][ni][j] + bv;
                if (ACT == 1) v = gelu_f(v);
                C[(size_t)rr * ldc + cc] = v;
            }
        }
    }
}

// ---------------- conv weight prepack: [oc][ch*288 + tap*32 + ci] bf16 hi/lo -------
template<int IC, int OC, int NCHUNK>
__global__ void prep_w(const float* __restrict__ w, unsigned short* __restrict__ Wh,
                       unsigned short* __restrict__ Wl){
    const int KP = NCHUNK * 288;
    int idx = blockIdx.x * 256 + threadIdx.x;
    if (idx >= OC * KP) return;
    int o = idx / KP, k = idx % KP;
    int ch = k / 288, rest = k % 288, t = rest / 32, c = rest & 31;
    int ci = ch * 32 + c;
    float v = (ci < IC) ? w[((size_t)o * IC + ci) * 9 + t] : 0.f;
    unsigned short hs, ls;
    bf16_split(v, hs, ls);
    Wh[idx] = hs; Wl[idx] = ls;
}

// ---------------- MFMA direct conv 3x3 (implicit im2col in LDS) -------------------
template<int IC, int OC, int PAD, int NCHUNK, int NFRAG>
__global__ __launch_bounds__(256) void conv_mfma(const float* __restrict__ in,
                                                 int inH, int inW,
                                                 const unsigned short* __restrict__ Wh,
                                                 const unsigned short* __restrict__ Wl,
                                                 const float* __restrict__ bias,
                                                 float* __restrict__ out){
    const int KP = NCHUNK * 288;
    const int CST = 40;
    __shared__ __align__(16) unsigned short Xh[3 * 68 * CST], Xl[3 * 68 * CST];
    int y = blockIdx.y;
    int x0 = blockIdx.x * 64;
    int tid = threadIdx.x;
    int lane = tid & 63, wid = tid >> 6;
    int wy = wid >> 1, wx = wid & 1;
    int l15 = lane & 15, g = lane >> 4;

    fv4 acc[2][NFRAG];
    #pragma unroll
    for (int mi = 0; mi < 2; mi++)
        #pragma unroll
        for (int ni = 0; ni < NFRAG; ni++) acc[mi][ni] = (fv4){0.f,0.f,0.f,0.f};

    for (int ch = 0; ch < NCHUNK; ch++){
        int ci0 = ch * 32;
        if (ch > 0) __syncthreads();
        for (int e = tid; e < 3 * 68 * 8; e += 256){
            int qd = e & 7;
            int c  = (e >> 3) % 68;
            int r  = e / 544;
            int iy = y - PAD + r, ix = x0 - PAD + c;
            fv4 v = (fv4){0.f,0.f,0.f,0.f};
            if ((unsigned)iy < (unsigned)inH && (unsigned)ix < (unsigned)inW &&
                (ci0 + qd * 4 + 4) <= IC)
                v = *reinterpret_cast<const fv4*>(in + ((size_t)iy * inW + ix) * IC + ci0 + qd * 4);
            unsigned short hs[4], ls[4];
            #pragma unroll
            for (int j = 0; j < 4; j++) bf16_split(v[j], hs[j], ls[j]);
            unsigned off = (r * 68 + c) * CST + qd * 4;
            *reinterpret_cast<uint2*>(&Xh[off]) = make_uint2(pack2(hs[0],hs[1]), pack2(hs[2],hs[3]));
            *reinterpret_cast<uint2*>(&Xl[off]) = make_uint2(pack2(ls[0],ls[1]), pack2(ls[2],ls[3]));
        }
        __syncthreads();
        #pragma unroll
        for (int t = 0; t < 9; t++){
            int ky = t / 3, kx = t % 3;
            short8 ah[2], al[2], bh[NFRAG], bl[NFRAG];
            #pragma unroll
            for (int mi = 0; mi < 2; mi++){
                unsigned off = (ky * 68 + wy * 32 + mi * 16 + l15 + kx) * CST + g * 8;
                ah[mi] = *reinterpret_cast<const short8*>(&Xh[off]);
                al[mi] = *reinterpret_cast<const short8*>(&Xl[off]);
            }
            #pragma unroll
            for (int ni = 0; ni < NFRAG; ni++){
                int oc = wx * (16 * NFRAG) + ni * 16 + l15;
                size_t woff = (size_t)oc * KP + ch * 288 + t * 32 + g * 8;
                bh[ni] = *reinterpret_cast<const short8*>(&Wh[woff]);
                bl[ni] = *reinterpret_cast<const short8*>(&Wl[woff]);
            }
            #pragma unroll
            for (int mi = 0; mi < 2; mi++)
                #pragma unroll
                for (int ni = 0; ni < NFRAG; ni++){
                    acc[mi][ni] = __builtin_amdgcn_mfma_f32_16x16x32_bf16(ah[mi], bh[ni], acc[mi][ni], 0, 0, 0);
                    acc[mi][ni] = __builtin_amdgcn_mfma_f32_16x16x32_bf16(ah[mi], bl[ni], acc[mi][ni], 0, 0, 0);
                    acc[mi][ni] = __builtin_amdgcn_mfma_f32_16x16x32_bf16(al[mi], bh[ni], acc[mi][ni], 0, 0, 0);
                }
        }
    }
    #pragma unroll
    for (int mi = 0; mi < 2; mi++)
        #pragma unroll
        for (int ni = 0; ni < NFRAG; ni++){
            int oc = wx * (16 * NFRAG) + ni * 16 + l15;
            float bv = bias[oc];
            #pragma unroll
            for (int j = 0; j < 4; j++){
                int x = x0 + wy * 32 + mi * 16 + g * 4 + j;
                if (x >= CONVH) continue;
                out[((size_t)y * CONVH + x) * OC + oc] = gelu_f(acc[mi][ni][j] + bv);
            }
        }
}

// ---------------- adaptive pool HWC into comb[:,128:] ----------------
__global__ void pool_kernel(const float* __restrict__ c2, float* __restrict__ comb){
    int idx = blockIdx.x * 256 + threadIdx.x;
    if (idx >= HW * 64) return;
    int o = idx & 63;
    int pix = idx >> 6;
    int xo = pix % Wdim, yo = pix / Wdim;
    int ys = yo * CONVH / Hdim, ye = ((yo + 1) * CONVH + Hdim - 1) / Hdim;
    int xs = xo * CONVH / Wdim, xe = ((xo + 1) * CONVH + Wdim - 1) / Wdim;
    float s = 0.f;
    for (int yy = ys; yy < ye; yy++)
        for (int xx = xs; xx < xe; xx++)
            s += c2[((size_t)yy * CONVH + xx) * 64 + o];
    comb[(size_t)pix * 192 + 128 + o] = s / (float)((ye - ys) * (xe - xs));
}

// ---------------- dt = softplus(raw + bias), transposed out [h][t] ----------------
__global__ void dt_kernel(const float* __restrict__ zx, const float* __restrict__ dt_bias,
                          float* __restrict__ dtbT){
    int t = blockIdx.x * 256 + threadIdx.x;
    int h = blockIdx.y;
    if (t >= HW) return;
    float v = zx[(size_t)t * 772 + 768 + h] + dt_bias[h];
    dtbT[h * DTP + t] = (v > 20.f) ? v : log1pf(expf(v));
}

// ---------------- depthwise causal conv1d (width 4) + silu, LDS-tiled ----------------
__global__ __launch_bounds__(256) void conv1d_tiled(const float* __restrict__ zx,
                                                    const float* __restrict__ w,
                                                    const float* __restrict__ b,
                                                    float* __restrict__ xbc){
    __shared__ float xs[67 * 128];
    __shared__ float wc[4 * 128];
    __shared__ float bc[128];
    int t0 = blockIdx.y * 64;
    int c0 = blockIdx.x * 128;
    int tid = threadIdx.x;
    for (int e = tid; e < 67 * 128; e += 256){
        int rr = e >> 7, cc = e & 127;
        int t = t0 - 3 + rr;
        xs[e] = (t >= 0 && t < HW) ? zx[(size_t)t * 772 + 256 + c0 + cc] : 0.f;
    }
    if (tid < 128){
        bc[tid] = b[c0 + tid];
        #pragma unroll
        for (int k = 0; k < 4; k++) wc[k * 128 + tid] = w[(c0 + tid) * 4 + k];
    }
    __syncthreads();
    for (int e = tid; e < 64 * 128; e += 256){
        int tt = e >> 7, cc = e & 127;
        if (t0 + tt >= HW) continue;
        float acc = bc[cc];
        #pragma unroll
        for (int k = 0; k < 4; k++) acc += xs[(tt + k) * 128 + cc] * wc[k * 128 + cc];
        xbc[(size_t)(t0 + tt) * 512 + c0 + cc] = silu_f(acc);
    }
}

// ---------------- SSD phase A (MFMA, head-merged): S^T[p][n] per (c,h) -------------
__global__ __launch_bounds__(256) void ssd_phaseA(const float* __restrict__ xbc,
                                                  const float* __restrict__ dtbT,
                                                  const float* __restrict__ A_log,
                                                  float* __restrict__ S,
                                                  float* __restrict__ chunkT){
    __shared__ __align__(16) unsigned short BTh[128 * SP], BTl[128 * SP]; // B^T [n][s]
    __shared__ __align__(16) unsigned short XTh[64 * SP],  XTl[64 * SP];  // (Xw_h)^T [p][s]
    __shared__ float wln4[4][64];
    int c = blockIdx.x;
    int t0 = c * QC, Q = min(QC, HW - t0);
    int tid = threadIdx.x;
    int lane = tid & 63, wid = tid >> 6;
    int wy = wid >> 1, wx = wid & 1;
    int l15 = lane & 15, g = lane >> 4;
    // per-wave cumsum for head = wid
    {
        float d = (lane < Q) ? dtbT[wid * DTP + t0 + lane] : 0.f;
        float A = -expf(A_log[wid]);
        float a = d * A;
        #pragma unroll
        for (int off = 1; off < 64; off <<= 1){
            float u = __shfl_up(a, off);
            if (lane >= off) a += u;
        }
        float T = __shfl(a, Q - 1);
        wln4[wid][lane] = (lane < Q) ? __expf(T - a) * d : 0.f;
        if (lane == 0) chunkT[c * 4 + wid] = T;
    }
    // stage B^T (shared by all heads)
    __syncthreads();
    for (int e2 = tid; e2 < 4096; e2 += 256){
        int nn = e2 & 127, sp = e2 >> 7;
        int s0 = 2 * sp;
        float v0 = (s0 < Q)     ? xbc[(size_t)(t0 + s0) * 512 + 256 + nn] : 0.f;
        float v1 = (s0 + 1 < Q) ? xbc[(size_t)(t0 + s0 + 1) * 512 + 256 + nn] : 0.f;
        unsigned short h0, l0, h1, l1;
        bf16_split(v0, h0, l0); bf16_split(v1, h1, l1);
        *reinterpret_cast<unsigned*>(&BTh[nn * SP + s0]) = pack2(h0, h1);
        *reinterpret_cast<unsigned*>(&BTl[nn * SP + s0]) = pack2(l0, l1);
    }
    for (int h = 0; h < 4; h++){
        // stage (Xw_h)^T
        for (int e2 = tid; e2 < 2048; e2 += 256){
            int pp = e2 & 63, sp = e2 >> 6;
            int s0 = 2 * sp;
            float v0 = (s0 < Q)     ? xbc[(size_t)(t0 + s0) * 512 + h * 64 + pp] * wln4[h][s0] : 0.f;
            float v1 = (s0 + 1 < Q) ? xbc[(size_t)(t0 + s0 + 1) * 512 + h * 64 + pp] * wln4[h][s0 + 1] : 0.f;
            unsigned short h0, l0, h1, l1;
            bf16_split(v0, h0, l0); bf16_split(v1, h1, l1);
            *reinterpret_cast<unsigned*>(&XTh[pp * SP + s0]) = pack2(h0, h1);
            *reinterpret_cast<unsigned*>(&XTl[pp * SP + s0]) = pack2(l0, l1);
        }
        __syncthreads();
        fv4 acc[2][4];
        #pragma unroll
        for (int mi = 0; mi < 2; mi++)
            #pragma unroll
            for (int ni = 0; ni < 4; ni++) acc[mi][ni] = (fv4){0.f,0.f,0.f,0.f};
        #pragma unroll
        for (int ks = 0; ks < 2; ks++){
            short8 ah[2], al[2], bh_[4], bl_[4];
            #pragma unroll
            for (int mi = 0; mi < 2; mi++){
                unsigned off = (wy * 32 + mi * 16 + l15) * SP + ks * 32 + g * 8;
                ah[mi] = *reinterpret_cast<const short8*>(&XTh[off]);
                al[mi] = *reinterpret_cast<const short8*>(&XTl[off]);
            }
            #pragma unroll
            for (int ni = 0; ni < 4; ni++){
                unsigned off = (wx * 64 + ni * 16 + l15) * SP + ks * 32 + g * 8;
                bh_[ni] = *reinterpret_cast<const short8*>(&BTh[off]);
                bl_[ni] = *reinterpret_cast<const short8*>(&BTl[off]);
            }
            #pragma unroll
            for (int mi = 0; mi < 2; mi++)
                #pragma unroll
                for (int ni = 0; ni < 4; ni++){
                    acc[mi][ni] = __builtin_amdgcn_mfma_f32_16x16x32_bf16(ah[mi], bh_[ni], acc[mi][ni], 0, 0, 0);
                    acc[mi][ni] = __builtin_amdgcn_mfma_f32_16x16x32_bf16(ah[mi], bl_[ni], acc[mi][ni], 0, 0, 0);
                    acc[mi][ni] = __builtin_amdgcn_mfma_f32_16x16x32_bf16(al[mi], bh_[ni], acc[mi][ni], 0, 0, 0);
                }
        }
        size_t sb = (size_t)(c * 4 + h) * 8192;
        #pragma unroll
        for (int mi = 0; mi < 2; mi++)
            #pragma unroll
            for (int ni = 0; ni < 4; ni++)
                #pragma unroll
                for (int j = 0; j < 4; j++){
                    int p = wy * 32 + mi * 16 + g * 4 + j;
                    int n = wx * 64 + ni * 16 + l15;
                    S[sb + p * 128 + n] = acc[mi][ni][j];
                }
        __syncthreads();   // before next head overwrites XT
    }
}

// ---------------- SSD phase B: in-place prefix over chunks (pipelined) ------------
__global__ __launch_bounds__(256) void ssd_phaseB(float* __restrict__ S,
                                                  const float* __restrict__ chunkT){
    __shared__ float e[NCH];
    int tid = threadIdx.x;
    int idx = blockIdx.x * 256 + tid;
    int h = idx >> 13, pn = idx & 8191;
    for (int c = tid; c < NCH; c += 256) e[c] = __expf(chunkT[c * 4 + h]);
    __syncthreads();
    #define LDS_(cc) S[((size_t)((cc) * 4 + h)) * 8192 + pn]
    float b0 = LDS_(0), b1 = LDS_(1), b2 = LDS_(2), b3 = LDS_(3);
    float s = 0.f;
    int c = 0;
    for (; c + 8 <= NCH; c += 4){
        float n0 = LDS_(c + 4), n1 = LDS_(c + 5), n2 = LDS_(c + 6), n3 = LDS_(c + 7);
        LDS_(c) = s;     s = fmaf(s, e[c],     b0);
        LDS_(c + 1) = s; s = fmaf(s, e[c + 1], b1);
        LDS_(c + 2) = s; s = fmaf(s, e[c + 2], b2);
        LDS_(c + 3) = s; s = fmaf(s, e[c + 3], b3);
        b0 = n0; b1 = n1; b2 = n2; b3 = n3;
    }
    for (; c < NCH; c++){
        float nx = (c + 4 < NCH) ? LDS_(c + 4) : 0.f;
        float loc = b0; b0 = b1; b1 = b2; b2 = b3; b3 = nx;
        LDS_(c) = s;
        s = fmaf(s, e[c], loc);
    }
    #undef LDS_
}

// ---------------- SSD phase C (MFMA, head-merged, direct-global S) ----------------
__global__ __launch_bounds__(256) void ssd_phaseC(const float* __restrict__ xbc,
                                                  const float* __restrict__ dtbT,
                                                  const float* __restrict__ A_log,
                                                  const float* __restrict__ Dvec,
                                                  const float* __restrict__ S,
                                                  float* __restrict__ y){
    __shared__ __align__(16) unsigned short U0h[64 * SP], U0l[64 * SP]; // C half-stage; later P [t][s]
    __shared__ __align__(16) unsigned short U1h[64 * SP], U1l[64 * SP]; // B half-stage; later X^T [p][s]
    __shared__ float cum4[4][64], dth4[4][64];
    int c = blockIdx.x;
    int t0 = c * QC, Q = min(QC, HW - t0);
    int tid = threadIdx.x;
    int lane = tid & 63, wid = tid >> 6;
    int wy = wid >> 1, wx = wid & 1;
    int l15 = lane & 15, g = lane >> 4;
    // per-wave cumsum for head = wid
    {
        float d = (lane < Q) ? dtbT[wid * DTP + t0 + lane] : 0.f;
        dth4[wid][lane] = d;
        float A = -expf(A_log[wid]);
        float a = d * A;
        #pragma unroll
        for (int off = 1; off < 64; off <<= 1){
            float u = __shfl_up(a, off);
            if (lane >= off) a += u;
        }
        cum4[wid][lane] = a;
    }

    fv4 accG[2][2];
    fv4 accA[4][2][2];
    #pragma unroll
    for (int mi = 0; mi < 2; mi++)
        #pragma unroll
        for (int ni = 0; ni < 2; ni++){
            accG[mi][ni] = (fv4){0.f,0.f,0.f,0.f};
            #pragma unroll
            for (int h = 0; h < 4; h++) accA[h][mi][ni] = (fv4){0.f,0.f,0.f,0.f};
        }

    #pragma unroll
    for (int ks = 0; ks < 2; ks++){
        int n0 = ks * 64;
        __syncthreads();
        // stage C half -> U0, B half -> U1
        for (int e2 = tid; e2 < 2048; e2 += 256){
            int rr = e2 >> 5, n2 = (e2 & 31) * 2;
            bool ok = rr < Q;
            const float* rp = xbc + (size_t)(t0 + rr) * 512;
            float c0 = ok ? rp[384 + n0 + n2]     : 0.f;
            float c1 = ok ? rp[384 + n0 + n2 + 1] : 0.f;
            float b0 = ok ? rp[256 + n0 + n2]     : 0.f;
            float b1 = ok ? rp[256 + n0 + n2 + 1] : 0.f;
            unsigned short xh0, xl0, xh1, xl1;
            bf16_split(c0, xh0, xl0); bf16_split(c1, xh1, xl1);
            *reinterpret_cast<unsigned*>(&U0h[rr * SP + n2]) = pack2(xh0, xh1);
            *reinterpret_cast<unsigned*>(&U0l[rr * SP + n2]) = pack2(xl0, xl1);
            bf16_split(b0, xh0, xl0); bf16_split(b1, xh1, xl1);
            *reinterpret_cast<unsigned*>(&U1h[rr * SP + n2]) = pack2(xh0, xh1);
            *reinterpret_cast<unsigned*>(&U1l[rr * SP + n2]) = pack2(xl0, xl1);
        }
        __syncthreads();
        #pragma unroll
        for (int kk = 0; kk < 2; kk++){
            short8 ah[2], al[2], bh[2], bl[2];
            #pragma unroll
            for (int mi = 0; mi < 2; mi++){
                unsigned off = (wy * 32 + mi * 16 + l15) * SP + kk * 32 + g * 8;
                ah[mi] = *reinterpret_cast<const short8*>(&U0h[off]);
                al[mi] = *reinterpret_cast<const short8*>(&U0l[off]);
            }
            #pragma unroll
            for (int ni = 0; ni < 2; ni++){
                unsigned off = (wx * 32 + ni * 16 + l15) * SP + kk * 32 + g * 8;
                bh[ni] = *reinterpret_cast<const short8*>(&U1h[off]);
                bl[ni] = *reinterpret_cast<const short8*>(&U1l[off]);
            }
            // G += C.B^T
            #pragma unroll
            for (int mi = 0; mi < 2; mi++)
                #pragma unroll
                for (int ni = 0; ni < 2; ni++){
                    accG[mi][ni] = __builtin_amdgcn_mfma_f32_16x16x32_bf16(ah[mi], bh[ni], accG[mi][ni], 0, 0, 0);
                    accG[mi][ni] = __builtin_amdgcn_mfma_f32_16x16x32_bf16(ah[mi], bl[ni], accG[mi][ni], 0, 0, 0);
                    accG[mi][ni] = __builtin_amdgcn_mfma_f32_16x16x32_bf16(al[mi], bh[ni], accG[mi][ni], 0, 0, 0);
                }
            // AC_h += C.S_h^T  (S direct from global, per-lane)
            #pragma unroll
            for (int h = 0; h < 4; h++){
                const float* sbp = S + (size_t)(c * 4 + h) * 8192;
                short8 sh[2], sl[2];
                #pragma unroll
                for (int ni = 0; ni < 2; ni++){
                    int p = wx * 32 + ni * 16 + l15;
                    split8g(sbp + (size_t)p * 128 + n0 + kk * 32 + g * 8, sh[ni], sl[ni]);
                }
                #pragma unroll
                for (int mi = 0; mi < 2; mi++)
                    #pragma unroll
                    for (int ni = 0; ni < 2; ni++){
                        accA[h][mi][ni] = __builtin_amdgcn_mfma_f32_16x16x32_bf16(ah[mi], sh[ni], accA[h][mi][ni], 0, 0, 0);
                        accA[h][mi][ni] = __builtin_amdgcn_mfma_f32_16x16x32_bf16(ah[mi], sl[ni], accA[h][mi][ni], 0, 0, 0);
                        accA[h][mi][ni] = __builtin_amdgcn_mfma_f32_16x16x32_bf16(al[mi], sh[ni], accA[h][mi][ni], 0, 0, 0);
                    }
            }
        }
    }
    // per-head finish: P, X^T, Y
    for (int h = 0; h < 4; h++){
        __syncthreads();   // staged buffers free to overwrite
        // write P quadrant (from accG registers)
        #pragma unroll
        for (int mi = 0; mi < 2; mi++)
            #pragma unroll
            for (int ni = 0; ni < 2; ni++)
                #pragma unroll
                for (int j = 0; j < 4; j++){
                    int t = wy * 32 + mi * 16 + g * 4 + j;
                    int s = wx * 32 + ni * 16 + l15;
                    float pv = 0.f;
                    if (s <= t && s < Q)
                        pv = accG[mi][ni][j] * __expf(cum4[h][t] - cum4[h][s]) * dth4[h][s];
                    unsigned short hs, ls;
                    bf16_split(pv, hs, ls);
                    U0h[t * SP + s] = hs;
                    U0l[t * SP + s] = ls;
                }
        // stage X_h^T [p][s]
        for (int e2 = tid; e2 < 2048; e2 += 256){
            int pp = e2 & 63, sp = e2 >> 6;
            int s0 = 2 * sp;
            float v0 = (s0 < Q)     ? xbc[(size_t)(t0 + s0) * 512 + h * 64 + pp] : 0.f;
            float v1 = (s0 + 1 < Q) ? xbc[(size_t)(t0 + s0 + 1) * 512 + h * 64 + pp] : 0.f;
            unsigned short h0, l0, h1, l1;
            bf16_split(v0, h0, l0); bf16_split(v1, h1, l1);
            *reinterpret_cast<unsigned*>(&U1h[pp * SP + s0]) = pack2(h0, h1);
            *reinterpret_cast<unsigned*>(&U1l[pp * SP + s0]) = pack2(l0, l1);
        }
        __syncthreads();
        fv4 accY[2][2];
        #pragma unroll
        for (int mi = 0; mi < 2; mi++)
            #pragma unroll
            for (int ni = 0; ni < 2; ni++)
                #pragma unroll
                for (int j = 0; j < 4; j++){
                    int t = wy * 32 + mi * 16 + g * 4 + j;
                    accY[mi][ni][j] = __expf(cum4[h][t]) * accA[h][mi][ni][j];
                }
        #pragma unroll
        for (int kk = 0; kk < 2; kk++){
            short8 ph[2], pl[2], xh[2], xl[2];
            #pragma unroll
            for (int mi = 0; mi < 2; mi++){
                unsigned off = (wy * 32 + mi * 16 + l15) * SP + kk * 32 + g * 8;
                ph[mi] = *reinterpret_cast<const short8*>(&U0h[off]);
                pl[mi] = *reinterpret_cast<const short8*>(&U0l[off]);
            }
            #pragma unroll
            for (int ni = 0; ni < 2; ni++){
                unsigned off = (wx * 32 + ni * 16 + l15) * SP + kk * 32 + g * 8;
                xh[ni] = *reinterpret_cast<const short8*>(&U1h[off]);
                xl[ni] = *reinterpret_cast<const short8*>(&U1l[off]);
            }
            #pragma unroll
            for (int mi = 0; mi < 2; mi++)
                #pragma unroll
                for (int ni = 0; ni < 2; ni++){
                    accY[mi][ni] = __builtin_amdgcn_mfma_f32_16x16x32_bf16(ph[mi], xh[ni], accY[mi][ni], 0, 0, 0);
                    accY[mi][ni] = __builtin_amdgcn_mfma_f32_16x16x32_bf16(ph[mi], xl[ni], accY[mi][ni], 0, 0, 0);
                    accY[mi][ni] = __builtin_amdgcn_mfma_f32_16x16x32_bf16(pl[mi], xh[ni], accY[mi][ni], 0, 0, 0);
                }
        }
        float Dh = Dvec[h];
        #pragma unroll
        for (int mi = 0; mi < 2; mi++)
            #pragma unroll
            for (int ni = 0; ni < 2; ni++)
                #pragma unroll
                for (int j = 0; j < 4; j++){
                    int t = wy * 32 + mi * 16 + g * 4 + j;
                    if (t >= Q) continue;
                    int p = wx * 32 + ni * 16 + l15;
                    float xv = xbc[(size_t)(t0 + t) * 512 + h * 64 + p];
                    y[(size_t)(t0 + t) * 256 + h * 64 + p] = accY[mi][ni][j] + Dh * xv;
                }
    }
}

// ---------------- gated RMSNorm ----------------
__global__ void gated_rms_kernel(float* __restrict__ y, const float* __restrict__ zx,
                                 const float* __restrict__ nw){
    int row = blockIdx.x, tid = threadIdx.x;
    float v = y[(size_t)row * 256 + tid];
    float z = zx[(size_t)row * 772 + tid];
    v *= silu_f(z);
    float s = v * v;
    __shared__ float r1[4];
    #pragma unroll
    for (int o = 32; o > 0; o >>= 1) s += __shfl_down(s, o);
    if ((tid & 63) == 0) r1[tid >> 6] = s;
    __syncthreads();
    float S = r1[0] + r1[1] + r1[2] + r1[3];
    float rs = rsqrtf(S / 256.f + 1e-5f);
    y[(size_t)row * 256 + tid] = v * rs * nw[tid];
}

extern "C" void kernel_launch(void* const* d_in, const int* in_sizes, int n_in,
                              void* d_out, int out_size, void* d_ws, size_t ws_size,
                              hipStream_t stream){
    (void)in_sizes; (void)n_in; (void)out_size; (void)ws_size;
    const float* x        = (const float*)d_in[0];
    const float* ln_pre_g = (const float*)d_in[1];
    const float* ln_pre_b = (const float*)d_in[2];
    const float* fe_w1    = (const float*)d_in[3];
    const float* fe_b1    = (const float*)d_in[4];
    const float* fe_w2    = (const float*)d_in[5];
    const float* fe_b2    = (const float*)d_in[6];
    const float* cv_w1    = (const float*)d_in[7];
    const float* cv_b1    = (const float*)d_in[8];
    const float* cv_w2    = (const float*)d_in[9];
    const float* cv_b2    = (const float*)d_in[10];
    const float* mp_w     = (const float*)d_in[11];
    const float* mp_b     = (const float*)d_in[12];
    const float* mp_ln_g  = (const float*)d_in[13];
    const float* mp_ln_b  = (const float*)d_in[14];
    const float* m_in_w   = (const float*)d_in[15];
    const float* m_conv_w = (const float*)d_in[16];
    const float* m_conv_b = (const float*)d_in[17];
    const float* m_dtb    = (const float*)d_in[18];
    const float* m_A_log  = (const float*)d_in[19];
    const float* m_D      = (const float*)d_in[20];
    const float* m_norm_w = (const float*)d_in[21];
    const float* m_out_w  = (const float*)d_in[22];
    const float* cls_ln_g = (const float*)d_in[23];
    const float* cls_ln_b = (const float*)d_in[24];
    const float* cls_w1   = (const float*)d_in[25];
    const float* cls_b1   = (const float*)d_in[26];
    const float* cls_w2   = (const float*)d_in[27];
    const float* cls_b2   = (const float*)d_in[28];
    const float* cls_w3   = (const float*)d_in[29];
    const float* cls_b3   = (const float*)d_in[30];

    float* ws   = (float*)d_ws;
    float* xn   = ws + OFF_XN;
    float* f1   = ws + OFF_F1;
    float* comb = ws + OFF_COMB;
    float* p    = ws + OFF_P;
    float* zx   = ws + OFF_ZX;
    float* xbc  = ws + OFF_XBC;
    float* Sbuf = ws + OFF_S;
    float* dtbT = ws + OFF_DT;
    float* chkT = ws + OFF_CT;
    float* c1h  = ws + OFF_XBC;                    // before xbc live
    float* c2h  = ws + OFF_XBC + 691488;
    float* pr   = ws + OFF_XN;
    float* ybuf = ws + OFF_F1;
    float* mo   = ws + OFF_COMB;
    float* cls0 = ws + OFF_XN;
    float* cls1 = ws + OFF_P;
    float* cls2 = ws + OFF_COMB + 2691200;
    unsigned short* W1h = (unsigned short*)(ws + OFF_W);
    unsigned short* W1l = (unsigned short*)(ws + OFF_W + 32256);
    unsigned short* W2h = (unsigned short*)(ws + OFF_W + 64512);
    unsigned short* W2l = (unsigned short*)(ws + OFF_W + 73728);

    // 0. conv weight prepack (tiny)
    prep_w<200, 32, 7><<<(32 * 2016 + 255) / 256, 256, 0, stream>>>(cv_w1, W1h, W1l);
    prep_w<32, 64, 1><<<(64 * 288 + 255) / 256, 256, 0, stream>>>(cv_w2, W2h, W2l);
    // 1. pre-LN
    ln_kernel<0><<<HW, 256, 0, stream>>>(x, ln_pre_g, ln_pre_b, xn, NBANDS);
    // 2-3. feature MLP (f -> comb[:, :128], ldc=192)
    gemm_mfma<1><<<dim3(4, 165), 256, 0, stream>>>(xn, 200, fe_w1, fe_b1, f1, 256, HW, 256, 200);
    gemm_mfma<1><<<dim3(2, 165), 256, 0, stream>>>(f1, 256, fe_w2, fe_b2, comb, 192, HW, 128, 256);
    // 4. conv1 (MFMA implicit-im2col): 200->32, pad 2
    conv_mfma<200, 32, 2, 7, 1><<<dim3(3, CONVH), 256, 0, stream>>>(xn, Hdim, Wdim, W1h, W1l, cv_b1, c1h);
    // 5. conv2 (MFMA): 32->64, pad 1
    conv_mfma<32, 64, 1, 1, 2><<<dim3(3, CONVH), 256, 0, stream>>>(c1h, CONVH, CONVH, W2h, W2l, cv_b2, c2h);
    // 6. adaptive pool -> comb[:, 128:192]
    pool_kernel<<<(HW * 64 + 255) / 256, 256, 0, stream>>>(c2h, comb);
    // 7-8. mid projection + LN + GELU
    gemm_mfma<0><<<dim3(2, 165), 256, 0, stream>>>(comb, 192, mp_w, mp_b, pr, 128, HW, 128, 192);
    ln_kernel<1><<<HW, 256, 0, stream>>>(pr, mp_ln_g, mp_ln_b, p, 128);
    // 9. mamba in_proj
    gemm_mfma<0><<<dim3(13, 165), 256, 0, stream>>>(p, 128, m_in_w, (const float*)nullptr, zx, 772, HW, 772, 128);
    // 10. dt softplus (transposed [h][t])
    dt_kernel<<<dim3((HW + 255) / 256, 4), 256, 0, stream>>>(zx, m_dtb, dtbT);
    // 11. depthwise causal conv + silu (tiled)
    conv1d_tiled<<<dim3(4, NCH), 256, 0, stream>>>(zx, m_conv_w, m_conv_b, xbc);
    // 12-14. SSD chunked scan (MFMA, head-merged)
    ssd_phaseA<<<NCH, 256, 0, stream>>>(xbc, dtbT, m_A_log, Sbuf, chkT);
    ssd_phaseB<<<128, 256, 0, stream>>>(Sbuf, chkT);
    ssd_phaseC<<<NCH, 256, 0, stream>>>(xbc, dtbT, m_A_log, m_D, Sbuf, ybuf);
    // 15. gated RMSNorm
    gated_rms_kernel<<<HW, 256, 0, stream>>>(ybuf, zx, m_norm_w);
    // 16. out proj
    gemm_mfma<0><<<dim3(2, 165), 256, 0, stream>>>(ybuf, 256, m_out_w, (const float*)nullptr, mo, 128, HW, 128, 256);
    // 17-20. classifier
    ln_kernel<0><<<HW, 256, 0, stream>>>(mo, cls_ln_g, cls_ln_b, cls0, 128);
    gemm_mfma<1><<<dim3(2, 165), 256, 0, stream>>>(cls0, 128, cls_w1, cls_b1, cls1, 128, HW, 128, 128);
    gemm_mfma<1><<<dim3(1, 165), 256, 0, stream>>>(cls1, 128, cls_w2, cls_b2, cls2, 64, HW, 64, 128);
    gemm_mfma<0><<<dim3(1, 165), 256, 0, stream>>>(cls2, 64, cls_w3, cls_b3, (float*)d_out, 17, HW, 17, 64);
}

// Round 7
// 518.451 us; speedup vs baseline: 1.0048x; 1.0048x over previous
//
#include <hip/hip_runtime.h>
#include <math.h>

#define HW 21025        // 145*145
#define Hdim 145
#define Wdim 145
#define NBANDS 200
#define CONVH 147
#define CONVHW 21609    // 147*147
#define QC 64
#define NCH 329         // ceil(21025/64)
#define DTP 21056       // padded L for transposed dt
#define SP 72           // short stride for [.][64-k] MFMA tiles
#define SSD_GRID 1344   // 8 * 4 * 42 (xcd-sibling swizzled, tail-guarded)

typedef __attribute__((ext_vector_type(4))) float fv4;
typedef __attribute__((ext_vector_type(8))) short short8;

// ---------------- workspace layout (float offsets) ----------------
#define OFF_XN   ((size_t)0)           // 4,205,000  xn; later pr, cls0
#define OFF_F1   ((size_t)4205000)     // 5,382,400  f1; later y (L x 256)
#define OFF_COMB ((size_t)9587400)     // 4,036,800  comb L x 192; later mo + cls2
#define OFF_P    ((size_t)13624200)    // 2,691,200  p; later cls1
#define OFF_ZX   ((size_t)16315400)    // 16,231,300 zxbcdt L x 772
#define OFF_XBC  ((size_t)32546700)    // 10,764,800 c1h+c2h first, then xbc L x 512
#define OFF_S    ((size_t)43311500)    // 10,780,672 S packed u32 (bf16 hi|lo)
#define OFF_DT   ((size_t)54092172)    // 84,224 (dt transposed [4][DTP])
#define OFF_CT   ((size_t)54176396)    // 1,316
#define OFF_W    ((size_t)54177712)    // 82,944: packed conv weights (bf16 hi/lo)

__device__ __forceinline__ float gelu_f(float x){
    return 0.5f * x * (1.0f + erff(x * 0.70710678118654752440f));
}
__device__ __forceinline__ float silu_f(float x){
    return x / (1.0f + expf(-x));
}

__device__ __forceinline__ void bf16_split(float x, unsigned short& hs, unsigned short& ls){
    unsigned u = __float_as_uint(x);
    hs = (unsigned short)(u >> 16);
    float hif = __uint_as_float(u & 0xFFFF0000u);
    float lof = x - hif;
    ls = (unsigned short)(__float_as_uint(lof) >> 16);
}
__device__ __forceinline__ unsigned pack2(unsigned short a, unsigned short b){
    return (unsigned)a | ((unsigned)b << 16);
}
// f32 -> (hi<<16)|lo packed split
__device__ __forceinline__ unsigned packsplit(float x){
    unsigned short hs, ls;
    bf16_split(x, hs, ls);
    return ((unsigned)hs << 16) | (unsigned)ls;
}
__device__ __forceinline__ float unpackf(unsigned u){
    return __uint_as_float(u & 0xFFFF0000u) + __uint_as_float(u << 16);
}
// load 8 consecutive f32 from global, split into hi/lo short8
__device__ __forceinline__ void split8g(const float* p, short8& h8, short8& l8){
    fv4 v0 = *reinterpret_cast<const fv4*>(p);
    fv4 v1 = *reinterpret_cast<const fv4*>(p + 4);
    unsigned short hs, ls;
    #pragma unroll
    for (int j = 0; j < 4; j++){
        bf16_split(v0[j], hs, ls); h8[j] = (short)hs; l8[j] = (short)ls;
        bf16_split(v1[j], hs, ls); h8[4 + j] = (short)hs; l8[4 + j] = (short)ls;
    }
}
// load 8 packed u32, unpack to hi/lo short8 (shifts only)
__device__ __forceinline__ void unpack8(const unsigned* p, short8& h8, short8& l8){
    uint4 a = *reinterpret_cast<const uint4*>(p);
    uint4 b = *reinterpret_cast<const uint4*>(p + 4);
    unsigned v0 = a.x, v1 = a.y, v2 = a.z, v3 = a.w;
    unsigned v4 = b.x, v5 = b.y, v6 = b.z, v7 = b.w;
    h8[0]=(short)(v0>>16); l8[0]=(short)(v0&0xFFFFu);
    h8[1]=(short)(v1>>16); l8[1]=(short)(v1&0xFFFFu);
    h8[2]=(short)(v2>>16); l8[2]=(short)(v2&0xFFFFu);
    h8[3]=(short)(v3>>16); l8[3]=(short)(v3&0xFFFFu);
    h8[4]=(short)(v4>>16); l8[4]=(short)(v4&0xFFFFu);
    h8[5]=(short)(v5>>16); l8[5]=(short)(v5&0xFFFFu);
    h8[6]=(short)(v6>>16); l8[6]=(short)(v6&0xFFFFu);
    h8[7]=(short)(v7>>16); l8[7]=(short)(v7&0xFFFFu);
}

// ---------------- LayerNorm (+ optional GELU) ----------------
template<int ACT>
__global__ void ln_kernel(const float* __restrict__ in, const float* __restrict__ g,
                          const float* __restrict__ b, float* __restrict__ out, int D){
    int row = blockIdx.x, tid = threadIdx.x;
    const float* r = in + (size_t)row * D;
    float s = 0.f, s2 = 0.f;
    for (int i = tid; i < D; i += 256){ float v = r[i]; s += v; s2 += v*v; }
    __shared__ float r1[4], r2[4];
    #pragma unroll
    for (int o = 32; o > 0; o >>= 1){ s += __shfl_down(s, o); s2 += __shfl_down(s2, o); }
    if ((tid & 63) == 0){ r1[tid >> 6] = s; r2[tid >> 6] = s2; }
    __syncthreads();
    float S = r1[0] + r1[1] + r1[2] + r1[3];
    float S2 = r2[0] + r2[1] + r2[2] + r2[3];
    float mean = S / (float)D;
    float var = S2 / (float)D - mean * mean;
    float rs = rsqrtf(fmaxf(var, 0.f) + 1e-5f);
    float* o_ = out + (size_t)row * D;
    for (int i = tid; i < D; i += 256){
        float v = (r[i] - mean) * rs * g[i] + b[i];
        if (ACT == 1) v = gelu_f(v);
        o_[i] = v;
    }
}

// ---------------- split-bf16 MFMA GEMM: C = act(A@B + bias) ----------------
template<int ACT>
__global__ __launch_bounds__(256) void gemm_mfma(const float* __restrict__ A, int lda,
                                                 const float* __restrict__ B,
                                                 const float* __restrict__ bias,
                                                 float* __restrict__ C, int ldc,
                                                 int M, int N, int K){
    const int SA = 40;
    __shared__ __align__(16) unsigned short Ah[128 * SA], Al[128 * SA];
    __shared__ __align__(16) unsigned short Bh[64 * SA],  Bl[64 * SA];
    int tid = threadIdx.x;
    int lane = tid & 63, wid = tid >> 6;
    int wy = wid >> 1, wx = wid & 1;
    int bm = blockIdx.y * 128, bn = blockIdx.x * 64;
    int l15 = lane & 15, g = lane >> 4;

    fv4 acc[4][2];
    #pragma unroll
    for (int i = 0; i < 4; i++)
        #pragma unroll
        for (int j = 0; j < 2; j++) acc[i][j] = (fv4){0.f,0.f,0.f,0.f};

    int am = tid >> 1;
    int aq = (tid & 1) * 4;
    bool arow_ok = (bm + am) < M;
    int bn_t = tid & 63;
    int bk8 = (tid >> 6) * 8;
    bool bcol_ok = (bn + bn_t) < N;

    int nK = (K + 31) / 32;
    for (int ks = 0; ks < nK; ks++){
        int k0 = ks * 32;
        const float* Ap = A + (size_t)(bm + am) * lda + k0;
        #pragma unroll
        for (int f = 0; f < 4; f++){
            int kq = aq + f;
            fv4 v = (fv4){0.f,0.f,0.f,0.f};
            if (arow_ok && (k0 + kq * 4 + 4) <= K)
                v = *reinterpret_cast<const fv4*>(Ap + kq * 4);
            unsigned short hs[4], ls[4];
            #pragma unroll
            for (int j = 0; j < 4; j++) bf16_split(v[j], hs[j], ls[j]);
            unsigned off = am * SA + kq * 4;
            *reinterpret_cast<uint2*>(&Ah[off]) = make_uint2(pack2(hs[0],hs[1]), pack2(hs[2],hs[3]));
            *reinterpret_cast<uint2*>(&Al[off]) = make_uint2(pack2(ls[0],ls[1]), pack2(ls[2],ls[3]));
        }
        {
            unsigned short hs[8], ls[8];
            #pragma unroll
            for (int j = 0; j < 8; j++){
                int kk = k0 + bk8 + j;
                float v = (bcol_ok && kk < K) ? B[(size_t)kk * N + bn + bn_t] : 0.f;
                bf16_split(v, hs[j], ls[j]);
            }
            unsigned off = bn_t * SA + bk8;
            *reinterpret_cast<uint4*>(&Bh[off]) = make_uint4(pack2(hs[0],hs[1]), pack2(hs[2],hs[3]),
                                                             pack2(hs[4],hs[5]), pack2(hs[6],hs[7]));
            *reinterpret_cast<uint4*>(&Bl[off]) = make_uint4(pack2(ls[0],ls[1]), pack2(ls[2],ls[3]),
                                                             pack2(ls[4],ls[5]), pack2(ls[6],ls[7]));
        }
        __syncthreads();
        short8 afh[4], afl[4], bfh[2], bfl[2];
        #pragma unroll
        for (int mi = 0; mi < 4; mi++){
            unsigned off = (wy * 64 + mi * 16 + l15) * SA + g * 8;
            afh[mi] = *reinterpret_cast<const short8*>(&Ah[off]);
            afl[mi] = *reinterpret_cast<const short8*>(&Al[off]);
        }
        #pragma unroll
        for (int ni = 0; ni < 2; ni++){
            unsigned off = (wx * 32 + ni * 16 + l15) * SA + g * 8;
            bfh[ni] = *reinterpret_cast<const short8*>(&Bh[off]);
            bfl[ni] = *reinterpret_cast<const short8*>(&Bl[off]);
        }
        #pragma unroll
        for (int mi = 0; mi < 4; mi++)
            #pragma unroll
            for (int ni = 0; ni < 2; ni++){
                acc[mi][ni] = __builtin_amdgcn_mfma_f32_16x16x32_bf16(afh[mi], bfh[ni], acc[mi][ni], 0, 0, 0);
                acc[mi][ni] = __builtin_amdgcn_mfma_f32_16x16x32_bf16(afh[mi], bfl[ni], acc[mi][ni], 0, 0, 0);
                acc[mi][ni] = __builtin_amdgcn_mfma_f32_16x16x32_bf16(afl[mi], bfh[ni], acc[mi][ni], 0, 0, 0);
            }
        __syncthreads();
    }
    #pragma unroll
    for (int mi = 0; mi < 4; mi++){
        #pragma unroll
        for (int ni = 0; ni < 2; ni++){
            int cc = bn + wx * 32 + ni * 16 + l15;
            if (cc >= N) continue;
            float bv = bias ? bias[cc] : 0.f;
            #pragma unroll
            for (int j = 0; j < 4; j++){
                int rr = bm + wy * 64 + mi * 16 + g * 4 + j;
                if (rr >= M) continue;
                float v = acc[mi][ni][j] + bv;
                if (ACT == 1) v = gelu_f(v);
                C[(size_t)rr * ldc + cc] = v;
            }
        }
    }
}

// ---------------- conv weight prepack ----------------
template<int IC, int OC, int NCHUNK>
__global__ void prep_w(const float* __restrict__ w, unsigned short* __restrict__ Wh,
                       unsigned short* __restrict__ Wl){
    const int KP = NCHUNK * 288;
    int idx = blockIdx.x * 256 + threadIdx.x;
    if (idx >= OC * KP) return;
    int o = idx / KP, k = idx % KP;
    int ch = k / 288, rest = k % 288, t = rest / 32, c = rest & 31;
    int ci = ch * 32 + c;
    float v = (ci < IC) ? w[((size_t)o * IC + ci) * 9 + t] : 0.f;
    unsigned short hs, ls;
    bf16_split(v, hs, ls);
    Wh[idx] = hs; Wl[idx] = ls;
}

// ---------------- MFMA direct conv 3x3 (implicit im2col in LDS) -------------------
template<int IC, int OC, int PAD, int NCHUNK, int NFRAG>
__global__ __launch_bounds__(256) void conv_mfma(const float* __restrict__ in,
                                                 int inH, int inW,
                                                 const unsigned short* __restrict__ Wh,
                                                 const unsigned short* __restrict__ Wl,
                                                 const float* __restrict__ bias,
                                                 float* __restrict__ out){
    const int KP = NCHUNK * 288;
    const int CST = 40;
    __shared__ __align__(16) unsigned short Xh[3 * 68 * CST], Xl[3 * 68 * CST];
    int y = blockIdx.y;
    int x0 = blockIdx.x * 64;
    int tid = threadIdx.x;
    int lane = tid & 63, wid = tid >> 6;
    int wy = wid >> 1, wx = wid & 1;
    int l15 = lane & 15, g = lane >> 4;

    fv4 acc[2][NFRAG];
    #pragma unroll
    for (int mi = 0; mi < 2; mi++)
        #pragma unroll
        for (int ni = 0; ni < NFRAG; ni++) acc[mi][ni] = (fv4){0.f,0.f,0.f,0.f};

    for (int ch = 0; ch < NCHUNK; ch++){
        int ci0 = ch * 32;
        if (ch > 0) __syncthreads();
        for (int e = tid; e < 3 * 68 * 8; e += 256){
            int qd = e & 7;
            int c  = (e >> 3) % 68;
            int r  = e / 544;
            int iy = y - PAD + r, ix = x0 - PAD + c;
            fv4 v = (fv4){0.f,0.f,0.f,0.f};
            if ((unsigned)iy < (unsigned)inH && (unsigned)ix < (unsigned)inW &&
                (ci0 + qd * 4 + 4) <= IC)
                v = *reinterpret_cast<const fv4*>(in + ((size_t)iy * inW + ix) * IC + ci0 + qd * 4);
            unsigned short hs[4], ls[4];
            #pragma unroll
            for (int j = 0; j < 4; j++) bf16_split(v[j], hs[j], ls[j]);
            unsigned off = (r * 68 + c) * CST + qd * 4;
            *reinterpret_cast<uint2*>(&Xh[off]) = make_uint2(pack2(hs[0],hs[1]), pack2(hs[2],hs[3]));
            *reinterpret_cast<uint2*>(&Xl[off]) = make_uint2(pack2(ls[0],ls[1]), pack2(ls[2],ls[3]));
        }
        __syncthreads();
        #pragma unroll
        for (int t = 0; t < 9; t++){
            int ky = t / 3, kx = t % 3;
            short8 ah[2], al[2], bh[NFRAG], bl[NFRAG];
            #pragma unroll
            for (int mi = 0; mi < 2; mi++){
                unsigned off = (ky * 68 + wy * 32 + mi * 16 + l15 + kx) * CST + g * 8;
                ah[mi] = *reinterpret_cast<const short8*>(&Xh[off]);
                al[mi] = *reinterpret_cast<const short8*>(&Xl[off]);
            }
            #pragma unroll
            for (int ni = 0; ni < NFRAG; ni++){
                int oc = wx * (16 * NFRAG) + ni * 16 + l15;
                size_t woff = (size_t)oc * KP + ch * 288 + t * 32 + g * 8;
                bh[ni] = *reinterpret_cast<const short8*>(&Wh[woff]);
                bl[ni] = *reinterpret_cast<const short8*>(&Wl[woff]);
            }
            #pragma unroll
            for (int mi = 0; mi < 2; mi++)
                #pragma unroll
                for (int ni = 0; ni < NFRAG; ni++){
                    acc[mi][ni] = __builtin_amdgcn_mfma_f32_16x16x32_bf16(ah[mi], bh[ni], acc[mi][ni], 0, 0, 0);
                    acc[mi][ni] = __builtin_amdgcn_mfma_f32_16x16x32_bf16(ah[mi], bl[ni], acc[mi][ni], 0, 0, 0);
                    acc[mi][ni] = __builtin_amdgcn_mfma_f32_16x16x32_bf16(al[mi], bh[ni], acc[mi][ni], 0, 0, 0);
                }
        }
    }
    #pragma unroll
    for (int mi = 0; mi < 2; mi++)
        #pragma unroll
        for (int ni = 0; ni < NFRAG; ni++){
            int oc = wx * (16 * NFRAG) + ni * 16 + l15;
            float bv = bias[oc];
            #pragma unroll
            for (int j = 0; j < 4; j++){
                int x = x0 + wy * 32 + mi * 16 + g * 4 + j;
                if (x >= CONVH) continue;
                out[((size_t)y * CONVH + x) * OC + oc] = gelu_f(acc[mi][ni][j] + bv);
            }
        }
}

// ---------------- adaptive pool HWC into comb[:,128:] ----------------
__global__ void pool_kernel(const float* __restrict__ c2, float* __restrict__ comb){
    int idx = blockIdx.x * 256 + threadIdx.x;
    if (idx >= HW * 64) return;
    int o = idx & 63;
    int pix = idx >> 6;
    int xo = pix % Wdim, yo = pix / Wdim;
    int ys = yo * CONVH / Hdim, ye = ((yo + 1) * CONVH + Hdim - 1) / Hdim;
    int xs = xo * CONVH / Wdim, xe = ((xo + 1) * CONVH + Wdim - 1) / Wdim;
    float s = 0.f;
    for (int yy = ys; yy < ye; yy++)
        for (int xx = xs; xx < xe; xx++)
            s += c2[((size_t)yy * CONVH + xx) * 64 + o];
    comb[(size_t)pix * 192 + 128 + o] = s / (float)((ye - ys) * (xe - xs));
}

// ---------------- dt = softplus(raw + bias), transposed out [h][t] ----------------
__global__ void dt_kernel(const float* __restrict__ zx, const float* __restrict__ dt_bias,
                          float* __restrict__ dtbT){
    int t = blockIdx.x * 256 + threadIdx.x;
    int h = blockIdx.y;
    if (t >= HW) return;
    float v = zx[(size_t)t * 772 + 768 + h] + dt_bias[h];
    dtbT[h * DTP + t] = (v > 20.f) ? v : log1pf(expf(v));
}

// ---------------- depthwise causal conv1d (width 4) + silu, LDS-tiled ----------------
__global__ __launch_bounds__(256) void conv1d_tiled(const float* __restrict__ zx,
                                                    const float* __restrict__ w,
                                                    const float* __restrict__ b,
                                                    float* __restrict__ xbc){
    __shared__ float xs[67 * 128];
    __shared__ float wc[4 * 128];
    __shared__ float bc[128];
    int t0 = blockIdx.y * 64;
    int c0 = blockIdx.x * 128;
    int tid = threadIdx.x;
    for (int e = tid; e < 67 * 128; e += 256){
        int rr = e >> 7, cc = e & 127;
        int t = t0 - 3 + rr;
        xs[e] = (t >= 0 && t < HW) ? zx[(size_t)t * 772 + 256 + c0 + cc] : 0.f;
    }
    if (tid < 128){
        bc[tid] = b[c0 + tid];
        #pragma unroll
        for (int k = 0; k < 4; k++) wc[k * 128 + tid] = w[(c0 + tid) * 4 + k];
    }
    __syncthreads();
    for (int e = tid; e < 64 * 128; e += 256){
        int tt = e >> 7, cc = e & 127;
        if (t0 + tt >= HW) continue;
        float acc = bc[cc];
        #pragma unroll
        for (int k = 0; k < 4; k++) acc += xs[(tt + k) * 128 + cc] * wc[k * 128 + cc];
        xbc[(size_t)(t0 + tt) * 512 + c0 + cc] = silu_f(acc);
    }
}

// ---------------- chunk cumsum (wave 0) ----------------
__device__ __forceinline__ void chunk_cumsum_t(const float* __restrict__ dtbT, int t0, int Q,
                                               int h, const float* __restrict__ A_log,
                                               float* cum, float* dth){
    int tid = threadIdx.x;
    if (tid < 64){
        float d = (tid < Q) ? dtbT[h * DTP + t0 + tid] : 0.f;
        dth[tid] = d;
        float A = -expf(A_log[h]);
        float a = d * A;
        #pragma unroll
        for (int off = 1; off < 64; off <<= 1){
            float u = __shfl_up(a, off);
            if (tid >= off) a += u;
        }
        cum[tid] = a;
    }
    __syncthreads();
}

// swizzled (c,h) decode: 4 head-siblings of a chunk share bid%8 -> same XCD L2
__device__ __forceinline__ bool ssd_decode(int bid, int& c, int& h){
    int m = bid & 7, rest = bid >> 3;
    h = rest & 3;
    c = (rest >> 2) * 8 + m;
    return c < NCH;
}

// ---------------- SSD phase A (MFMA, per (c,h), packed-split S out) ----------------
__global__ __launch_bounds__(256) void ssd_phaseA(const float* __restrict__ xbc,
                                                  const float* __restrict__ dtbT,
                                                  const float* __restrict__ A_log,
                                                  unsigned* __restrict__ Sp,
                                                  float* __restrict__ chunkT){
    __shared__ __align__(16) unsigned short BTh[128 * SP], BTl[128 * SP]; // B^T [n][s]
    __shared__ __align__(16) unsigned short XTh[64 * SP],  XTl[64 * SP];  // (Xw)^T [p][s]
    __shared__ float cum[64], dth[64], wln[64];
    int c, h;
    if (!ssd_decode(blockIdx.x, c, h)) return;
    int t0 = c * QC, Q = min(QC, HW - t0);
    int tid = threadIdx.x;
    chunk_cumsum_t(dtbT, t0, Q, h, A_log, cum, dth);
    float T = cum[Q - 1];
    if (tid == 0) chunkT[c * 4 + h] = T;
    if (tid < 64) wln[tid] = (tid < Q) ? __expf(T - cum[tid]) * dth[tid] : 0.f;
    __syncthreads();
    for (int e2 = tid; e2 < 4096; e2 += 256){
        int nn = e2 & 127, sp = e2 >> 7;
        int s0 = 2 * sp;
        float v0 = (s0 < Q)     ? xbc[(size_t)(t0 + s0) * 512 + 256 + nn] : 0.f;
        float v1 = (s0 + 1 < Q) ? xbc[(size_t)(t0 + s0 + 1) * 512 + 256 + nn] : 0.f;
        unsigned short h0, l0, h1, l1;
        bf16_split(v0, h0, l0); bf16_split(v1, h1, l1);
        *reinterpret_cast<unsigned*>(&BTh[nn * SP + s0]) = pack2(h0, h1);
        *reinterpret_cast<unsigned*>(&BTl[nn * SP + s0]) = pack2(l0, l1);
    }
    for (int e2 = tid; e2 < 2048; e2 += 256){
        int pp = e2 & 63, sp = e2 >> 6;
        int s0 = 2 * sp;
        float v0 = (s0 < Q)     ? xbc[(size_t)(t0 + s0) * 512 + h * 64 + pp] * wln[s0] : 0.f;
        float v1 = (s0 + 1 < Q) ? xbc[(size_t)(t0 + s0 + 1) * 512 + h * 64 + pp] * wln[s0 + 1] : 0.f;
        unsigned short h0, l0, h1, l1;
        bf16_split(v0, h0, l0); bf16_split(v1, h1, l1);
        *reinterpret_cast<unsigned*>(&XTh[pp * SP + s0]) = pack2(h0, h1);
        *reinterpret_cast<unsigned*>(&XTl[pp * SP + s0]) = pack2(l0, l1);
    }
    __syncthreads();
    int lane = tid & 63, wid = tid >> 6;
    int wy = wid >> 1, wx = wid & 1;
    int l15 = lane & 15, g = lane >> 4;
    fv4 acc[2][4];
    #pragma unroll
    for (int mi = 0; mi < 2; mi++)
        #pragma unroll
        for (int ni = 0; ni < 4; ni++) acc[mi][ni] = (fv4){0.f,0.f,0.f,0.f};
    #pragma unroll
    for (int ks = 0; ks < 2; ks++){
        short8 ah[2], al[2], bh_[4], bl_[4];
        #pragma unroll
        for (int mi = 0; mi < 2; mi++){
            unsigned off = (wy * 32 + mi * 16 + l15) * SP + ks * 32 + g * 8;
            ah[mi] = *reinterpret_cast<const short8*>(&XTh[off]);
            al[mi] = *reinterpret_cast<const short8*>(&XTl[off]);
        }
        #pragma unroll
        for (int ni = 0; ni < 4; ni++){
            unsigned off = (wx * 64 + ni * 16 + l15) * SP + ks * 32 + g * 8;
            bh_[ni] = *reinterpret_cast<const short8*>(&BTh[off]);
            bl_[ni] = *reinterpret_cast<const short8*>(&BTl[off]);
        }
        #pragma unroll
        for (int mi = 0; mi < 2; mi++)
            #pragma unroll
            for (int ni = 0; ni < 4; ni++){
                acc[mi][ni] = __builtin_amdgcn_mfma_f32_16x16x32_bf16(ah[mi], bh_[ni], acc[mi][ni], 0, 0, 0);
                acc[mi][ni] = __builtin_amdgcn_mfma_f32_16x16x32_bf16(ah[mi], bl_[ni], acc[mi][ni], 0, 0, 0);
                acc[mi][ni] = __builtin_amdgcn_mfma_f32_16x16x32_bf16(al[mi], bh_[ni], acc[mi][ni], 0, 0, 0);
            }
    }
    size_t sb = (size_t)(c * 4 + h) * 8192;
    #pragma unroll
    for (int mi = 0; mi < 2; mi++)
        #pragma unroll
        for (int ni = 0; ni < 4; ni++)
            #pragma unroll
            for (int j = 0; j < 4; j++){
                int p = wy * 32 + mi * 16 + g * 4 + j;
                int n = wx * 64 + ni * 16 + l15;
                Sp[sb + p * 128 + n] = packsplit(acc[mi][ni][j]);
            }
}

// ---------------- SSD phase B: in-place prefix over chunks (packed u32) ------------
__global__ __launch_bounds__(256) void ssd_phaseB(unsigned* __restrict__ Sp,
                                                  const float* __restrict__ chunkT){
    __shared__ float e[NCH];
    int tid = threadIdx.x;
    int idx = blockIdx.x * 256 + tid;
    int h = idx >> 13, pn = idx & 8191;
    for (int c = tid; c < NCH; c += 256) e[c] = __expf(chunkT[c * 4 + h]);
    __syncthreads();
    #define ADDR_(cc) Sp[((size_t)((cc) * 4 + h)) * 8192 + pn]
    unsigned r0 = ADDR_(0), r1 = ADDR_(1), r2 = ADDR_(2), r3 = ADDR_(3);
    float s = 0.f;
    int c = 0;
    for (; c + 8 <= NCH; c += 4){
        unsigned n0 = ADDR_(c + 4), n1 = ADDR_(c + 5), n2 = ADDR_(c + 6), n3 = ADDR_(c + 7);
        ADDR_(c) = packsplit(s);     s = fmaf(s, e[c],     unpackf(r0));
        ADDR_(c + 1) = packsplit(s); s = fmaf(s, e[c + 1], unpackf(r1));
        ADDR_(c + 2) = packsplit(s); s = fmaf(s, e[c + 2], unpackf(r2));
        ADDR_(c + 3) = packsplit(s); s = fmaf(s, e[c + 3], unpackf(r3));
        r0 = n0; r1 = n1; r2 = n2; r3 = n3;
    }
    for (; c < NCH; c++){
        unsigned nx = (c + 4 < NCH) ? ADDR_(c + 4) : 0u;
        float loc = unpackf(r0); r0 = r1; r1 = r2; r2 = r3; r3 = nx;
        ADDR_(c) = packsplit(s);
        s = fmaf(s, e[c], loc);
    }
    #undef ADDR_
}

// ---------------- SSD phase C (MFMA, per (c,h), direct-global C/B/S) ---------------
__global__ __launch_bounds__(256) void ssd_phaseC(const float* __restrict__ xbc,
                                                  const float* __restrict__ dtbT,
                                                  const float* __restrict__ A_log,
                                                  const float* __restrict__ Dvec,
                                                  const unsigned* __restrict__ Sp,
                                                  float* __restrict__ y){
    __shared__ __align__(16) unsigned short U0h[64 * SP], U0l[64 * SP]; // P [t][s]
    __shared__ __align__(16) unsigned short U1h[64 * SP], U1l[64 * SP]; // X^T [p][s]
    __shared__ float cum[64], dth[64];
    int c, h;
    if (!ssd_decode(blockIdx.x, c, h)) return;
    int t0 = c * QC, Q = min(QC, HW - t0);
    int tid = threadIdx.x;
    chunk_cumsum_t(dtbT, t0, Q, h, A_log, cum, dth);
    int lane = tid & 63, wid = tid >> 6;
    int wy = wid >> 1, wx = wid & 1;
    int l15 = lane & 15, g = lane >> 4;

    // row indices (clamped: last chunk would read past xbc; values masked later)
    int trow[2], srow[2], prow[2];
    #pragma unroll
    for (int i = 0; i < 2; i++){
        trow[i] = min(t0 + wy * 32 + i * 16 + l15, HW - 1);
        srow[i] = min(t0 + wx * 32 + i * 16 + l15, HW - 1);
        prow[i] = wx * 32 + i * 16 + l15;           // S row p (always valid)
    }

    fv4 accG[2][2], accA[2][2];
    #pragma unroll
    for (int mi = 0; mi < 2; mi++)
        #pragma unroll
        for (int ni = 0; ni < 2; ni++){ accG[mi][ni] = (fv4){0.f,0.f,0.f,0.f}; accA[mi][ni] = (fv4){0.f,0.f,0.f,0.f}; }

    const unsigned* Sbase = Sp + (size_t)(c * 4 + h) * 8192;
    #pragma unroll
    for (int k0 = 0; k0 < 128; k0 += 32){
        short8 ah[2], al[2], bh[2], bl[2], sh[2], sl[2];
        #pragma unroll
        for (int mi = 0; mi < 2; mi++)
            split8g(xbc + (size_t)trow[mi] * 512 + 384 + k0 + g * 8, ah[mi], al[mi]);
        #pragma unroll
        for (int ni = 0; ni < 2; ni++){
            split8g(xbc + (size_t)srow[ni] * 512 + 256 + k0 + g * 8, bh[ni], bl[ni]);
            unpack8(Sbase + prow[ni] * 128 + k0 + g * 8, sh[ni], sl[ni]);
        }
        #pragma unroll
        for (int mi = 0; mi < 2; mi++)
            #pragma unroll
            for (int ni = 0; ni < 2; ni++){
                accG[mi][ni] = __builtin_amdgcn_mfma_f32_16x16x32_bf16(ah[mi], bh[ni], accG[mi][ni], 0, 0, 0);
                accG[mi][ni] = __builtin_amdgcn_mfma_f32_16x16x32_bf16(ah[mi], bl[ni], accG[mi][ni], 0, 0, 0);
                accG[mi][ni] = __builtin_amdgcn_mfma_f32_16x16x32_bf16(al[mi], bh[ni], accG[mi][ni], 0, 0, 0);
                accA[mi][ni] = __builtin_amdgcn_mfma_f32_16x16x32_bf16(ah[mi], sh[ni], accA[mi][ni], 0, 0, 0);
                accA[mi][ni] = __builtin_amdgcn_mfma_f32_16x16x32_bf16(ah[mi], sl[ni], accA[mi][ni], 0, 0, 0);
                accA[mi][ni] = __builtin_amdgcn_mfma_f32_16x16x32_bf16(al[mi], sh[ni], accA[mi][ni], 0, 0, 0);
            }
    }
    // P = mask(G) * exp(cum_t - cum_s) * dt_s -> U0 [t][s]
    #pragma unroll
    for (int mi = 0; mi < 2; mi++)
        #pragma unroll
        for (int ni = 0; ni < 2; ni++)
            #pragma unroll
            for (int j = 0; j < 4; j++){
                int t = wy * 32 + mi * 16 + g * 4 + j;
                int s = wx * 32 + ni * 16 + l15;
                float pv = 0.f;
                if (s <= t && s < Q)
                    pv = accG[mi][ni][j] * __expf(cum[t] - cum[s]) * dth[s];
                unsigned short hs, ls;
                bf16_split(pv, hs, ls);
                U0h[t * SP + s] = hs;
                U0l[t * SP + s] = ls;
            }
    // stage X^T [p][s] -> U1
    for (int e2 = tid; e2 < 2048; e2 += 256){
        int pp = e2 & 63, sp = e2 >> 6;
        int s0 = 2 * sp;
        float v0 = (s0 < Q)     ? xbc[(size_t)(t0 + s0) * 512 + h * 64 + pp] : 0.f;
        float v1 = (s0 + 1 < Q) ? xbc[(size_t)(t0 + s0 + 1) * 512 + h * 64 + pp] : 0.f;
        unsigned short h0, l0, h1, l1;
        bf16_split(v0, h0, l0); bf16_split(v1, h1, l1);
        *reinterpret_cast<unsigned*>(&U1h[pp * SP + s0]) = pack2(h0, h1);
        *reinterpret_cast<unsigned*>(&U1l[pp * SP + s0]) = pack2(l0, l1);
    }
    __syncthreads();
    // Y = exp(cum_t)*accA + P @ X
    fv4 accY[2][2];
    #pragma unroll
    for (int mi = 0; mi < 2; mi++)
        #pragma unroll
        for (int ni = 0; ni < 2; ni++)
            #pragma unroll
            for (int j = 0; j < 4; j++){
                int t = wy * 32 + mi * 16 + g * 4 + j;
                accY[mi][ni][j] = __expf(cum[t]) * accA[mi][ni][j];
            }
    #pragma unroll
    for (int kk = 0; kk < 2; kk++){
        short8 ph[2], pl[2], xh[2], xl[2];
        #pragma unroll
        for (int mi = 0; mi < 2; mi++){
            unsigned off = (wy * 32 + mi * 16 + l15) * SP + kk * 32 + g * 8;
            ph[mi] = *reinterpret_cast<const short8*>(&U0h[off]);
            pl[mi] = *reinterpret_cast<const short8*>(&U0l[off]);
        }
        #pragma unroll
        for (int ni = 0; ni < 2; ni++){
            unsigned off = (wx * 32 + ni * 16 + l15) * SP + kk * 32 + g * 8;
            xh[ni] = *reinterpret_cast<const short8*>(&U1h[off]);
            xl[ni] = *reinterpret_cast<const short8*>(&U1l[off]);
        }
        #pragma unroll
        for (int mi = 0; mi < 2; mi++)
            #pragma unroll
            for (int ni = 0; ni < 2; ni++){
                accY[mi][ni] = __builtin_amdgcn_mfma_f32_16x16x32_bf16(ph[mi], xh[ni], accY[mi][ni], 0, 0, 0);
                accY[mi][ni] = __builtin_amdgcn_mfma_f32_16x16x32_bf16(ph[mi], xl[ni], accY[mi][ni], 0, 0, 0);
                accY[mi][ni] = __builtin_amdgcn_mfma_f32_16x16x32_bf16(pl[mi], xh[ni], accY[mi][ni], 0, 0, 0);
            }
    }
    float Dh = Dvec[h];
    #pragma unroll
    for (int mi = 0; mi < 2; mi++)
        #pragma unroll
        for (int ni = 0; ni < 2; ni++)
            #pragma unroll
            for (int j = 0; j < 4; j++){
                int t = wy * 32 + mi * 16 + g * 4 + j;
                if (t >= Q) continue;
                int p = wx * 32 + ni * 16 + l15;
                float xv = xbc[(size_t)(t0 + t) * 512 + h * 64 + p];
                y[(size_t)(t0 + t) * 256 + h * 64 + p] = accY[mi][ni][j] + Dh * xv;
            }
}

// ---------------- gated RMSNorm ----------------
__global__ void gated_rms_kernel(float* __restrict__ y, const float* __restrict__ zx,
                                 const float* __restrict__ nw){
    int row = blockIdx.x, tid = threadIdx.x;
    float v = y[(size_t)row * 256 + tid];
    float z = zx[(size_t)row * 772 + tid];
    v *= silu_f(z);
    float s = v * v;
    __shared__ float r1[4];
    #pragma unroll
    for (int o = 32; o > 0; o >>= 1) s += __shfl_down(s, o);
    if ((tid & 63) == 0) r1[tid >> 6] = s;
    __syncthreads();
    float S = r1[0] + r1[1] + r1[2] + r1[3];
    float rs = rsqrtf(S / 256.f + 1e-5f);
    y[(size_t)row * 256 + tid] = v * rs * nw[tid];
}

extern "C" void kernel_launch(void* const* d_in, const int* in_sizes, int n_in,
                              void* d_out, int out_size, void* d_ws, size_t ws_size,
                              hipStream_t stream){
    (void)in_sizes; (void)n_in; (void)out_size; (void)ws_size;
    const float* x        = (const float*)d_in[0];
    const float* ln_pre_g = (const float*)d_in[1];
    const float* ln_pre_b = (const float*)d_in[2];
    const float* fe_w1    = (const float*)d_in[3];
    const float* fe_b1    = (const float*)d_in[4];
    const float* fe_w2    = (const float*)d_in[5];
    const float* fe_b2    = (const float*)d_in[6];
    const float* cv_w1    = (const float*)d_in[7];
    const float* cv_b1    = (const float*)d_in[8];
    const float* cv_w2    = (const float*)d_in[9];
    const float* cv_b2    = (const float*)d_in[10];
    const float* mp_w     = (const float*)d_in[11];
    const float* mp_b     = (const float*)d_in[12];
    const float* mp_ln_g  = (const float*)d_in[13];
    const float* mp_ln_b  = (const float*)d_in[14];
    const float* m_in_w   = (const float*)d_in[15];
    const float* m_conv_w = (const float*)d_in[16];
    const float* m_conv_b = (const float*)d_in[17];
    const float* m_dtb    = (const float*)d_in[18];
    const float* m_A_log  = (const float*)d_in[19];
    const float* m_D      = (const float*)d_in[20];
    const float* m_norm_w = (const float*)d_in[21];
    const float* m_out_w  = (const float*)d_in[22];
    const float* cls_ln_g = (const float*)d_in[23];
    const float* cls_ln_b = (const float*)d_in[24];
    const float* cls_w1   = (const float*)d_in[25];
    const float* cls_b1   = (const float*)d_in[26];
    const float* cls_w2   = (const float*)d_in[27];
    const float* cls_b2   = (const float*)d_in[28];
    const float* cls_w3   = (const float*)d_in[29];
    const float* cls_b3   = (const float*)d_in[30];

    float* ws   = (float*)d_ws;
    float* xn   = ws + OFF_XN;
    float* f1   = ws + OFF_F1;
    float* comb = ws + OFF_COMB;
    float* p    = ws + OFF_P;
    float* zx   = ws + OFF_ZX;
    float* xbc  = ws + OFF_XBC;
    unsigned* Sp = (unsigned*)(ws + OFF_S);
    float* dtbT = ws + OFF_DT;
    float* chkT = ws + OFF_CT;
    float* c1h  = ws + OFF_XBC;                    // before xbc live
    float* c2h  = ws + OFF_XBC + 691488;
    float* pr   = ws + OFF_XN;
    float* ybuf = ws + OFF_F1;
    float* mo   = ws + OFF_COMB;
    float* cls0 = ws + OFF_XN;
    float* cls1 = ws + OFF_P;
    float* cls2 = ws + OFF_COMB + 2691200;
    unsigned short* W1h = (unsigned short*)(ws + OFF_W);
    unsigned short* W1l = (unsigned short*)(ws + OFF_W + 32256);
    unsigned short* W2h = (unsigned short*)(ws + OFF_W + 64512);
    unsigned short* W2l = (unsigned short*)(ws + OFF_W + 73728);

    // 0. conv weight prepack (tiny)
    prep_w<200, 32, 7><<<(32 * 2016 + 255) / 256, 256, 0, stream>>>(cv_w1, W1h, W1l);
    prep_w<32, 64, 1><<<(64 * 288 + 255) / 256, 256, 0, stream>>>(cv_w2, W2h, W2l);
    // 1. pre-LN
    ln_kernel<0><<<HW, 256, 0, stream>>>(x, ln_pre_g, ln_pre_b, xn, NBANDS);
    // 2-3. feature MLP (f -> comb[:, :128], ldc=192)
    gemm_mfma<1><<<dim3(4, 165), 256, 0, stream>>>(xn, 200, fe_w1, fe_b1, f1, 256, HW, 256, 200);
    gemm_mfma<1><<<dim3(2, 165), 256, 0, stream>>>(f1, 256, fe_w2, fe_b2, comb, 192, HW, 128, 256);
    // 4. conv1 (MFMA implicit-im2col): 200->32, pad 2
    conv_mfma<200, 32, 2, 7, 1><<<dim3(3, CONVH), 256, 0, stream>>>(xn, Hdim, Wdim, W1h, W1l, cv_b1, c1h);
    // 5. conv2 (MFMA): 32->64, pad 1
    conv_mfma<32, 64, 1, 1, 2><<<dim3(3, CONVH), 256, 0, stream>>>(c1h, CONVH, CONVH, W2h, W2l, cv_b2, c2h);
    // 6. adaptive pool -> comb[:, 128:192]
    pool_kernel<<<(HW * 64 + 255) / 256, 256, 0, stream>>>(c2h, comb);
    // 7-8. mid projection + LN + GELU
    gemm_mfma<0><<<dim3(2, 165), 256, 0, stream>>>(comb, 192, mp_w, mp_b, pr, 128, HW, 128, 192);
    ln_kernel<1><<<HW, 256, 0, stream>>>(pr, mp_ln_g, mp_ln_b, p, 128);
    // 9. mamba in_proj
    gemm_mfma<0><<<dim3(13, 165), 256, 0, stream>>>(p, 128, m_in_w, (const float*)nullptr, zx, 772, HW, 772, 128);
    // 10. dt softplus (transposed [h][t])
    dt_kernel<<<dim3((HW + 255) / 256, 4), 256, 0, stream>>>(zx, m_dtb, dtbT);
    // 11. depthwise causal conv + silu (tiled)
    conv1d_tiled<<<dim3(4, NCH), 256, 0, stream>>>(zx, m_conv_w, m_conv_b, xbc);
    // 12-14. SSD chunked scan (MFMA, xcd-sibling swizzled)
    ssd_phaseA<<<SSD_GRID, 256, 0, stream>>>(xbc, dtbT, m_A_log, Sp, chkT);
    ssd_phaseB<<<128, 256, 0, stream>>>(Sp, chkT);
    ssd_phaseC<<<SSD_GRID, 256, 0, stream>>>(xbc, dtbT, m_A_log, m_D, Sp, ybuf);
    // 15. gated RMSNorm
    gated_rms_kernel<<<HW, 256, 0, stream>>>(ybuf, zx, m_norm_w);
    // 16. out proj
    gemm_mfma<0><<<dim3(2, 165), 256, 0, stream>>>(ybuf, 256, m_out_w, (const float*)nullptr, mo, 128, HW, 128, 256);
    // 17-20. classifier
    ln_kernel<0><<<HW, 256, 0, stream>>>(mo, cls_ln_g, cls_ln_b, cls0, 128);
    gemm_mfma<1><<<dim3(2, 165), 256, 0, stream>>>(cls0, 128, cls_w1, cls_b1, cls1, 128, HW, 128, 128);
    gemm_mfma<1><<<dim3(1, 165), 256, 0, stream>>>(cls1, 128, cls_w2, cls_b2, cls2, 64, HW, 64, 128);
    gemm_mfma<0><<<dim3(1, 165), 256, 0, stream>>>(cls2, 64, cls_w3, cls_b3, (float*)d_out, 17, HW, 17, 64);
}

// Round 8
// 504.052 us; speedup vs baseline: 1.0335x; 1.0286x over previous
//
#include <hip/hip_runtime.h>
#include <math.h>

#define HW 21025        // 145*145
#define Hdim 145
#define Wdim 145
#define NBANDS 200
#define CONVH 147
#define CONVHW 21609    // 147*147
#define QC 64
#define NCH 329         // ceil(21025/64)
#define DTP 21056       // padded L for transposed dt
#define SP 72           // short stride for [.][64-k] MFMA tiles
#define SSD_GRID 1344   // 8 * 4 * 42 (xcd-sibling swizzled, tail-guarded)
#define NYB165 165      // row-blocks for M=21025 at BM=128

typedef __attribute__((ext_vector_type(4))) float fv4;
typedef __attribute__((ext_vector_type(8))) short short8;

// ---------------- workspace layout (float offsets) ----------------
#define OFF_XN   ((size_t)0)           // 4,205,000  xn; later pr, cls0
#define OFF_F1   ((size_t)4205000)     // 5,382,400  f1; later y (L x 256)
#define OFF_COMB ((size_t)9587400)     // 4,036,800  comb L x 192; later mo + cls2
#define OFF_P    ((size_t)13624200)    // 2,691,200  p; later cls1
#define OFF_ZX   ((size_t)16315400)    // 16,231,300 zxbcdt L x 772
#define OFF_XBC  ((size_t)32546700)    // 10,764,800 c1h+c2h first, then xbc packed u32
#define OFF_S    ((size_t)43311500)    // 10,780,672 S packed u32 (bf16 hi|lo)
#define OFF_DT   ((size_t)54092172)    // 84,224 (dt transposed [4][DTP])
#define OFF_CT   ((size_t)54176396)    // 1,316
#define OFF_W    ((size_t)54177712)    // 82,944: packed conv weights (bf16 hi/lo)

__device__ __forceinline__ float gelu_f(float x){
    return 0.5f * x * (1.0f + erff(x * 0.70710678118654752440f));
}
__device__ __forceinline__ float silu_f(float x){
    return x / (1.0f + expf(-x));
}

__device__ __forceinline__ void bf16_split(float x, unsigned short& hs, unsigned short& ls){
    unsigned u = __float_as_uint(x);
    hs = (unsigned short)(u >> 16);
    float hif = __uint_as_float(u & 0xFFFF0000u);
    float lof = x - hif;
    ls = (unsigned short)(__float_as_uint(lof) >> 16);
}
__device__ __forceinline__ unsigned pack2(unsigned short a, unsigned short b){
    return (unsigned)a | ((unsigned)b << 16);
}
// f32 -> (hi<<16)|lo packed split
__device__ __forceinline__ unsigned packsplit(float x){
    unsigned short hs, ls;
    bf16_split(x, hs, ls);
    return ((unsigned)hs << 16) | (unsigned)ls;
}
__device__ __forceinline__ float unpackf(unsigned u){
    return __uint_as_float(u & 0xFFFF0000u) + __uint_as_float(u << 16);
}
// load 8 consecutive f32 from global, split into hi/lo short8
__device__ __forceinline__ void split8g(const float* p, short8& h8, short8& l8){
    fv4 v0 = *reinterpret_cast<const fv4*>(p);
    fv4 v1 = *reinterpret_cast<const fv4*>(p + 4);
    unsigned short hs, ls;
    #pragma unroll
    for (int j = 0; j < 4; j++){
        bf16_split(v0[j], hs, ls); h8[j] = (short)hs; l8[j] = (short)ls;
        bf16_split(v1[j], hs, ls); h8[4 + j] = (short)hs; l8[4 + j] = (short)ls;
    }
}
// load 8 packed u32, unpack to hi/lo short8 (shifts only)
__device__ __forceinline__ void unpack8(const unsigned* p, short8& h8, short8& l8){
    uint4 a = *reinterpret_cast<const uint4*>(p);
    uint4 b = *reinterpret_cast<const uint4*>(p + 4);
    unsigned v0 = a.x, v1 = a.y, v2 = a.z, v3 = a.w;
    unsigned v4 = b.x, v5 = b.y, v6 = b.z, v7 = b.w;
    h8[0]=(short)(v0>>16); l8[0]=(short)(v0&0xFFFFu);
    h8[1]=(short)(v1>>16); l8[1]=(short)(v1&0xFFFFu);
    h8[2]=(short)(v2>>16); l8[2]=(short)(v2&0xFFFFu);
    h8[3]=(short)(v3>>16); l8[3]=(short)(v3&0xFFFFu);
    h8[4]=(short)(v4>>16); l8[4]=(short)(v4&0xFFFFu);
    h8[5]=(short)(v5>>16); l8[5]=(short)(v5&0xFFFFu);
    h8[6]=(short)(v6>>16); l8[6]=(short)(v6&0xFFFFu);
    h8[7]=(short)(v7>>16); l8[7]=(short)(v7&0xFFFFu);
}

// XCD-grouped decode: all NXB col-blocks of one row-group share bid%8 -> same XCD L2
__device__ __forceinline__ bool gemm_decode(int bid, int NXB, int NYB, int& bx, int& by){
    int m = bid & 7;
    int r = bid >> 3;
    bx = r % NXB;
    by = (r / NXB) * 8 + m;
    return by < NYB;
}
__host__ __forceinline__ int gemm_grid(int NXB, int NYB){ return 8 * ((NYB + 7) / 8) * NXB; }

// ---------------- LayerNorm (+ optional GELU) ----------------
template<int ACT>
__global__ void ln_kernel(const float* __restrict__ in, const float* __restrict__ g,
                          const float* __restrict__ b, float* __restrict__ out, int D){
    int row = blockIdx.x, tid = threadIdx.x;
    const float* r = in + (size_t)row * D;
    float s = 0.f, s2 = 0.f;
    for (int i = tid; i < D; i += 256){ float v = r[i]; s += v; s2 += v*v; }
    __shared__ float r1[4], r2[4];
    #pragma unroll
    for (int o = 32; o > 0; o >>= 1){ s += __shfl_down(s, o); s2 += __shfl_down(s2, o); }
    if ((tid & 63) == 0){ r1[tid >> 6] = s; r2[tid >> 6] = s2; }
    __syncthreads();
    float S = r1[0] + r1[1] + r1[2] + r1[3];
    float S2 = r2[0] + r2[1] + r2[2] + r2[3];
    float mean = S / (float)D;
    float var = S2 / (float)D - mean * mean;
    float rs = rsqrtf(fmaxf(var, 0.f) + 1e-5f);
    float* o_ = out + (size_t)row * D;
    for (int i = tid; i < D; i += 256){
        float v = (r[i] - mean) * rs * g[i] + b[i];
        if (ACT == 1) v = gelu_f(v);
        o_[i] = v;
    }
}

// ---------------- split-bf16 MFMA GEMM (XCD-grouped 1D grid) ----------------
template<int ACT>
__global__ __launch_bounds__(256) void gemm_mfma(const float* __restrict__ A, int lda,
                                                 const float* __restrict__ B,
                                                 const float* __restrict__ bias,
                                                 float* __restrict__ C, int ldc,
                                                 int M, int N, int K, int NXB, int NYB){
    const int SA = 40;
    __shared__ __align__(16) unsigned short Ah[128 * SA], Al[128 * SA];
    __shared__ __align__(16) unsigned short Bh[64 * SA],  Bl[64 * SA];
    int bx, by;
    if (!gemm_decode(blockIdx.x, NXB, NYB, bx, by)) return;
    int tid = threadIdx.x;
    int lane = tid & 63, wid = tid >> 6;
    int wy = wid >> 1, wx = wid & 1;
    int bm = by * 128, bn = bx * 64;
    int l15 = lane & 15, g = lane >> 4;

    fv4 acc[4][2];
    #pragma unroll
    for (int i = 0; i < 4; i++)
        #pragma unroll
        for (int j = 0; j < 2; j++) acc[i][j] = (fv4){0.f,0.f,0.f,0.f};

    int am = tid >> 1;
    int aq = (tid & 1) * 4;
    bool arow_ok = (bm + am) < M;
    int bn_t = tid & 63;
    int bk8 = (tid >> 6) * 8;
    bool bcol_ok = (bn + bn_t) < N;

    int nK = (K + 31) / 32;
    for (int ks = 0; ks < nK; ks++){
        int k0 = ks * 32;
        const float* Ap = A + (size_t)(bm + am) * lda + k0;
        #pragma unroll
        for (int f = 0; f < 4; f++){
            int kq = aq + f;
            fv4 v = (fv4){0.f,0.f,0.f,0.f};
            if (arow_ok && (k0 + kq * 4 + 4) <= K)
                v = *reinterpret_cast<const fv4*>(Ap + kq * 4);
            unsigned short hs[4], ls[4];
            #pragma unroll
            for (int j = 0; j < 4; j++) bf16_split(v[j], hs[j], ls[j]);
            unsigned off = am * SA + kq * 4;
            *reinterpret_cast<uint2*>(&Ah[off]) = make_uint2(pack2(hs[0],hs[1]), pack2(hs[2],hs[3]));
            *reinterpret_cast<uint2*>(&Al[off]) = make_uint2(pack2(ls[0],ls[1]), pack2(ls[2],ls[3]));
        }
        {
            unsigned short hs[8], ls[8];
            #pragma unroll
            for (int j = 0; j < 8; j++){
                int kk = k0 + bk8 + j;
                float v = (bcol_ok && kk < K) ? B[(size_t)kk * N + bn + bn_t] : 0.f;
                bf16_split(v, hs[j], ls[j]);
            }
            unsigned off = bn_t * SA + bk8;
            *reinterpret_cast<uint4*>(&Bh[off]) = make_uint4(pack2(hs[0],hs[1]), pack2(hs[2],hs[3]),
                                                             pack2(hs[4],hs[5]), pack2(hs[6],hs[7]));
            *reinterpret_cast<uint4*>(&Bl[off]) = make_uint4(pack2(ls[0],ls[1]), pack2(ls[2],ls[3]),
                                                             pack2(ls[4],ls[5]), pack2(ls[6],ls[7]));
        }
        __syncthreads();
        short8 afh[4], afl[4], bfh[2], bfl[2];
        #pragma unroll
        for (int mi = 0; mi < 4; mi++){
            unsigned off = (wy * 64 + mi * 16 + l15) * SA + g * 8;
            afh[mi] = *reinterpret_cast<const short8*>(&Ah[off]);
            afl[mi] = *reinterpret_cast<const short8*>(&Al[off]);
        }
        #pragma unroll
        for (int ni = 0; ni < 2; ni++){
            unsigned off = (wx * 32 + ni * 16 + l15) * SA + g * 8;
            bfh[ni] = *reinterpret_cast<const short8*>(&Bh[off]);
            bfl[ni] = *reinterpret_cast<const short8*>(&Bl[off]);
        }
        #pragma unroll
        for (int mi = 0; mi < 4; mi++)
            #pragma unroll
            for (int ni = 0; ni < 2; ni++){
                acc[mi][ni] = __builtin_amdgcn_mfma_f32_16x16x32_bf16(afh[mi], bfh[ni], acc[mi][ni], 0, 0, 0);
                acc[mi][ni] = __builtin_amdgcn_mfma_f32_16x16x32_bf16(afh[mi], bfl[ni], acc[mi][ni], 0, 0, 0);
                acc[mi][ni] = __builtin_amdgcn_mfma_f32_16x16x32_bf16(afl[mi], bfh[ni], acc[mi][ni], 0, 0, 0);
            }
        __syncthreads();
    }
    #pragma unroll
    for (int mi = 0; mi < 4; mi++){
        #pragma unroll
        for (int ni = 0; ni < 2; ni++){
            int cc = bn + wx * 32 + ni * 16 + l15;
            if (cc >= N) continue;
            float bv = bias ? bias[cc] : 0.f;
            #pragma unroll
            for (int j = 0; j < 4; j++){
                int rr = bm + wy * 64 + mi * 16 + g * 4 + j;
                if (rr >= M) continue;
                float v = acc[mi][ni][j] + bv;
                if (ACT == 1) v = gelu_f(v);
                C[(size_t)rr * ldc + cc] = v;
            }
        }
    }
}

// ---------------- conv weight prepack ----------------
template<int IC, int OC, int NCHUNK>
__global__ void prep_w(const float* __restrict__ w, unsigned short* __restrict__ Wh,
                       unsigned short* __restrict__ Wl){
    const int KP = NCHUNK * 288;
    int idx = blockIdx.x * 256 + threadIdx.x;
    if (idx >= OC * KP) return;
    int o = idx / KP, k = idx % KP;
    int ch = k / 288, rest = k % 288, t = rest / 32, c = rest & 31;
    int ci = ch * 32 + c;
    float v = (ci < IC) ? w[((size_t)o * IC + ci) * 9 + t] : 0.f;
    unsigned short hs, ls;
    bf16_split(v, hs, ls);
    Wh[idx] = hs; Wl[idx] = ls;
}

// ---------------- MFMA direct conv 3x3 (implicit im2col in LDS) -------------------
template<int IC, int OC, int PAD, int NCHUNK, int NFRAG>
__global__ __launch_bounds__(256) void conv_mfma(const float* __restrict__ in,
                                                 int inH, int inW,
                                                 const unsigned short* __restrict__ Wh,
                                                 const unsigned short* __restrict__ Wl,
                                                 const float* __restrict__ bias,
                                                 float* __restrict__ out){
    const int KP = NCHUNK * 288;
    const int CST = 40;
    __shared__ __align__(16) unsigned short Xh[3 * 68 * CST], Xl[3 * 68 * CST];
    int y = blockIdx.y;
    int x0 = blockIdx.x * 64;
    int tid = threadIdx.x;
    int lane = tid & 63, wid = tid >> 6;
    int wy = wid >> 1, wx = wid & 1;
    int l15 = lane & 15, g = lane >> 4;

    fv4 acc[2][NFRAG];
    #pragma unroll
    for (int mi = 0; mi < 2; mi++)
        #pragma unroll
        for (int ni = 0; ni < NFRAG; ni++) acc[mi][ni] = (fv4){0.f,0.f,0.f,0.f};

    for (int ch = 0; ch < NCHUNK; ch++){
        int ci0 = ch * 32;
        if (ch > 0) __syncthreads();
        for (int e = tid; e < 3 * 68 * 8; e += 256){
            int qd = e & 7;
            int c  = (e >> 3) % 68;
            int r  = e / 544;
            int iy = y - PAD + r, ix = x0 - PAD + c;
            fv4 v = (fv4){0.f,0.f,0.f,0.f};
            if ((unsigned)iy < (unsigned)inH && (unsigned)ix < (unsigned)inW &&
                (ci0 + qd * 4 + 4) <= IC)
                v = *reinterpret_cast<const fv4*>(in + ((size_t)iy * inW + ix) * IC + ci0 + qd * 4);
            unsigned short hs[4], ls[4];
            #pragma unroll
            for (int j = 0; j < 4; j++) bf16_split(v[j], hs[j], ls[j]);
            unsigned off = (r * 68 + c) * CST + qd * 4;
            *reinterpret_cast<uint2*>(&Xh[off]) = make_uint2(pack2(hs[0],hs[1]), pack2(hs[2],hs[3]));
            *reinterpret_cast<uint2*>(&Xl[off]) = make_uint2(pack2(ls[0],ls[1]), pack2(ls[2],ls[3]));
        }
        __syncthreads();
        #pragma unroll
        for (int t = 0; t < 9; t++){
            int ky = t / 3, kx = t % 3;
            short8 ah[2], al[2], bh[NFRAG], bl[NFRAG];
            #pragma unroll
            for (int mi = 0; mi < 2; mi++){
                unsigned off = (ky * 68 + wy * 32 + mi * 16 + l15 + kx) * CST + g * 8;
                ah[mi] = *reinterpret_cast<const short8*>(&Xh[off]);
                al[mi] = *reinterpret_cast<const short8*>(&Xl[off]);
            }
            #pragma unroll
            for (int ni = 0; ni < NFRAG; ni++){
                int oc = wx * (16 * NFRAG) + ni * 16 + l15;
                size_t woff = (size_t)oc * KP + ch * 288 + t * 32 + g * 8;
                bh[ni] = *reinterpret_cast<const short8*>(&Wh[woff]);
                bl[ni] = *reinterpret_cast<const short8*>(&Wl[woff]);
            }
            #pragma unroll
            for (int mi = 0; mi < 2; mi++)
                #pragma unroll
                for (int ni = 0; ni < NFRAG; ni++){
                    acc[mi][ni] = __builtin_amdgcn_mfma_f32_16x16x32_bf16(ah[mi], bh[ni], acc[mi][ni], 0, 0, 0);
                    acc[mi][ni] = __builtin_amdgcn_mfma_f32_16x16x32_bf16(ah[mi], bl[ni], acc[mi][ni], 0, 0, 0);
                    acc[mi][ni] = __builtin_amdgcn_mfma_f32_16x16x32_bf16(al[mi], bh[ni], acc[mi][ni], 0, 0, 0);
                }
        }
    }
    #pragma unroll
    for (int mi = 0; mi < 2; mi++)
        #pragma unroll
        for (int ni = 0; ni < NFRAG; ni++){
            int oc = wx * (16 * NFRAG) + ni * 16 + l15;
            float bv = bias[oc];
            #pragma unroll
            for (int j = 0; j < 4; j++){
                int x = x0 + wy * 32 + mi * 16 + g * 4 + j;
                if (x >= CONVH) continue;
                out[((size_t)y * CONVH + x) * OC + oc] = gelu_f(acc[mi][ni][j] + bv);
            }
        }
}

// ---------------- adaptive pool HWC into comb[:,128:] ----------------
__global__ void pool_kernel(const float* __restrict__ c2, float* __restrict__ comb){
    int idx = blockIdx.x * 256 + threadIdx.x;
    if (idx >= HW * 64) return;
    int o = idx & 63;
    int pix = idx >> 6;
    int xo = pix % Wdim, yo = pix / Wdim;
    int ys = yo * CONVH / Hdim, ye = ((yo + 1) * CONVH + Hdim - 1) / Hdim;
    int xs = xo * CONVH / Wdim, xe = ((xo + 1) * CONVH + Wdim - 1) / Wdim;
    float s = 0.f;
    for (int yy = ys; yy < ye; yy++)
        for (int xx = xs; xx < xe; xx++)
            s += c2[((size_t)yy * CONVH + xx) * 64 + o];
    comb[(size_t)pix * 192 + 128 + o] = s / (float)((ye - ys) * (xe - xs));
}

// ---------------- dt = softplus(raw + bias), transposed out [h][t] ----------------
__global__ void dt_kernel(const float* __restrict__ zx, const float* __restrict__ dt_bias,
                          float* __restrict__ dtbT){
    int t = blockIdx.x * 256 + threadIdx.x;
    int h = blockIdx.y;
    if (t >= HW) return;
    float v = zx[(size_t)t * 772 + 768 + h] + dt_bias[h];
    dtbT[h * DTP + t] = (v > 20.f) ? v : log1pf(expf(v));
}

// ---------------- depthwise causal conv1d (width 4) + silu -> packed u32 ------------
__global__ __launch_bounds__(256) void conv1d_tiled(const float* __restrict__ zx,
                                                    const float* __restrict__ w,
                                                    const float* __restrict__ b,
                                                    unsigned* __restrict__ xbcp){
    __shared__ float xs[67 * 128];
    __shared__ float wc[4 * 128];
    __shared__ float bc[128];
    int t0 = blockIdx.y * 64;
    int c0 = blockIdx.x * 128;
    int tid = threadIdx.x;
    for (int e = tid; e < 67 * 128; e += 256){
        int rr = e >> 7, cc = e & 127;
        int t = t0 - 3 + rr;
        xs[e] = (t >= 0 && t < HW) ? zx[(size_t)t * 772 + 256 + c0 + cc] : 0.f;
    }
    if (tid < 128){
        bc[tid] = b[c0 + tid];
        #pragma unroll
        for (int k = 0; k < 4; k++) wc[k * 128 + tid] = w[(c0 + tid) * 4 + k];
    }
    __syncthreads();
    for (int e = tid; e < 64 * 128; e += 256){
        int tt = e >> 7, cc = e & 127;
        if (t0 + tt >= HW) continue;
        float acc = bc[cc];
        #pragma unroll
        for (int k = 0; k < 4; k++) acc += xs[(tt + k) * 128 + cc] * wc[k * 128 + cc];
        xbcp[(size_t)(t0 + tt) * 512 + c0 + cc] = packsplit(silu_f(acc));
    }
}

// ---------------- chunk cumsum (wave 0) ----------------
__device__ __forceinline__ void chunk_cumsum_t(const float* __restrict__ dtbT, int t0, int Q,
                                               int h, const float* __restrict__ A_log,
                                               float* cum, float* dth){
    int tid = threadIdx.x;
    if (tid < 64){
        float d = (tid < Q) ? dtbT[h * DTP + t0 + tid] : 0.f;
        dth[tid] = d;
        float A = -expf(A_log[h]);
        float a = d * A;
        #pragma unroll
        for (int off = 1; off < 64; off <<= 1){
            float u = __shfl_up(a, off);
            if (tid >= off) a += u;
        }
        cum[tid] = a;
    }
    __syncthreads();
}

// swizzled (c,h) decode: 4 head-siblings of a chunk share bid%8 -> same XCD L2
__device__ __forceinline__ bool ssd_decode(int bid, int& c, int& h){
    int m = bid & 7, rest = bid >> 3;
    h = rest & 3;
    c = (rest >> 2) * 8 + m;
    return c < NCH;
}

// ---------------- SSD phase A (MFMA, per (c,h), packed in/out) ----------------
__global__ __launch_bounds__(256) void ssd_phaseA(const unsigned* __restrict__ xbcp,
                                                  const float* __restrict__ dtbT,
                                                  const float* __restrict__ A_log,
                                                  unsigned* __restrict__ Sp,
                                                  float* __restrict__ chunkT){
    __shared__ __align__(16) unsigned short BTh[128 * SP], BTl[128 * SP]; // B^T [n][s]
    __shared__ __align__(16) unsigned short XTh[64 * SP],  XTl[64 * SP];  // (Xw)^T [p][s]
    __shared__ float cum[64], dth[64], wln[64];
    int c, h;
    if (!ssd_decode(blockIdx.x, c, h)) return;
    int t0 = c * QC, Q = min(QC, HW - t0);
    int tid = threadIdx.x;
    chunk_cumsum_t(dtbT, t0, Q, h, A_log, cum, dth);
    float T = cum[Q - 1];
    if (tid == 0) chunkT[c * 4 + h] = T;
    if (tid < 64) wln[tid] = (tid < Q) ? __expf(T - cum[tid]) * dth[tid] : 0.f;
    __syncthreads();
    for (int e2 = tid; e2 < 4096; e2 += 256){
        int nn = e2 & 127, sp = e2 >> 7;
        int s0 = 2 * sp;
        unsigned v0 = (s0 < Q)     ? xbcp[(size_t)(t0 + s0) * 512 + 256 + nn] : 0u;
        unsigned v1 = (s0 + 1 < Q) ? xbcp[(size_t)(t0 + s0 + 1) * 512 + 256 + nn] : 0u;
        *reinterpret_cast<unsigned*>(&BTh[nn * SP + s0]) = pack2((unsigned short)(v0 >> 16), (unsigned short)(v1 >> 16));
        *reinterpret_cast<unsigned*>(&BTl[nn * SP + s0]) = pack2((unsigned short)(v0 & 0xFFFFu), (unsigned short)(v1 & 0xFFFFu));
    }
    for (int e2 = tid; e2 < 2048; e2 += 256){
        int pp = e2 & 63, sp = e2 >> 6;
        int s0 = 2 * sp;
        float v0 = (s0 < Q)     ? unpackf(xbcp[(size_t)(t0 + s0) * 512 + h * 64 + pp]) * wln[s0] : 0.f;
        float v1 = (s0 + 1 < Q) ? unpackf(xbcp[(size_t)(t0 + s0 + 1) * 512 + h * 64 + pp]) * wln[s0 + 1] : 0.f;
        unsigned short h0, l0, h1, l1;
        bf16_split(v0, h0, l0); bf16_split(v1, h1, l1);
        *reinterpret_cast<unsigned*>(&XTh[pp * SP + s0]) = pack2(h0, h1);
        *reinterpret_cast<unsigned*>(&XTl[pp * SP + s0]) = pack2(l0, l1);
    }
    __syncthreads();
    int lane = tid & 63, wid = tid >> 6;
    int wy = wid >> 1, wx = wid & 1;
    int l15 = lane & 15, g = lane >> 4;
    fv4 acc[2][4];
    #pragma unroll
    for (int mi = 0; mi < 2; mi++)
        #pragma unroll
        for (int ni = 0; ni < 4; ni++) acc[mi][ni] = (fv4){0.f,0.f,0.f,0.f};
    #pragma unroll
    for (int ks = 0; ks < 2; ks++){
        short8 ah[2], al[2], bh_[4], bl_[4];
        #pragma unroll
        for (int mi = 0; mi < 2; mi++){
            unsigned off = (wy * 32 + mi * 16 + l15) * SP + ks * 32 + g * 8;
            ah[mi] = *reinterpret_cast<const short8*>(&XTh[off]);
            al[mi] = *reinterpret_cast<const short8*>(&XTl[off]);
        }
        #pragma unroll
        for (int ni = 0; ni < 4; ni++){
            unsigned off = (wx * 64 + ni * 16 + l15) * SP + ks * 32 + g * 8;
            bh_[ni] = *reinterpret_cast<const short8*>(&BTh[off]);
            bl_[ni] = *reinterpret_cast<const short8*>(&BTl[off]);
        }
        #pragma unroll
        for (int mi = 0; mi < 2; mi++)
            #pragma unroll
            for (int ni = 0; ni < 4; ni++){
                acc[mi][ni] = __builtin_amdgcn_mfma_f32_16x16x32_bf16(ah[mi], bh_[ni], acc[mi][ni], 0, 0, 0);
                acc[mi][ni] = __builtin_amdgcn_mfma_f32_16x16x32_bf16(ah[mi], bl_[ni], acc[mi][ni], 0, 0, 0);
                acc[mi][ni] = __builtin_amdgcn_mfma_f32_16x16x32_bf16(al[mi], bh_[ni], acc[mi][ni], 0, 0, 0);
            }
    }
    size_t sb = (size_t)(c * 4 + h) * 8192;
    #pragma unroll
    for (int mi = 0; mi < 2; mi++)
        #pragma unroll
        for (int ni = 0; ni < 4; ni++)
            #pragma unroll
            for (int j = 0; j < 4; j++){
                int p = wy * 32 + mi * 16 + g * 4 + j;
                int n = wx * 64 + ni * 16 + l15;
                Sp[sb + p * 128 + n] = packsplit(acc[mi][ni][j]);
            }
}

// ---------------- SSD phase B: in-place prefix over chunks (packed u32) ------------
__global__ __launch_bounds__(256) void ssd_phaseB(unsigned* __restrict__ Sp,
                                                  const float* __restrict__ chunkT){
    __shared__ float e[NCH];
    int tid = threadIdx.x;
    int idx = blockIdx.x * 256 + tid;
    int h = idx >> 13, pn = idx & 8191;
    for (int c = tid; c < NCH; c += 256) e[c] = __expf(chunkT[c * 4 + h]);
    __syncthreads();
    #define ADDR_(cc) Sp[((size_t)((cc) * 4 + h)) * 8192 + pn]
    unsigned r0 = ADDR_(0), r1 = ADDR_(1), r2 = ADDR_(2), r3 = ADDR_(3);
    float s = 0.f;
    int c = 0;
    for (; c + 8 <= NCH; c += 4){
        unsigned n0 = ADDR_(c + 4), n1 = ADDR_(c + 5), n2 = ADDR_(c + 6), n3 = ADDR_(c + 7);
        ADDR_(c) = packsplit(s);     s = fmaf(s, e[c],     unpackf(r0));
        ADDR_(c + 1) = packsplit(s); s = fmaf(s, e[c + 1], unpackf(r1));
        ADDR_(c + 2) = packsplit(s); s = fmaf(s, e[c + 2], unpackf(r2));
        ADDR_(c + 3) = packsplit(s); s = fmaf(s, e[c + 3], unpackf(r3));
        r0 = n0; r1 = n1; r2 = n2; r3 = n3;
    }
    for (; c < NCH; c++){
        unsigned nx = (c + 4 < NCH) ? ADDR_(c + 4) : 0u;
        float loc = unpackf(r0); r0 = r1; r1 = r2; r2 = r3; r3 = nx;
        ADDR_(c) = packsplit(s);
        s = fmaf(s, e[c], loc);
    }
    #undef ADDR_
}

// ---------------- SSD phase C (MFMA, per (c,h), packed direct-global) ---------------
__global__ __launch_bounds__(256) void ssd_phaseC(const unsigned* __restrict__ xbcp,
                                                  const float* __restrict__ dtbT,
                                                  const float* __restrict__ A_log,
                                                  const float* __restrict__ Dvec,
                                                  const unsigned* __restrict__ Sp,
                                                  float* __restrict__ y){
    __shared__ __align__(16) unsigned short U0h[64 * SP], U0l[64 * SP]; // P [t][s]
    __shared__ __align__(16) unsigned short U1h[64 * SP], U1l[64 * SP]; // X^T [p][s]
    __shared__ float cum[64], dth[64];
    int c, h;
    if (!ssd_decode(blockIdx.x, c, h)) return;
    int t0 = c * QC, Q = min(QC, HW - t0);
    int tid = threadIdx.x;
    chunk_cumsum_t(dtbT, t0, Q, h, A_log, cum, dth);
    int lane = tid & 63, wid = tid >> 6;
    int wy = wid >> 1, wx = wid & 1;
    int l15 = lane & 15, g = lane >> 4;

    int trow[2], srow[2], prow[2];
    #pragma unroll
    for (int i = 0; i < 2; i++){
        trow[i] = min(t0 + wy * 32 + i * 16 + l15, HW - 1);
        srow[i] = min(t0 + wx * 32 + i * 16 + l15, HW - 1);
        prow[i] = wx * 32 + i * 16 + l15;
    }

    fv4 accG[2][2], accA[2][2];
    #pragma unroll
    for (int mi = 0; mi < 2; mi++)
        #pragma unroll
        for (int ni = 0; ni < 2; ni++){ accG[mi][ni] = (fv4){0.f,0.f,0.f,0.f}; accA[mi][ni] = (fv4){0.f,0.f,0.f,0.f}; }

    const unsigned* Sbase = Sp + (size_t)(c * 4 + h) * 8192;
    #pragma unroll
    for (int k0 = 0; k0 < 128; k0 += 32){
        short8 ah[2], al[2], bh[2], bl[2], sh[2], sl[2];
        #pragma unroll
        for (int mi = 0; mi < 2; mi++)
            unpack8(xbcp + (size_t)trow[mi] * 512 + 384 + k0 + g * 8, ah[mi], al[mi]);
        #pragma unroll
        for (int ni = 0; ni < 2; ni++){
            unpack8(xbcp + (size_t)srow[ni] * 512 + 256 + k0 + g * 8, bh[ni], bl[ni]);
            unpack8(Sbase + prow[ni] * 128 + k0 + g * 8, sh[ni], sl[ni]);
        }
        #pragma unroll
        for (int mi = 0; mi < 2; mi++)
            #pragma unroll
            for (int ni = 0; ni < 2; ni++){
                accG[mi][ni] = __builtin_amdgcn_mfma_f32_16x16x32_bf16(ah[mi], bh[ni], accG[mi][ni], 0, 0, 0);
                accG[mi][ni] = __builtin_amdgcn_mfma_f32_16x16x32_bf16(ah[mi], bl[ni], accG[mi][ni], 0, 0, 0);
                accG[mi][ni] = __builtin_amdgcn_mfma_f32_16x16x32_bf16(al[mi], bh[ni], accG[mi][ni], 0, 0, 0);
                accA[mi][ni] = __builtin_amdgcn_mfma_f32_16x16x32_bf16(ah[mi], sh[ni], accA[mi][ni], 0, 0, 0);
                accA[mi][ni] = __builtin_amdgcn_mfma_f32_16x16x32_bf16(ah[mi], sl[ni], accA[mi][ni], 0, 0, 0);
                accA[mi][ni] = __builtin_amdgcn_mfma_f32_16x16x32_bf16(al[mi], sh[ni], accA[mi][ni], 0, 0, 0);
            }
    }
    // P = mask(G) * exp(cum_t - cum_s) * dt_s -> U0 [t][s]
    #pragma unroll
    for (int mi = 0; mi < 2; mi++)
        #pragma unroll
        for (int ni = 0; ni < 2; ni++)
            #pragma unroll
            for (int j = 0; j < 4; j++){
                int t = wy * 32 + mi * 16 + g * 4 + j;
                int s = wx * 32 + ni * 16 + l15;
                float pv = 0.f;
                if (s <= t && s < Q)
                    pv = accG[mi][ni][j] * __expf(cum[t] - cum[s]) * dth[s];
                unsigned short hs, ls;
                bf16_split(pv, hs, ls);
                U0h[t * SP + s] = hs;
                U0l[t * SP + s] = ls;
            }
    // stage X^T [p][s] -> U1 (pure shifts from packed)
    for (int e2 = tid; e2 < 2048; e2 += 256){
        int pp = e2 & 63, sp = e2 >> 6;
        int s0 = 2 * sp;
        unsigned v0 = (s0 < Q)     ? xbcp[(size_t)(t0 + s0) * 512 + h * 64 + pp] : 0u;
        unsigned v1 = (s0 + 1 < Q) ? xbcp[(size_t)(t0 + s0 + 1) * 512 + h * 64 + pp] : 0u;
        *reinterpret_cast<unsigned*>(&U1h[pp * SP + s0]) = pack2((unsigned short)(v0 >> 16), (unsigned short)(v1 >> 16));
        *reinterpret_cast<unsigned*>(&U1l[pp * SP + s0]) = pack2((unsigned short)(v0 & 0xFFFFu), (unsigned short)(v1 & 0xFFFFu));
    }
    __syncthreads();
    // Y = exp(cum_t)*accA + P @ X
    fv4 accY[2][2];
    #pragma unroll
    for (int mi = 0; mi < 2; mi++)
        #pragma unroll
        for (int ni = 0; ni < 2; ni++)
            #pragma unroll
            for (int j = 0; j < 4; j++){
                int t = wy * 32 + mi * 16 + g * 4 + j;
                accY[mi][ni][j] = __expf(cum[t]) * accA[mi][ni][j];
            }
    #pragma unroll
    for (int kk = 0; kk < 2; kk++){
        short8 ph[2], pl[2], xh[2], xl[2];
        #pragma unroll
        for (int mi = 0; mi < 2; mi++){
            unsigned off = (wy * 32 + mi * 16 + l15) * SP + kk * 32 + g * 8;
            ph[mi] = *reinterpret_cast<const short8*>(&U0h[off]);
            pl[mi] = *reinterpret_cast<const short8*>(&U0l[off]);
        }
        #pragma unroll
        for (int ni = 0; ni < 2; ni++){
            unsigned off = (wx * 32 + ni * 16 + l15) * SP + kk * 32 + g * 8;
            xh[ni] = *reinterpret_cast<const short8*>(&U1h[off]);
            xl[ni] = *reinterpret_cast<const short8*>(&U1l[off]);
        }
        #pragma unroll
        for (int mi = 0; mi < 2; mi++)
            #pragma unroll
            for (int ni = 0; ni < 2; ni++){
                accY[mi][ni] = __builtin_amdgcn_mfma_f32_16x16x32_bf16(ph[mi], xh[ni], accY[mi][ni], 0, 0, 0);
                accY[mi][ni] = __builtin_amdgcn_mfma_f32_16x16x32_bf16(ph[mi], xl[ni], accY[mi][ni], 0, 0, 0);
                accY[mi][ni] = __builtin_amdgcn_mfma_f32_16x16x32_bf16(pl[mi], xh[ni], accY[mi][ni], 0, 0, 0);
            }
    }
    float Dh = Dvec[h];
    #pragma unroll
    for (int mi = 0; mi < 2; mi++)
        #pragma unroll
        for (int ni = 0; ni < 2; ni++)
            #pragma unroll
            for (int j = 0; j < 4; j++){
                int t = wy * 32 + mi * 16 + g * 4 + j;
                if (t >= Q) continue;
                int p = wx * 32 + ni * 16 + l15;
                float xv = unpackf(xbcp[(size_t)(t0 + t) * 512 + h * 64 + p]);
                y[(size_t)(t0 + t) * 256 + h * 64 + p] = accY[mi][ni][j] + Dh * xv;
            }
}

// ---------------- gated RMSNorm ----------------
__global__ void gated_rms_kernel(float* __restrict__ y, const float* __restrict__ zx,
                                 const float* __restrict__ nw){
    int row = blockIdx.x, tid = threadIdx.x;
    float v = y[(size_t)row * 256 + tid];
    float z = zx[(size_t)row * 772 + tid];
    v *= silu_f(z);
    float s = v * v;
    __shared__ float r1[4];
    #pragma unroll
    for (int o = 32; o > 0; o >>= 1) s += __shfl_down(s, o);
    if ((tid & 63) == 0) r1[tid >> 6] = s;
    __syncthreads();
    float S = r1[0] + r1[1] + r1[2] + r1[3];
    float rs = rsqrtf(S / 256.f + 1e-5f);
    y[(size_t)row * 256 + tid] = v * rs * nw[tid];
}

extern "C" void kernel_launch(void* const* d_in, const int* in_sizes, int n_in,
                              void* d_out, int out_size, void* d_ws, size_t ws_size,
                              hipStream_t stream){
    (void)in_sizes; (void)n_in; (void)out_size; (void)ws_size;
    const float* x        = (const float*)d_in[0];
    const float* ln_pre_g = (const float*)d_in[1];
    const float* ln_pre_b = (const float*)d_in[2];
    const float* fe_w1    = (const float*)d_in[3];
    const float* fe_b1    = (const float*)d_in[4];
    const float* fe_w2    = (const float*)d_in[5];
    const float* fe_b2    = (const float*)d_in[6];
    const float* cv_w1    = (const float*)d_in[7];
    const float* cv_b1    = (const float*)d_in[8];
    const float* cv_w2    = (const float*)d_in[9];
    const float* cv_b2    = (const float*)d_in[10];
    const float* mp_w     = (const float*)d_in[11];
    const float* mp_b     = (const float*)d_in[12];
    const float* mp_ln_g  = (const float*)d_in[13];
    const float* mp_ln_b  = (const float*)d_in[14];
    const float* m_in_w   = (const float*)d_in[15];
    const float* m_conv_w = (const float*)d_in[16];
    const float* m_conv_b = (const float*)d_in[17];
    const float* m_dtb    = (const float*)d_in[18];
    const float* m_A_log  = (const float*)d_in[19];
    const float* m_D      = (const float*)d_in[20];
    const float* m_norm_w = (const float*)d_in[21];
    const float* m_out_w  = (const float*)d_in[22];
    const float* cls_ln_g = (const float*)d_in[23];
    const float* cls_ln_b = (const float*)d_in[24];
    const float* cls_w1   = (const float*)d_in[25];
    const float* cls_b1   = (const float*)d_in[26];
    const float* cls_w2   = (const float*)d_in[27];
    const float* cls_b2   = (const float*)d_in[28];
    const float* cls_w3   = (const float*)d_in[29];
    const float* cls_b3   = (const float*)d_in[30];

    float* ws   = (float*)d_ws;
    float* xn   = ws + OFF_XN;
    float* f1   = ws + OFF_F1;
    float* comb = ws + OFF_COMB;
    float* p    = ws + OFF_P;
    float* zx   = ws + OFF_ZX;
    unsigned* xbcp = (unsigned*)(ws + OFF_XBC);
    unsigned* Sp = (unsigned*)(ws + OFF_S);
    float* dtbT = ws + OFF_DT;
    float* chkT = ws + OFF_CT;
    float* c1h  = ws + OFF_XBC;                    // before xbcp live
    float* c2h  = ws + OFF_XBC + 691488;
    float* pr   = ws + OFF_XN;
    float* ybuf = ws + OFF_F1;
    float* mo   = ws + OFF_COMB;
    float* cls0 = ws + OFF_XN;
    float* cls1 = ws + OFF_P;
    float* cls2 = ws + OFF_COMB + 2691200;
    unsigned short* W1h = (unsigned short*)(ws + OFF_W);
    unsigned short* W1l = (unsigned short*)(ws + OFF_W + 32256);
    unsigned short* W2h = (unsigned short*)(ws + OFF_W + 64512);
    unsigned short* W2l = (unsigned short*)(ws + OFF_W + 73728);

    // 0. conv weight prepack (tiny)
    prep_w<200, 32, 7><<<(32 * 2016 + 255) / 256, 256, 0, stream>>>(cv_w1, W1h, W1l);
    prep_w<32, 64, 1><<<(64 * 288 + 255) / 256, 256, 0, stream>>>(cv_w2, W2h, W2l);
    // 1. pre-LN
    ln_kernel<0><<<HW, 256, 0, stream>>>(x, ln_pre_g, ln_pre_b, xn, NBANDS);
    // 2-3. feature MLP (f -> comb[:, :128], ldc=192)
    gemm_mfma<1><<<gemm_grid(4, NYB165), 256, 0, stream>>>(xn, 200, fe_w1, fe_b1, f1, 256, HW, 256, 200, 4, NYB165);
    gemm_mfma<1><<<gemm_grid(2, NYB165), 256, 0, stream>>>(f1, 256, fe_w2, fe_b2, comb, 192, HW, 128, 256, 2, NYB165);
    // 4. conv1 (MFMA implicit-im2col): 200->32, pad 2
    conv_mfma<200, 32, 2, 7, 1><<<dim3(3, CONVH), 256, 0, stream>>>(xn, Hdim, Wdim, W1h, W1l, cv_b1, c1h);
    // 5. conv2 (MFMA): 32->64, pad 1
    conv_mfma<32, 64, 1, 1, 2><<<dim3(3, CONVH), 256, 0, stream>>>(c1h, CONVH, CONVH, W2h, W2l, cv_b2, c2h);
    // 6. adaptive pool -> comb[:, 128:192]
    pool_kernel<<<(HW * 64 + 255) / 256, 256, 0, stream>>>(c2h, comb);
    // 7-8. mid projection + LN + GELU
    gemm_mfma<0><<<gemm_grid(2, NYB165), 256, 0, stream>>>(comb, 192, mp_w, mp_b, pr, 128, HW, 128, 192, 2, NYB165);
    ln_kernel<1><<<HW, 256, 0, stream>>>(pr, mp_ln_g, mp_ln_b, p, 128);
    // 9. mamba in_proj
    gemm_mfma<0><<<gemm_grid(13, NYB165), 256, 0, stream>>>(p, 128, m_in_w, (const float*)nullptr, zx, 772, HW, 772, 128, 13, NYB165);
    // 10. dt softplus (transposed [h][t])
    dt_kernel<<<dim3((HW + 255) / 256, 4), 256, 0, stream>>>(zx, m_dtb, dtbT);
    // 11. depthwise causal conv + silu -> packed u32
    conv1d_tiled<<<dim3(4, NCH), 256, 0, stream>>>(zx, m_conv_w, m_conv_b, xbcp);
    // 12-14. SSD chunked scan (MFMA, xcd-sibling swizzled, packed)
    ssd_phaseA<<<SSD_GRID, 256, 0, stream>>>(xbcp, dtbT, m_A_log, Sp, chkT);
    ssd_phaseB<<<128, 256, 0, stream>>>(Sp, chkT);
    ssd_phaseC<<<SSD_GRID, 256, 0, stream>>>(xbcp, dtbT, m_A_log, m_D, Sp, ybuf);
    // 15. gated RMSNorm
    gated_rms_kernel<<<HW, 256, 0, stream>>>(ybuf, zx, m_norm_w);
    // 16. out proj
    gemm_mfma<0><<<gemm_grid(2, NYB165), 256, 0, stream>>>(ybuf, 256, m_out_w, (const float*)nullptr, mo, 128, HW, 128, 256, 2, NYB165);
    // 17-20. classifier
    ln_kernel<0><<<HW, 256, 0, stream>>>(mo, cls_ln_g, cls_ln_b, cls0, 128);
    gemm_mfma<1><<<gemm_grid(2, NYB165), 256, 0, stream>>>(cls0, 128, cls_w1, cls_b1, cls1, 128, HW, 128, 128, 2, NYB165);
    gemm_mfma<1><<<gemm_grid(1, NYB165), 256, 0, stream>>>(cls1, 128, cls_w2, cls_b2, cls2, 64, HW, 64, 128, 1, NYB165);
    gemm_mfma<0><<<gemm_grid(1, NYB165), 256, 0, stream>>>(cls2, 64, cls_w3, cls_b3, (float*)d_out, 17, HW, 17, 64, 1, NYB165);
}

// Round 9
// 474.887 us; speedup vs baseline: 1.0970x; 1.0614x over previous
//
#include <hip/hip_runtime.h>
#include <math.h>

#define HW 21025        // 145*145
#define Hdim 145
#define Wdim 145
#define NBANDS 200
#define CONVH 147
#define CONVHW 21609    // 147*147
#define QC 64
#define NCH 329         // ceil(21025/64)
#define DTP 21056       // padded L for transposed dt
#define SP 72           // short stride for [.][64-k] MFMA tiles
#define SSD_GRID 1344   // 8 * 4 * 42 (xcd-sibling swizzled, tail-guarded)

typedef __attribute__((ext_vector_type(4))) float fv4;
typedef __attribute__((ext_vector_type(8))) short short8;

// ---------------- workspace layout (float offsets) ----------------
#define OFF_XN   ((size_t)0)           // 4,205,000  xn; later cls0
#define OFF_F1   ((size_t)4205000)     // 5,382,400  f1; later y (L x 256)
#define OFF_COMB ((size_t)9587400)     // 4,036,800  comb L x 192; later cls2
#define OFF_P    ((size_t)13624200)    // 2,691,200  p; later cls1
#define OFF_ZX   ((size_t)16315400)    // 16,231,300 zxbcdt L x 772
#define OFF_XBC  ((size_t)32546700)    // 10,764,800 c1h+c2h first, then xbc packed u32
#define OFF_S    ((size_t)43311500)    // 10,780,672 S packed u32 (bf16 hi|lo)
#define OFF_DT   ((size_t)54092172)    // 84,224 (dt transposed [4][DTP])
#define OFF_CT   ((size_t)54176396)    // 1,316
#define OFF_W    ((size_t)54177712)    // 82,944: packed conv weights (bf16 hi/lo)

__device__ __forceinline__ float gelu_f(float x){
    return 0.5f * x * (1.0f + erff(x * 0.70710678118654752440f));
}
__device__ __forceinline__ float silu_f(float x){
    return x / (1.0f + expf(-x));
}

__device__ __forceinline__ void bf16_split(float x, unsigned short& hs, unsigned short& ls){
    unsigned u = __float_as_uint(x);
    hs = (unsigned short)(u >> 16);
    float hif = __uint_as_float(u & 0xFFFF0000u);
    float lof = x - hif;
    ls = (unsigned short)(__float_as_uint(lof) >> 16);
}
__device__ __forceinline__ unsigned pack2(unsigned short a, unsigned short b){
    return (unsigned)a | ((unsigned)b << 16);
}
__device__ __forceinline__ unsigned packsplit(float x){
    unsigned short hs, ls;
    bf16_split(x, hs, ls);
    return ((unsigned)hs << 16) | (unsigned)ls;
}
__device__ __forceinline__ float unpackf(unsigned u){
    return __uint_as_float(u & 0xFFFF0000u) + __uint_as_float(u << 16);
}
__device__ __forceinline__ void split8g(const float* p, short8& h8, short8& l8){
    fv4 v0 = *reinterpret_cast<const fv4*>(p);
    fv4 v1 = *reinterpret_cast<const fv4*>(p + 4);
    unsigned short hs, ls;
    #pragma unroll
    for (int j = 0; j < 4; j++){
        bf16_split(v0[j], hs, ls); h8[j] = (short)hs; l8[j] = (short)ls;
        bf16_split(v1[j], hs, ls); h8[4 + j] = (short)hs; l8[4 + j] = (short)ls;
    }
}
__device__ __forceinline__ void unpack8(const unsigned* p, short8& h8, short8& l8){
    uint4 a = *reinterpret_cast<const uint4*>(p);
    uint4 b = *reinterpret_cast<const uint4*>(p + 4);
    unsigned v0 = a.x, v1 = a.y, v2 = a.z, v3 = a.w;
    unsigned v4 = b.x, v5 = b.y, v6 = b.z, v7 = b.w;
    h8[0]=(short)(v0>>16); l8[0]=(short)(v0&0xFFFFu);
    h8[1]=(short)(v1>>16); l8[1]=(short)(v1&0xFFFFu);
    h8[2]=(short)(v2>>16); l8[2]=(short)(v2&0xFFFFu);
    h8[3]=(short)(v3>>16); l8[3]=(short)(v3&0xFFFFu);
    h8[4]=(short)(v4>>16); l8[4]=(short)(v4&0xFFFFu);
    h8[5]=(short)(v5>>16); l8[5]=(short)(v5&0xFFFFu);
    h8[6]=(short)(v6>>16); l8[6]=(short)(v6&0xFFFFu);
    h8[7]=(short)(v7>>16); l8[7]=(short)(v7&0xFFFFu);
}

// XCD-grouped decode: all NXB col-blocks of one row-group share bid%8 -> same XCD L2
__device__ __forceinline__ bool gemm_decode(int bid, int NXB, int NYB, int& bx, int& by){
    int m = bid & 7;
    int r = bid >> 3;
    bx = r % NXB;
    by = (r / NXB) * 8 + m;
    return by < NYB;
}
__host__ __forceinline__ int gemm_grid(int NXB, int NYB){ return 8 * ((NYB + 7) / 8) * NXB; }

// ---------------- LayerNorm (pre-LN only) ----------------
template<int ACT>
__global__ void ln_kernel(const float* __restrict__ in, const float* __restrict__ g,
                          const float* __restrict__ b, float* __restrict__ out, int D){
    int row = blockIdx.x, tid = threadIdx.x;
    const float* r = in + (size_t)row * D;
    float s = 0.f, s2 = 0.f;
    for (int i = tid; i < D; i += 256){ float v = r[i]; s += v; s2 += v*v; }
    __shared__ float r1[4], r2[4];
    #pragma unroll
    for (int o = 32; o > 0; o >>= 1){ s += __shfl_down(s, o); s2 += __shfl_down(s2, o); }
    if ((tid & 63) == 0){ r1[tid >> 6] = s; r2[tid >> 6] = s2; }
    __syncthreads();
    float S = r1[0] + r1[1] + r1[2] + r1[3];
    float S2 = r2[0] + r2[1] + r2[2] + r2[3];
    float mean = S / (float)D;
    float var = S2 / (float)D - mean * mean;
    float rs = rsqrtf(fmaxf(var, 0.f) + 1e-5f);
    float* o_ = out + (size_t)row * D;
    for (int i = tid; i < D; i += 256){
        float v = (r[i] - mean) * rs * g[i] + b[i];
        if (ACT == 1) v = gelu_f(v);
        o_[i] = v;
    }
}

// ---------------- wide split-bf16 MFMA GEMM: BN=128, BM=MI*32 ----------------
// ACT: 0 none, 1 gelu, 2 LN, 3 LN+gelu (LN requires N==128, NXB==1)
template<int ACT, int MI>
__global__ __launch_bounds__(256) void gemm_mfma_w(const float* __restrict__ A, int lda,
                                                   const float* __restrict__ B, int ldb,
                                                   const float* __restrict__ bias,
                                                   const float* __restrict__ lng,
                                                   const float* __restrict__ lnb,
                                                   float* __restrict__ C, int ldc,
                                                   int M, int N, int K, int NXB, int NYB){
    const int SA = 40;
    const int BM = MI * 32;
    __shared__ __align__(16) unsigned short Ah[BM * SA], Al[BM * SA];
    __shared__ __align__(16) unsigned short Bh[128 * SA], Bl[128 * SA];
    __shared__ float rs1[2][BM], rs2_[2][BM];
    int bx, by;
    if (!gemm_decode(blockIdx.x, NXB, NYB, bx, by)) return;
    int tid = threadIdx.x;
    int lane = tid & 63, wid = tid >> 6;
    int wy = wid >> 1, wx = wid & 1;
    int bm = by * BM, bn = bx * 128;
    int l15 = lane & 15, g = lane >> 4;

    fv4 acc[MI][4];
    #pragma unroll
    for (int i = 0; i < MI; i++)
        #pragma unroll
        for (int j = 0; j < 4; j++) acc[i][j] = (fv4){0.f,0.f,0.f,0.f};

    int bcol = tid & 127;
    int bk16 = (tid >> 7) * 16;
    bool bcol_ok = (bn + bcol) < N;

    int nK = (K + 31) / 32;
    for (int ks = 0; ks < nK; ks++){
        int k0 = ks * 32;
        // ---- stage A: BM rows x 32 k ----
        #pragma unroll
        for (int f = 0; f < MI; f++){
            int idx = tid * MI + f;
            int row = idx >> 3, qd = idx & 7;
            fv4 v = (fv4){0.f,0.f,0.f,0.f};
            if ((bm + row) < M && (k0 + qd * 4 + 4) <= K)
                v = *reinterpret_cast<const fv4*>(A + (size_t)(bm + row) * lda + k0 + qd * 4);
            unsigned short hs[4], ls[4];
            #pragma unroll
            for (int j = 0; j < 4; j++) bf16_split(v[j], hs[j], ls[j]);
            unsigned off = row * SA + qd * 4;
            *reinterpret_cast<uint2*>(&Ah[off]) = make_uint2(pack2(hs[0],hs[1]), pack2(hs[2],hs[3]));
            *reinterpret_cast<uint2*>(&Al[off]) = make_uint2(pack2(ls[0],ls[1]), pack2(ls[2],ls[3]));
        }
        // ---- stage B: 128 cols x 32 k (transposed [col][k]) ----
        {
            unsigned short hs[16], ls[16];
            #pragma unroll
            for (int j = 0; j < 16; j++){
                int kk = k0 + bk16 + j;
                float v = (bcol_ok && kk < K) ? B[(size_t)kk * ldb + bn + bcol] : 0.f;
                bf16_split(v, hs[j], ls[j]);
            }
            unsigned off = bcol * SA + bk16;
            *reinterpret_cast<uint4*>(&Bh[off]) = make_uint4(pack2(hs[0],hs[1]), pack2(hs[2],hs[3]),
                                                             pack2(hs[4],hs[5]), pack2(hs[6],hs[7]));
            *reinterpret_cast<uint4*>(&Bh[off + 8]) = make_uint4(pack2(hs[8],hs[9]), pack2(hs[10],hs[11]),
                                                                 pack2(hs[12],hs[13]), pack2(hs[14],hs[15]));
            *reinterpret_cast<uint4*>(&Bl[off]) = make_uint4(pack2(ls[0],ls[1]), pack2(ls[2],ls[3]),
                                                             pack2(ls[4],ls[5]), pack2(ls[6],ls[7]));
            *reinterpret_cast<uint4*>(&Bl[off + 8]) = make_uint4(pack2(ls[8],ls[9]), pack2(ls[10],ls[11]),
                                                                 pack2(ls[12],ls[13]), pack2(ls[14],ls[15]));
        }
        __syncthreads();
        short8 afh[MI], afl[MI], bfh[4], bfl[4];
        #pragma unroll
        for (int mi = 0; mi < MI; mi++){
            unsigned off = (wy * (MI * 16) + mi * 16 + l15) * SA + g * 8;
            afh[mi] = *reinterpret_cast<const short8*>(&Ah[off]);
            afl[mi] = *reinterpret_cast<const short8*>(&Al[off]);
        }
        #pragma unroll
        for (int ni = 0; ni < 4; ni++){
            unsigned off = (wx * 64 + ni * 16 + l15) * SA + g * 8;
            bfh[ni] = *reinterpret_cast<const short8*>(&Bh[off]);
            bfl[ni] = *reinterpret_cast<const short8*>(&Bl[off]);
        }
        #pragma unroll
        for (int mi = 0; mi < MI; mi++)
            #pragma unroll
            for (int ni = 0; ni < 4; ni++){
                acc[mi][ni] = __builtin_amdgcn_mfma_f32_16x16x32_bf16(afh[mi], bfh[ni], acc[mi][ni], 0, 0, 0);
                acc[mi][ni] = __builtin_amdgcn_mfma_f32_16x16x32_bf16(afh[mi], bfl[ni], acc[mi][ni], 0, 0, 0);
                acc[mi][ni] = __builtin_amdgcn_mfma_f32_16x16x32_bf16(afl[mi], bfh[ni], acc[mi][ni], 0, 0, 0);
            }
        __syncthreads();
    }
    // per-col params
    float bv[4], lgv[4], lbv[4];
    #pragma unroll
    for (int ni = 0; ni < 4; ni++){
        int cc = bn + wx * 64 + ni * 16 + l15;
        bool ok = cc < N;
        bv[ni]  = (bias && ok) ? bias[cc] : 0.f;
        if (ACT >= 2){ lgv[ni] = ok ? lng[cc] : 1.f; lbv[ni] = ok ? lnb[cc] : 0.f; }
    }
    if (ACT >= 2){
        // fused row-LN: partials -> shfl reduce over l15 -> LDS combine over wx
        #pragma unroll
        for (int mi = 0; mi < MI; mi++)
            #pragma unroll
            for (int j = 0; j < 4; j++){
                float s = 0.f, s2 = 0.f;
                #pragma unroll
                for (int ni = 0; ni < 4; ni++){
                    float v = acc[mi][ni][j] + bv[ni];
                    s += v; s2 += v * v;
                }
                #pragma unroll
                for (int o = 1; o < 16; o <<= 1){
                    s += __shfl_xor(s, o); s2 += __shfl_xor(s2, o);
                }
                int row = wy * (MI * 16) + mi * 16 + g * 4 + j;
                if (l15 == 0){ rs1[wx][row] = s; rs2_[wx][row] = s2; }
            }
        __syncthreads();
        #pragma unroll
        for (int mi = 0; mi < MI; mi++)
            #pragma unroll
            for (int j = 0; j < 4; j++){
                int row = wy * (MI * 16) + mi * 16 + g * 4 + j;
                int rr = bm + row;
                if (rr >= M) continue;
                float S = rs1[0][row] + rs1[1][row];
                float S2 = rs2_[0][row] + rs2_[1][row];
                float mean = S / 128.f;
                float var = S2 / 128.f - mean * mean;
                float rsq = rsqrtf(fmaxf(var, 0.f) + 1e-5f);
                #pragma unroll
                for (int ni = 0; ni < 4; ni++){
                    int cc = bn + wx * 64 + ni * 16 + l15;
                    float v = acc[mi][ni][j] + bv[ni];
                    v = (v - mean) * rsq * lgv[ni] + lbv[ni];
                    if (ACT == 3) v = gelu_f(v);
                    C[(size_t)rr * ldc + cc] = v;
                }
            }
    } else {
        #pragma unroll
        for (int mi = 0; mi < MI; mi++)
            #pragma unroll
            for (int ni = 0; ni < 4; ni++){
                int cc = bn + wx * 64 + ni * 16 + l15;
                if (cc >= N) continue;
                #pragma unroll
                for (int j = 0; j < 4; j++){
                    int rr = bm + wy * (MI * 16) + mi * 16 + g * 4 + j;
                    if (rr >= M) continue;
                    float v = acc[mi][ni][j] + bv[ni];
                    if (ACT == 1) v = gelu_f(v);
                    C[(size_t)rr * ldc + cc] = v;
                }
            }
    }
}

// ---------------- narrow split-bf16 MFMA GEMM (BN=64) for small-N tails ------------
template<int ACT>
__global__ __launch_bounds__(256) void gemm_mfma(const float* __restrict__ A, int lda,
                                                 const float* __restrict__ B,
                                                 const float* __restrict__ bias,
                                                 float* __restrict__ C, int ldc,
                                                 int M, int N, int K, int NXB, int NYB){
    const int SA = 40;
    __shared__ __align__(16) unsigned short Ah[128 * SA], Al[128 * SA];
    __shared__ __align__(16) unsigned short Bh[64 * SA],  Bl[64 * SA];
    int bx, by;
    if (!gemm_decode(blockIdx.x, NXB, NYB, bx, by)) return;
    int tid = threadIdx.x;
    int lane = tid & 63, wid = tid >> 6;
    int wy = wid >> 1, wx = wid & 1;
    int bm = by * 128, bn = bx * 64;
    int l15 = lane & 15, g = lane >> 4;

    fv4 acc[4][2];
    #pragma unroll
    for (int i = 0; i < 4; i++)
        #pragma unroll
        for (int j = 0; j < 2; j++) acc[i][j] = (fv4){0.f,0.f,0.f,0.f};

    int am = tid >> 1;
    int aq = (tid & 1) * 4;
    bool arow_ok = (bm + am) < M;
    int bn_t = tid & 63;
    int bk8 = (tid >> 6) * 8;
    bool bcol_ok = (bn + bn_t) < N;

    int nK = (K + 31) / 32;
    for (int ks = 0; ks < nK; ks++){
        int k0 = ks * 32;
        const float* Ap = A + (size_t)(bm + am) * lda + k0;
        #pragma unroll
        for (int f = 0; f < 4; f++){
            int kq = aq + f;
            fv4 v = (fv4){0.f,0.f,0.f,0.f};
            if (arow_ok && (k0 + kq * 4 + 4) <= K)
                v = *reinterpret_cast<const fv4*>(Ap + kq * 4);
            unsigned short hs[4], ls[4];
            #pragma unroll
            for (int j = 0; j < 4; j++) bf16_split(v[j], hs[j], ls[j]);
            unsigned off = am * SA + kq * 4;
            *reinterpret_cast<uint2*>(&Ah[off]) = make_uint2(pack2(hs[0],hs[1]), pack2(hs[2],hs[3]));
            *reinterpret_cast<uint2*>(&Al[off]) = make_uint2(pack2(ls[0],ls[1]), pack2(ls[2],ls[3]));
        }
        {
            unsigned short hs[8], ls[8];
            #pragma unroll
            for (int j = 0; j < 8; j++){
                int kk = k0 + bk8 + j;
                float v = (bcol_ok && kk < K) ? B[(size_t)kk * N + bn + bn_t] : 0.f;
                bf16_split(v, hs[j], ls[j]);
            }
            unsigned off = bn_t * SA + bk8;
            *reinterpret_cast<uint4*>(&Bh[off]) = make_uint4(pack2(hs[0],hs[1]), pack2(hs[2],hs[3]),
                                                             pack2(hs[4],hs[5]), pack2(hs[6],hs[7]));
            *reinterpret_cast<uint4*>(&Bl[off]) = make_uint4(pack2(ls[0],ls[1]), pack2(ls[2],ls[3]),
                                                             pack2(ls[4],ls[5]), pack2(ls[6],ls[7]));
        }
        __syncthreads();
        short8 afh[4], afl[4], bfh[2], bfl[2];
        #pragma unroll
        for (int mi = 0; mi < 4; mi++){
            unsigned off = (wy * 64 + mi * 16 + l15) * SA + g * 8;
            afh[mi] = *reinterpret_cast<const short8*>(&Ah[off]);
            afl[mi] = *reinterpret_cast<const short8*>(&Al[off]);
        }
        #pragma unroll
        for (int ni = 0; ni < 2; ni++){
            unsigned off = (wx * 32 + ni * 16 + l15) * SA + g * 8;
            bfh[ni] = *reinterpret_cast<const short8*>(&Bh[off]);
            bfl[ni] = *reinterpret_cast<const short8*>(&Bl[off]);
        }
        #pragma unroll
        for (int mi = 0; mi < 4; mi++)
            #pragma unroll
            for (int ni = 0; ni < 2; ni++){
                acc[mi][ni] = __builtin_amdgcn_mfma_f32_16x16x32_bf16(afh[mi], bfh[ni], acc[mi][ni], 0, 0, 0);
                acc[mi][ni] = __builtin_amdgcn_mfma_f32_16x16x32_bf16(afh[mi], bfl[ni], acc[mi][ni], 0, 0, 0);
                acc[mi][ni] = __builtin_amdgcn_mfma_f32_16x16x32_bf16(afl[mi], bfh[ni], acc[mi][ni], 0, 0, 0);
            }
        __syncthreads();
    }
    #pragma unroll
    for (int mi = 0; mi < 4; mi++){
        #pragma unroll
        for (int ni = 0; ni < 2; ni++){
            int cc = bn + wx * 32 + ni * 16 + l15;
            if (cc >= N) continue;
            float bv = bias ? bias[cc] : 0.f;
            #pragma unroll
            for (int j = 0; j < 4; j++){
                int rr = bm + wy * 64 + mi * 16 + g * 4 + j;
                if (rr >= M) continue;
                float v = acc[mi][ni][j] + bv;
                if (ACT == 1) v = gelu_f(v);
                C[(size_t)rr * ldc + cc] = v;
            }
        }
    }
}

// ---------------- dt from p: dtbT[h][t] = softplus(p[t]·w_dt[:,h] + dt_bias[h]) ----
__global__ __launch_bounds__(256) void dt_from_p(const float* __restrict__ p,
                                                 const float* __restrict__ w,
                                                 const float* __restrict__ dtb,
                                                 float* __restrict__ dtbT){
    __shared__ float wl[512];
    int tid = threadIdx.x;
    for (int i = tid; i < 512; i += 256){
        int k = i >> 2, h = i & 3;
        wl[i] = w[(size_t)k * 772 + 768 + h];
    }
    __syncthreads();
    int t = blockIdx.x * 64 + (tid >> 2);
    int h = tid & 3;
    if (t >= HW) return;
    const float* pr = p + (size_t)t * 128;
    float s = 0.f;
    for (int k = 0; k < 128; k += 4){
        fv4 v = *reinterpret_cast<const fv4*>(pr + k);
        s += v[0]*wl[k*4+h] + v[1]*wl[(k+1)*4+h] + v[2]*wl[(k+2)*4+h] + v[3]*wl[(k+3)*4+h];
    }
    s += dtb[h];
    dtbT[h * DTP + t] = (s > 20.f) ? s : log1pf(expf(s));
}

// ---------------- conv weight prepack ----------------
template<int IC, int OC, int NCHUNK>
__global__ void prep_w(const float* __restrict__ w, unsigned short* __restrict__ Wh,
                       unsigned short* __restrict__ Wl){
    const int KP = NCHUNK * 288;
    int idx = blockIdx.x * 256 + threadIdx.x;
    if (idx >= OC * KP) return;
    int o = idx / KP, k = idx % KP;
    int ch = k / 288, rest = k % 288, t = rest / 32, c = rest & 31;
    int ci = ch * 32 + c;
    float v = (ci < IC) ? w[((size_t)o * IC + ci) * 9 + t] : 0.f;
    unsigned short hs, ls;
    bf16_split(v, hs, ls);
    Wh[idx] = hs; Wl[idx] = ls;
}

// ---------------- MFMA direct conv 3x3 (implicit im2col in LDS) -------------------
template<int IC, int OC, int PAD, int NCHUNK, int NFRAG>
__global__ __launch_bounds__(256) void conv_mfma(const float* __restrict__ in,
                                                 int inH, int inW,
                                                 const unsigned short* __restrict__ Wh,
                                                 const unsigned short* __restrict__ Wl,
                                                 const float* __restrict__ bias,
                                                 float* __restrict__ out){
    const int KP = NCHUNK * 288;
    const int CST = 40;
    __shared__ __align__(16) unsigned short Xh[3 * 68 * CST], Xl[3 * 68 * CST];
    int y = blockIdx.y;
    int x0 = blockIdx.x * 64;
    int tid = threadIdx.x;
    int lane = tid & 63, wid = tid >> 6;
    int wy = wid >> 1, wx = wid & 1;
    int l15 = lane & 15, g = lane >> 4;

    fv4 acc[2][NFRAG];
    #pragma unroll
    for (int mi = 0; mi < 2; mi++)
        #pragma unroll
        for (int ni = 0; ni < NFRAG; ni++) acc[mi][ni] = (fv4){0.f,0.f,0.f,0.f};

    for (int ch = 0; ch < NCHUNK; ch++){
        int ci0 = ch * 32;
        if (ch > 0) __syncthreads();
        for (int e = tid; e < 3 * 68 * 8; e += 256){
            int qd = e & 7;
            int c  = (e >> 3) % 68;
            int r  = e / 544;
            int iy = y - PAD + r, ix = x0 - PAD + c;
            fv4 v = (fv4){0.f,0.f,0.f,0.f};
            if ((unsigned)iy < (unsigned)inH && (unsigned)ix < (unsigned)inW &&
                (ci0 + qd * 4 + 4) <= IC)
                v = *reinterpret_cast<const fv4*>(in + ((size_t)iy * inW + ix) * IC + ci0 + qd * 4);
            unsigned short hs[4], ls[4];
            #pragma unroll
            for (int j = 0; j < 4; j++) bf16_split(v[j], hs[j], ls[j]);
            unsigned off = (r * 68 + c) * CST + qd * 4;
            *reinterpret_cast<uint2*>(&Xh[off]) = make_uint2(pack2(hs[0],hs[1]), pack2(hs[2],hs[3]));
            *reinterpret_cast<uint2*>(&Xl[off]) = make_uint2(pack2(ls[0],ls[1]), pack2(ls[2],ls[3]));
        }
        __syncthreads();
        #pragma unroll
        for (int t = 0; t < 9; t++){
            int ky = t / 3, kx = t % 3;
            short8 ah[2], al[2], bh[NFRAG], bl[NFRAG];
            #pragma unroll
            for (int mi = 0; mi < 2; mi++){
                unsigned off = (ky * 68 + wy * 32 + mi * 16 + l15 + kx) * CST + g * 8;
                ah[mi] = *reinterpret_cast<const short8*>(&Xh[off]);
                al[mi] = *reinterpret_cast<const short8*>(&Xl[off]);
            }
            #pragma unroll
            for (int ni = 0; ni < NFRAG; ni++){
                int oc = wx * (16 * NFRAG) + ni * 16 + l15;
                size_t woff = (size_t)oc * KP + ch * 288 + t * 32 + g * 8;
                bh[ni] = *reinterpret_cast<const short8*>(&Wh[woff]);
                bl[ni] = *reinterpret_cast<const short8*>(&Wl[woff]);
            }
            #pragma unroll
            for (int mi = 0; mi < 2; mi++)
                #pragma unroll
                for (int ni = 0; ni < NFRAG; ni++){
                    acc[mi][ni] = __builtin_amdgcn_mfma_f32_16x16x32_bf16(ah[mi], bh[ni], acc[mi][ni], 0, 0, 0);
                    acc[mi][ni] = __builtin_amdgcn_mfma_f32_16x16x32_bf16(ah[mi], bl[ni], acc[mi][ni], 0, 0, 0);
                    acc[mi][ni] = __builtin_amdgcn_mfma_f32_16x16x32_bf16(al[mi], bh[ni], acc[mi][ni], 0, 0, 0);
                }
        }
    }
    #pragma unroll
    for (int mi = 0; mi < 2; mi++)
        #pragma unroll
        for (int ni = 0; ni < NFRAG; ni++){
            int oc = wx * (16 * NFRAG) + ni * 16 + l15;
            float bv = bias[oc];
            #pragma unroll
            for (int j = 0; j < 4; j++){
                int x = x0 + wy * 32 + mi * 16 + g * 4 + j;
                if (x >= CONVH) continue;
                out[((size_t)y * CONVH + x) * OC + oc] = gelu_f(acc[mi][ni][j] + bv);
            }
        }
}

// ---------------- adaptive pool HWC into comb[:,128:] ----------------
__global__ void pool_kernel(const float* __restrict__ c2, float* __restrict__ comb){
    int idx = blockIdx.x * 256 + threadIdx.x;
    if (idx >= HW * 64) return;
    int o = idx & 63;
    int pix = idx >> 6;
    int xo = pix % Wdim, yo = pix / Wdim;
    int ys = yo * CONVH / Hdim, ye = ((yo + 1) * CONVH + Hdim - 1) / Hdim;
    int xs = xo * CONVH / Wdim, xe = ((xo + 1) * CONVH + Wdim - 1) / Wdim;
    float s = 0.f;
    for (int yy = ys; yy < ye; yy++)
        for (int xx = xs; xx < xe; xx++)
            s += c2[((size_t)yy * CONVH + xx) * 64 + o];
    comb[(size_t)pix * 192 + 128 + o] = s / (float)((ye - ys) * (xe - xs));
}

// ---------------- depthwise causal conv1d (width 4) + silu -> packed u32 ------------
__global__ __launch_bounds__(256) void conv1d_tiled(const float* __restrict__ zx,
                                                    const float* __restrict__ w,
                                                    const float* __restrict__ b,
                                                    unsigned* __restrict__ xbcp){
    __shared__ float xs[67 * 128];
    __shared__ float wc[4 * 128];
    __shared__ float bc[128];
    int t0 = blockIdx.y * 64;
    int c0 = blockIdx.x * 128;
    int tid = threadIdx.x;
    for (int e = tid; e < 67 * 128; e += 256){
        int rr = e >> 7, cc = e & 127;
        int t = t0 - 3 + rr;
        xs[e] = (t >= 0 && t < HW) ? zx[(size_t)t * 772 + 256 + c0 + cc] : 0.f;
    }
    if (tid < 128){
        bc[tid] = b[c0 + tid];
        #pragma unroll
        for (int k = 0; k < 4; k++) wc[k * 128 + tid] = w[(c0 + tid) * 4 + k];
    }
    __syncthreads();
    for (int e = tid; e < 64 * 128; e += 256){
        int tt = e >> 7, cc = e & 127;
        if (t0 + tt >= HW) continue;
        float acc = bc[cc];
        #pragma unroll
        for (int k = 0; k < 4; k++) acc += xs[(tt + k) * 128 + cc] * wc[k * 128 + cc];
        xbcp[(size_t)(t0 + tt) * 512 + c0 + cc] = packsplit(silu_f(acc));
    }
}

// ---------------- chunk cumsum (wave 0) ----------------
__device__ __forceinline__ void chunk_cumsum_t(const float* __restrict__ dtbT, int t0, int Q,
                                               int h, const float* __restrict__ A_log,
                                               float* cum, float* dth){
    int tid = threadIdx.x;
    if (tid < 64){
        float d = (tid < Q) ? dtbT[h * DTP + t0 + tid] : 0.f;
        dth[tid] = d;
        float A = -expf(A_log[h]);
        float a = d * A;
        #pragma unroll
        for (int off = 1; off < 64; off <<= 1){
            float u = __shfl_up(a, off);
            if (tid >= off) a += u;
        }
        cum[tid] = a;
    }
    __syncthreads();
}

// swizzled (c,h) decode: 4 head-siblings of a chunk share bid%8 -> same XCD L2
__device__ __forceinline__ bool ssd_decode(int bid, int& c, int& h){
    int m = bid & 7, rest = bid >> 3;
    h = rest & 3;
    c = (rest >> 2) * 8 + m;
    return c < NCH;
}

// ---------------- SSD phase A (MFMA, per (c,h), packed in/out) ----------------
__global__ __launch_bounds__(256) void ssd_phaseA(const unsigned* __restrict__ xbcp,
                                                  const float* __restrict__ dtbT,
                                                  const float* __restrict__ A_log,
                                                  unsigned* __restrict__ Sp,
                                                  float* __restrict__ chunkT){
    __shared__ __align__(16) unsigned short BTh[128 * SP], BTl[128 * SP]; // B^T [n][s]
    __shared__ __align__(16) unsigned short XTh[64 * SP],  XTl[64 * SP];  // (Xw)^T [p][s]
    __shared__ float cum[64], dth[64], wln[64];
    int c, h;
    if (!ssd_decode(blockIdx.x, c, h)) return;
    int t0 = c * QC, Q = min(QC, HW - t0);
    int tid = threadIdx.x;
    chunk_cumsum_t(dtbT, t0, Q, h, A_log, cum, dth);
    float T = cum[Q - 1];
    if (tid == 0) chunkT[c * 4 + h] = T;
    if (tid < 64) wln[tid] = (tid < Q) ? __expf(T - cum[tid]) * dth[tid] : 0.f;
    __syncthreads();
    for (int e2 = tid; e2 < 4096; e2 += 256){
        int nn = e2 & 127, sp = e2 >> 7;
        int s0 = 2 * sp;
        unsigned v0 = (s0 < Q)     ? xbcp[(size_t)(t0 + s0) * 512 + 256 + nn] : 0u;
        unsigned v1 = (s0 + 1 < Q) ? xbcp[(size_t)(t0 + s0 + 1) * 512 + 256 + nn] : 0u;
        *reinterpret_cast<unsigned*>(&BTh[nn * SP + s0]) = pack2((unsigned short)(v0 >> 16), (unsigned short)(v1 >> 16));
        *reinterpret_cast<unsigned*>(&BTl[nn * SP + s0]) = pack2((unsigned short)(v0 & 0xFFFFu), (unsigned short)(v1 & 0xFFFFu));
    }
    for (int e2 = tid; e2 < 2048; e2 += 256){
        int pp = e2 & 63, sp = e2 >> 6;
        int s0 = 2 * sp;
        float v0 = (s0 < Q)     ? unpackf(xbcp[(size_t)(t0 + s0) * 512 + h * 64 + pp]) * wln[s0] : 0.f;
        float v1 = (s0 + 1 < Q) ? unpackf(xbcp[(size_t)(t0 + s0 + 1) * 512 + h * 64 + pp]) * wln[s0 + 1] : 0.f;
        unsigned short h0, l0, h1, l1;
        bf16_split(v0, h0, l0); bf16_split(v1, h1, l1);
        *reinterpret_cast<unsigned*>(&XTh[pp * SP + s0]) = pack2(h0, h1);
        *reinterpret_cast<unsigned*>(&XTl[pp * SP + s0]) = pack2(l0, l1);
    }
    __syncthreads();
    int lane = tid & 63, wid = tid >> 6;
    int wy = wid >> 1, wx = wid & 1;
    int l15 = lane & 15, g = lane >> 4;
    fv4 acc[2][4];
    #pragma unroll
    for (int mi = 0; mi < 2; mi++)
        #pragma unroll
        for (int ni = 0; ni < 4; ni++) acc[mi][ni] = (fv4){0.f,0.f,0.f,0.f};
    #pragma unroll
    for (int ks = 0; ks < 2; ks++){
        short8 ah[2], al[2], bh_[4], bl_[4];
        #pragma unroll
        for (int mi = 0; mi < 2; mi++){
            unsigned off = (wy * 32 + mi * 16 + l15) * SP + ks * 32 + g * 8;
            ah[mi] = *reinterpret_cast<const short8*>(&XTh[off]);
            al[mi] = *reinterpret_cast<const short8*>(&XTl[off]);
        }
        #pragma unroll
        for (int ni = 0; ni < 4; ni++){
            unsigned off = (wx * 64 + ni * 16 + l15) * SP + ks * 32 + g * 8;
            bh_[ni] = *reinterpret_cast<const short8*>(&BTh[off]);
            bl_[ni] = *reinterpret_cast<const short8*>(&BTl[off]);
        }
        #pragma unroll
        for (int mi = 0; mi < 2; mi++)
            #pragma unroll
            for (int ni = 0; ni < 4; ni++){
                acc[mi][ni] = __builtin_amdgcn_mfma_f32_16x16x32_bf16(ah[mi], bh_[ni], acc[mi][ni], 0, 0, 0);
                acc[mi][ni] = __builtin_amdgcn_mfma_f32_16x16x32_bf16(ah[mi], bl_[ni], acc[mi][ni], 0, 0, 0);
                acc[mi][ni] = __builtin_amdgcn_mfma_f32_16x16x32_bf16(al[mi], bh_[ni], acc[mi][ni], 0, 0, 0);
            }
    }
    size_t sb = (size_t)(c * 4 + h) * 8192;
    #pragma unroll
    for (int mi = 0; mi < 2; mi++)
        #pragma unroll
        for (int ni = 0; ni < 4; ni++)
            #pragma unroll
            for (int j = 0; j < 4; j++){
                int p = wy * 32 + mi * 16 + g * 4 + j;
                int n = wx * 64 + ni * 16 + l15;
                Sp[sb + p * 128 + n] = packsplit(acc[mi][ni][j]);
            }
}

// ---------------- SSD phase B: in-place prefix over chunks (packed u32) ------------
__global__ __launch_bounds__(256) void ssd_phaseB(unsigned* __restrict__ Sp,
                                                  const float* __restrict__ chunkT){
    __shared__ float e[NCH];
    int tid = threadIdx.x;
    int idx = blockIdx.x * 256 + tid;
    int h = idx >> 13, pn = idx & 8191;
    for (int c = tid; c < NCH; c += 256) e[c] = __expf(chunkT[c * 4 + h]);
    __syncthreads();
    #define ADDR_(cc) Sp[((size_t)((cc) * 4 + h)) * 8192 + pn]
    unsigned r0 = ADDR_(0), r1 = ADDR_(1), r2 = ADDR_(2), r3 = ADDR_(3);
    float s = 0.f;
    int c = 0;
    for (; c + 8 <= NCH; c += 4){
        unsigned n0 = ADDR_(c + 4), n1 = ADDR_(c + 5), n2 = ADDR_(c + 6), n3 = ADDR_(c + 7);
        ADDR_(c) = packsplit(s);     s = fmaf(s, e[c],     unpackf(r0));
        ADDR_(c + 1) = packsplit(s); s = fmaf(s, e[c + 1], unpackf(r1));
        ADDR_(c + 2) = packsplit(s); s = fmaf(s, e[c + 2], unpackf(r2));
        ADDR_(c + 3) = packsplit(s); s = fmaf(s, e[c + 3], unpackf(r3));
        r0 = n0; r1 = n1; r2 = n2; r3 = n3;
    }
    for (; c < NCH; c++){
        unsigned nx = (c + 4 < NCH) ? ADDR_(c + 4) : 0u;
        float loc = unpackf(r0); r0 = r1; r1 = r2; r2 = r3; r3 = nx;
        ADDR_(c) = packsplit(s);
        s = fmaf(s, e[c], loc);
    }
    #undef ADDR_
}

// ---------------- SSD phase C (MFMA, per (c,h), packed direct-global) ---------------
__global__ __launch_bounds__(256) void ssd_phaseC(const unsigned* __restrict__ xbcp,
                                                  const float* __restrict__ dtbT,
                                                  const float* __restrict__ A_log,
                                                  const float* __restrict__ Dvec,
                                                  const unsigned* __restrict__ Sp,
                                                  float* __restrict__ y){
    __shared__ __align__(16) unsigned short U0h[64 * SP], U0l[64 * SP]; // P [t][s]
    __shared__ __align__(16) unsigned short U1h[64 * SP], U1l[64 * SP]; // X^T [p][s]
    __shared__ float cum[64], dth[64];
    int c, h;
    if (!ssd_decode(blockIdx.x, c, h)) return;
    int t0 = c * QC, Q = min(QC, HW - t0);
    int tid = threadIdx.x;
    chunk_cumsum_t(dtbT, t0, Q, h, A_log, cum, dth);
    int lane = tid & 63, wid = tid >> 6;
    int wy = wid >> 1, wx = wid & 1;
    int l15 = lane & 15, g = lane >> 4;

    int trow[2], srow[2], prow[2];
    #pragma unroll
    for (int i = 0; i < 2; i++){
        trow[i] = min(t0 + wy * 32 + i * 16 + l15, HW - 1);
        srow[i] = min(t0 + wx * 32 + i * 16 + l15, HW - 1);
        prow[i] = wx * 32 + i * 16 + l15;
    }

    fv4 accG[2][2], accA[2][2];
    #pragma unroll
    for (int mi = 0; mi < 2; mi++)
        #pragma unroll
        for (int ni = 0; ni < 2; ni++){ accG[mi][ni] = (fv4){0.f,0.f,0.f,0.f}; accA[mi][ni] = (fv4){0.f,0.f,0.f,0.f}; }

    const unsigned* Sbase = Sp + (size_t)(c * 4 + h) * 8192;
    #pragma unroll
    for (int k0 = 0; k0 < 128; k0 += 32){
        short8 ah[2], al[2], bh[2], bl[2], sh[2], sl[2];
        #pragma unroll
        for (int mi = 0; mi < 2; mi++)
            unpack8(xbcp + (size_t)trow[mi] * 512 + 384 + k0 + g * 8, ah[mi], al[mi]);
        #pragma unroll
        for (int ni = 0; ni < 2; ni++){
            unpack8(xbcp + (size_t)srow[ni] * 512 + 256 + k0 + g * 8, bh[ni], bl[ni]);
            unpack8(Sbase + prow[ni] * 128 + k0 + g * 8, sh[ni], sl[ni]);
        }
        #pragma unroll
        for (int mi = 0; mi < 2; mi++)
            #pragma unroll
            for (int ni = 0; ni < 2; ni++){
                accG[mi][ni] = __builtin_amdgcn_mfma_f32_16x16x32_bf16(ah[mi], bh[ni], accG[mi][ni], 0, 0, 0);
                accG[mi][ni] = __builtin_amdgcn_mfma_f32_16x16x32_bf16(ah[mi], bl[ni], accG[mi][ni], 0, 0, 0);
                accG[mi][ni] = __builtin_amdgcn_mfma_f32_16x16x32_bf16(al[mi], bh[ni], accG[mi][ni], 0, 0, 0);
                accA[mi][ni] = __builtin_amdgcn_mfma_f32_16x16x32_bf16(ah[mi], sh[ni], accA[mi][ni], 0, 0, 0);
                accA[mi][ni] = __builtin_amdgcn_mfma_f32_16x16x32_bf16(ah[mi], sl[ni], accA[mi][ni], 0, 0, 0);
                accA[mi][ni] = __builtin_amdgcn_mfma_f32_16x16x32_bf16(al[mi], sh[ni], accA[mi][ni], 0, 0, 0);
            }
    }
    // P = mask(G) * exp(cum_t - cum_s) * dt_s -> U0 [t][s]
    #pragma unroll
    for (int mi = 0; mi < 2; mi++)
        #pragma unroll
        for (int ni = 0; ni < 2; ni++)
            #pragma unroll
            for (int j = 0; j < 4; j++){
                int t = wy * 32 + mi * 16 + g * 4 + j;
                int s = wx * 32 + ni * 16 + l15;
                float pv = 0.f;
                if (s <= t && s < Q)
                    pv = accG[mi][ni][j] * __expf(cum[t] - cum[s]) * dth[s];
                unsigned short hs, ls;
                bf16_split(pv, hs, ls);
                U0h[t * SP + s] = hs;
                U0l[t * SP + s] = ls;
            }
    // stage X^T [p][s] -> U1 (pure shifts from packed)
    for (int e2 = tid; e2 < 2048; e2 += 256){
        int pp = e2 & 63, sp = e2 >> 6;
        int s0 = 2 * sp;
        unsigned v0 = (s0 < Q)     ? xbcp[(size_t)(t0 + s0) * 512 + h * 64 + pp] : 0u;
        unsigned v1 = (s0 + 1 < Q) ? xbcp[(size_t)(t0 + s0 + 1) * 512 + h * 64 + pp] : 0u;
        *reinterpret_cast<unsigned*>(&U1h[pp * SP + s0]) = pack2((unsigned short)(v0 >> 16), (unsigned short)(v1 >> 16));
        *reinterpret_cast<unsigned*>(&U1l[pp * SP + s0]) = pack2((unsigned short)(v0 & 0xFFFFu), (unsigned short)(v1 & 0xFFFFu));
    }
    __syncthreads();
    // Y = exp(cum_t)*accA + P @ X
    fv4 accY[2][2];
    #pragma unroll
    for (int mi = 0; mi < 2; mi++)
        #pragma unroll
        for (int ni = 0; ni < 2; ni++)
            #pragma unroll
            for (int j = 0; j < 4; j++){
                int t = wy * 32 + mi * 16 + g * 4 + j;
                accY[mi][ni][j] = __expf(cum[t]) * accA[mi][ni][j];
            }
    #pragma unroll
    for (int kk = 0; kk < 2; kk++){
        short8 ph[2], pl[2], xh[2], xl[2];
        #pragma unroll
        for (int mi = 0; mi < 2; mi++){
            unsigned off = (wy * 32 + mi * 16 + l15) * SP + kk * 32 + g * 8;
            ph[mi] = *reinterpret_cast<const short8*>(&U0h[off]);
            pl[mi] = *reinterpret_cast<const short8*>(&U0l[off]);
        }
        #pragma unroll
        for (int ni = 0; ni < 2; ni++){
            unsigned off = (wx * 32 + ni * 16 + l15) * SP + kk * 32 + g * 8;
            xh[ni] = *reinterpret_cast<const short8*>(&U1h[off]);
            xl[ni] = *reinterpret_cast<const short8*>(&U1l[off]);
        }
        #pragma unroll
        for (int mi = 0; mi < 2; mi++)
            #pragma unroll
            for (int ni = 0; ni < 2; ni++){
                accY[mi][ni] = __builtin_amdgcn_mfma_f32_16x16x32_bf16(ph[mi], xh[ni], accY[mi][ni], 0, 0, 0);
                accY[mi][ni] = __builtin_amdgcn_mfma_f32_16x16x32_bf16(ph[mi], xl[ni], accY[mi][ni], 0, 0, 0);
                accY[mi][ni] = __builtin_amdgcn_mfma_f32_16x16x32_bf16(pl[mi], xh[ni], accY[mi][ni], 0, 0, 0);
            }
    }
    float Dh = Dvec[h];
    #pragma unroll
    for (int mi = 0; mi < 2; mi++)
        #pragma unroll
        for (int ni = 0; ni < 2; ni++)
            #pragma unroll
            for (int j = 0; j < 4; j++){
                int t = wy * 32 + mi * 16 + g * 4 + j;
                if (t >= Q) continue;
                int p = wx * 32 + ni * 16 + l15;
                float xv = unpackf(xbcp[(size_t)(t0 + t) * 512 + h * 64 + p]);
                y[(size_t)(t0 + t) * 256 + h * 64 + p] = accY[mi][ni][j] + Dh * xv;
            }
}

// ---------------- gated RMSNorm ----------------
__global__ void gated_rms_kernel(float* __restrict__ y, const float* __restrict__ zx,
                                 const float* __restrict__ nw){
    int row = blockIdx.x, tid = threadIdx.x;
    float v = y[(size_t)row * 256 + tid];
    float z = zx[(size_t)row * 772 + tid];
    v *= silu_f(z);
    float s = v * v;
    __shared__ float r1[4];
    #pragma unroll
    for (int o = 32; o > 0; o >>= 1) s += __shfl_down(s, o);
    if ((tid & 63) == 0) r1[tid >> 6] = s;
    __syncthreads();
    float S = r1[0] + r1[1] + r1[2] + r1[3];
    float rs = rsqrtf(S / 256.f + 1e-5f);
    y[(size_t)row * 256 + tid] = v * rs * nw[tid];
}

extern "C" void kernel_launch(void* const* d_in, const int* in_sizes, int n_in,
                              void* d_out, int out_size, void* d_ws, size_t ws_size,
                              hipStream_t stream){
    (void)in_sizes; (void)n_in; (void)out_size; (void)ws_size;
    const float* x        = (const float*)d_in[0];
    const float* ln_pre_g = (const float*)d_in[1];
    const float* ln_pre_b = (const float*)d_in[2];
    const float* fe_w1    = (const float*)d_in[3];
    const float* fe_b1    = (const float*)d_in[4];
    const float* fe_w2    = (const float*)d_in[5];
    const float* fe_b2    = (const float*)d_in[6];
    const float* cv_w1    = (const float*)d_in[7];
    const float* cv_b1    = (const float*)d_in[8];
    const float* cv_w2    = (const float*)d_in[9];
    const float* cv_b2    = (const float*)d_in[10];
    const float* mp_w     = (const float*)d_in[11];
    const float* mp_b     = (const float*)d_in[12];
    const float* mp_ln_g  = (const float*)d_in[13];
    const float* mp_ln_b  = (const float*)d_in[14];
    const float* m_in_w   = (const float*)d_in[15];
    const float* m_conv_w = (const float*)d_in[16];
    const float* m_conv_b = (const float*)d_in[17];
    const float* m_dtb    = (const float*)d_in[18];
    const float* m_A_log  = (const float*)d_in[19];
    const float* m_D      = (const float*)d_in[20];
    const float* m_norm_w = (const float*)d_in[21];
    const float* m_out_w  = (const float*)d_in[22];
    const float* cls_ln_g = (const float*)d_in[23];
    const float* cls_ln_b = (const float*)d_in[24];
    const float* cls_w1   = (const float*)d_in[25];
    const float* cls_b1   = (const float*)d_in[26];
    const float* cls_w2   = (const float*)d_in[27];
    const float* cls_b2   = (const float*)d_in[28];
    const float* cls_w3   = (const float*)d_in[29];
    const float* cls_b3   = (const float*)d_in[30];

    float* ws   = (float*)d_ws;
    float* xn   = ws + OFF_XN;
    float* f1   = ws + OFF_F1;
    float* comb = ws + OFF_COMB;
    float* p    = ws + OFF_P;
    float* zx   = ws + OFF_ZX;
    unsigned* xbcp = (unsigned*)(ws + OFF_XBC);
    unsigned* Sp = (unsigned*)(ws + OFF_S);
    float* dtbT = ws + OFF_DT;
    float* chkT = ws + OFF_CT;
    float* c1h  = ws + OFF_XBC;                    // before xbcp live
    float* c2h  = ws + OFF_XBC + 691488;
    float* ybuf = ws + OFF_F1;
    float* cls0 = ws + OFF_XN;
    float* cls1 = ws + OFF_P;
    float* cls2 = ws + OFF_COMB + 2691200;
    unsigned short* W1h = (unsigned short*)(ws + OFF_W);
    unsigned short* W1l = (unsigned short*)(ws + OFF_W + 32256);
    unsigned short* W2h = (unsigned short*)(ws + OFF_W + 64512);
    unsigned short* W2l = (unsigned short*)(ws + OFF_W + 73728);

    // 0. conv weight prepack (tiny)
    prep_w<200, 32, 7><<<(32 * 2016 + 255) / 256, 256, 0, stream>>>(cv_w1, W1h, W1l);
    prep_w<32, 64, 1><<<(64 * 288 + 255) / 256, 256, 0, stream>>>(cv_w2, W2h, W2l);
    // 1. pre-LN
    ln_kernel<0><<<HW, 256, 0, stream>>>(x, ln_pre_g, ln_pre_b, xn, NBANDS);
    // 2-3. feature MLP (f -> comb[:, :128])
    gemm_mfma_w<1, 4><<<gemm_grid(2, 165), 256, 0, stream>>>(xn, 200, fe_w1, 256, fe_b1,
        (const float*)nullptr, (const float*)nullptr, f1, 256, HW, 256, 200, 2, 165);
    gemm_mfma_w<1, 2><<<gemm_grid(1, 329), 256, 0, stream>>>(f1, 256, fe_w2, 128, fe_b2,
        (const float*)nullptr, (const float*)nullptr, comb, 192, HW, 128, 256, 1, 329);
    // 4. conv1 (MFMA implicit-im2col): 200->32, pad 2
    conv_mfma<200, 32, 2, 7, 1><<<dim3(3, CONVH), 256, 0, stream>>>(xn, Hdim, Wdim, W1h, W1l, cv_b1, c1h);
    // 5. conv2 (MFMA): 32->64, pad 1
    conv_mfma<32, 64, 1, 1, 2><<<dim3(3, CONVH), 256, 0, stream>>>(c1h, CONVH, CONVH, W2h, W2l, cv_b2, c2h);
    // 6. adaptive pool -> comb[:, 128:192]
    pool_kernel<<<(HW * 64 + 255) / 256, 256, 0, stream>>>(c2h, comb);
    // 7. mid projection + fused LN + GELU -> p
    gemm_mfma_w<3, 2><<<gemm_grid(1, 329), 256, 0, stream>>>(comb, 192, mp_w, 128, mp_b,
        mp_ln_g, mp_ln_b, p, 128, HW, 128, 192, 1, 329);
    // 8. mamba in_proj (cols 0..768 only; dt computed separately)
    gemm_mfma_w<0, 4><<<gemm_grid(6, 165), 256, 0, stream>>>(p, 128, m_in_w, 772,
        (const float*)nullptr, (const float*)nullptr, (const float*)nullptr,
        zx, 772, HW, 768, 128, 6, 165);
    // 9. dt from p (fused softplus, transposed write)
    dt_from_p<<<(HW + 63) / 64, 256, 0, stream>>>(p, m_in_w, m_dtb, dtbT);
    // 10. depthwise causal conv + silu -> packed u32
    conv1d_tiled<<<dim3(4, NCH), 256, 0, stream>>>(zx, m_conv_w, m_conv_b, xbcp);
    // 11-13. SSD chunked scan (MFMA, xcd-sibling swizzled, packed)
    ssd_phaseA<<<SSD_GRID, 256, 0, stream>>>(xbcp, dtbT, m_A_log, Sp, chkT);
    ssd_phaseB<<<128, 256, 0, stream>>>(Sp, chkT);
    ssd_phaseC<<<SSD_GRID, 256, 0, stream>>>(xbcp, dtbT, m_A_log, m_D, Sp, ybuf);
    // 14. gated RMSNorm
    gated_rms_kernel<<<HW, 256, 0, stream>>>(ybuf, zx, m_norm_w);
    // 15. out proj + fused cls LN -> cls0
    gemm_mfma_w<2, 2><<<gemm_grid(1, 329), 256, 0, stream>>>(ybuf, 256, m_out_w, 128,
        (const float*)nullptr, cls_ln_g, cls_ln_b, cls0, 128, HW, 128, 256, 1, 329);
    // 16-18. classifier
    gemm_mfma_w<1, 2><<<gemm_grid(1, 329), 256, 0, stream>>>(cls0, 128, cls_w1, 128, cls_b1,
        (const float*)nullptr, (const float*)nullptr, cls1, 128, HW, 128, 128, 1, 329);
    gemm_mfma<1><<<gemm_grid(1, 165), 256, 0, stream>>>(cls1, 128, cls_w2, cls_b2, cls2, 64, HW, 64, 128, 1, 165);
    gemm_mfma<0><<<gemm_grid(1, 165), 256, 0, stream>>>(cls2, 64, cls_w3, cls_b3, (float*)d_out, 17, HW, 17, 64, 1, 165);
}

// Round 10
// 469.260 us; speedup vs baseline: 1.1101x; 1.0120x over previous
//
#include <hip/hip_runtime.h>
#include <math.h>

#define HW 21025        // 145*145
#define Hdim 145
#define Wdim 145
#define NBANDS 200
#define CONVH 147
#define CONVHW 21609    // 147*147
#define QC 64
#define NCH 329         // ceil(21025/64)
#define DTP 21056       // padded L for transposed dt
#define SP 72           // short stride for [.][64-k] MFMA tiles
#define SSD_GRID 1344   // 8 * 4 * 42 (xcd-sibling swizzled, tail-guarded)

typedef __attribute__((ext_vector_type(4))) float fv4;
typedef __attribute__((ext_vector_type(8))) short short8;

// ---------------- workspace layout (float offsets) ----------------
#define OFF_XN   ((size_t)0)           // 4,205,000  xn; later cls0
#define OFF_F1   ((size_t)4205000)     // 5,382,400  f1; later y (L x 256)
#define OFF_COMB ((size_t)9587400)     // 4,036,800  comb L x 192; later cls2
#define OFF_P    ((size_t)13624200)    // 2,691,200  p; later cls1
#define OFF_ZX   ((size_t)16315400)    // 16,231,300 zxbcdt L x 772
#define OFF_XBC  ((size_t)32546700)    // 10,764,800 c1h+c2h first, then xbc packed u32
#define OFF_S    ((size_t)43311500)    // S as bf16 ushort (1316*8192*2B)
#define OFF_DT   ((size_t)54092172)    // 84,224 (dt transposed [4][DTP])
#define OFF_CT   ((size_t)54176396)    // 1,316
#define OFF_W    ((size_t)54177712)    // 82,944: packed conv weights (bf16 hi/lo)

__device__ __forceinline__ float gelu_f(float x){
    return 0.5f * x * (1.0f + erff(x * 0.70710678118654752440f));
}
__device__ __forceinline__ float silu_f(float x){
    return x / (1.0f + expf(-x));
}

__device__ __forceinline__ void bf16_split(float x, unsigned short& hs, unsigned short& ls){
    unsigned u = __float_as_uint(x);
    hs = (unsigned short)(u >> 16);
    float hif = __uint_as_float(u & 0xFFFF0000u);
    float lof = x - hif;
    ls = (unsigned short)(__float_as_uint(lof) >> 16);
}
__device__ __forceinline__ unsigned pack2(unsigned short a, unsigned short b){
    return (unsigned)a | ((unsigned)b << 16);
}
__device__ __forceinline__ unsigned packsplit(float x){
    unsigned short hs, ls;
    bf16_split(x, hs, ls);
    return ((unsigned)hs << 16) | (unsigned)ls;
}
__device__ __forceinline__ float unpackf(unsigned u){
    return __uint_as_float(u & 0xFFFF0000u) + __uint_as_float(u << 16);
}
// round-to-nearest-even bf16
__device__ __forceinline__ unsigned short bf16rnd(float x){
    unsigned u = __float_as_uint(x);
    unsigned r = u + 0x7FFFu + ((u >> 16) & 1u);
    return (unsigned short)(r >> 16);
}
__device__ __forceinline__ float bf16f(unsigned short h){
    return __uint_as_float((unsigned)h << 16);
}
__device__ __forceinline__ void unpack8(const unsigned* p, short8& h8, short8& l8){
    uint4 a = *reinterpret_cast<const uint4*>(p);
    uint4 b = *reinterpret_cast<const uint4*>(p + 4);
    unsigned v0 = a.x, v1 = a.y, v2 = a.z, v3 = a.w;
    unsigned v4 = b.x, v5 = b.y, v6 = b.z, v7 = b.w;
    h8[0]=(short)(v0>>16); l8[0]=(short)(v0&0xFFFFu);
    h8[1]=(short)(v1>>16); l8[1]=(short)(v1&0xFFFFu);
    h8[2]=(short)(v2>>16); l8[2]=(short)(v2&0xFFFFu);
    h8[3]=(short)(v3>>16); l8[3]=(short)(v3&0xFFFFu);
    h8[4]=(short)(v4>>16); l8[4]=(short)(v4&0xFFFFu);
    h8[5]=(short)(v5>>16); l8[5]=(short)(v5&0xFFFFu);
    h8[6]=(short)(v6>>16); l8[6]=(short)(v6&0xFFFFu);
    h8[7]=(short)(v7>>16); l8[7]=(short)(v7&0xFFFFu);
}

// XCD-grouped decode
__device__ __forceinline__ bool gemm_decode(int bid, int NXB, int NYB, int& bx, int& by){
    int m = bid & 7;
    int r = bid >> 3;
    bx = r % NXB;
    by = (r / NXB) * 8 + m;
    return by < NYB;
}
__host__ __forceinline__ int gemm_grid(int NXB, int NYB){ return 8 * ((NYB + 7) / 8) * NXB; }

// ---------------- LayerNorm (pre-LN only) ----------------
template<int ACT>
__global__ void ln_kernel(const float* __restrict__ in, const float* __restrict__ g,
                          const float* __restrict__ b, float* __restrict__ out, int D){
    int row = blockIdx.x, tid = threadIdx.x;
    const float* r = in + (size_t)row * D;
    float s = 0.f, s2 = 0.f;
    for (int i = tid; i < D; i += 256){ float v = r[i]; s += v; s2 += v*v; }
    __shared__ float r1[4], r2[4];
    #pragma unroll
    for (int o = 32; o > 0; o >>= 1){ s += __shfl_down(s, o); s2 += __shfl_down(s2, o); }
    if ((tid & 63) == 0){ r1[tid >> 6] = s; r2[tid >> 6] = s2; }
    __syncthreads();
    float S = r1[0] + r1[1] + r1[2] + r1[3];
    float S2 = r2[0] + r2[1] + r2[2] + r2[3];
    float mean = S / (float)D;
    float var = S2 / (float)D - mean * mean;
    float rs = rsqrtf(fmaxf(var, 0.f) + 1e-5f);
    float* o_ = out + (size_t)row * D;
    for (int i = tid; i < D; i += 256){
        float v = (r[i] - mean) * rs * g[i] + b[i];
        if (ACT == 1) v = gelu_f(v);
        o_[i] = v;
    }
}

// ---------------- wide split-bf16 MFMA GEMM: BN=128, BM=MI*32 ----------------
// ACT: 0 none, 1 gelu, 2 LN, 3 LN+gelu (LN requires N==128, NXB==1)
template<int ACT, int MI>
__global__ __launch_bounds__(256) void gemm_mfma_w(const float* __restrict__ A, int lda,
                                                   const float* __restrict__ B, int ldb,
                                                   const float* __restrict__ bias,
                                                   const float* __restrict__ lng,
                                                   const float* __restrict__ lnb,
                                                   float* __restrict__ C, int ldc,
                                                   int M, int N, int K, int NXB, int NYB){
    const int SA = 40;
    const int BM = MI * 32;
    __shared__ __align__(16) unsigned short Ah[BM * SA], Al[BM * SA];
    __shared__ __align__(16) unsigned short Bh[128 * SA], Bl[128 * SA];
    __shared__ float rs1[2][BM], rs2_[2][BM];
    int bx, by;
    if (!gemm_decode(blockIdx.x, NXB, NYB, bx, by)) return;
    int tid = threadIdx.x;
    int lane = tid & 63, wid = tid >> 6;
    int wy = wid >> 1, wx = wid & 1;
    int bm = by * BM, bn = bx * 128;
    int l15 = lane & 15, g = lane >> 4;

    fv4 acc[MI][4];
    #pragma unroll
    for (int i = 0; i < MI; i++)
        #pragma unroll
        for (int j = 0; j < 4; j++) acc[i][j] = (fv4){0.f,0.f,0.f,0.f};

    int bcol = tid & 127;
    int bk16 = (tid >> 7) * 16;
    bool bcol_ok = (bn + bcol) < N;

    int nK = (K + 31) / 32;
    for (int ks = 0; ks < nK; ks++){
        int k0 = ks * 32;
        #pragma unroll
        for (int f = 0; f < MI; f++){
            int idx = tid * MI + f;
            int row = idx >> 3, qd = idx & 7;
            fv4 v = (fv4){0.f,0.f,0.f,0.f};
            if ((bm + row) < M && (k0 + qd * 4 + 4) <= K)
                v = *reinterpret_cast<const fv4*>(A + (size_t)(bm + row) * lda + k0 + qd * 4);
            unsigned short hs[4], ls[4];
            #pragma unroll
            for (int j = 0; j < 4; j++) bf16_split(v[j], hs[j], ls[j]);
            unsigned off = row * SA + qd * 4;
            *reinterpret_cast<uint2*>(&Ah[off]) = make_uint2(pack2(hs[0],hs[1]), pack2(hs[2],hs[3]));
            *reinterpret_cast<uint2*>(&Al[off]) = make_uint2(pack2(ls[0],ls[1]), pack2(ls[2],ls[3]));
        }
        {
            unsigned short hs[16], ls[16];
            #pragma unroll
            for (int j = 0; j < 16; j++){
                int kk = k0 + bk16 + j;
                float v = (bcol_ok && kk < K) ? B[(size_t)kk * ldb + bn + bcol] : 0.f;
                bf16_split(v, hs[j], ls[j]);
            }
            unsigned off = bcol * SA + bk16;
            *reinterpret_cast<uint4*>(&Bh[off]) = make_uint4(pack2(hs[0],hs[1]), pack2(hs[2],hs[3]),
                                                             pack2(hs[4],hs[5]), pack2(hs[6],hs[7]));
            *reinterpret_cast<uint4*>(&Bh[off + 8]) = make_uint4(pack2(hs[8],hs[9]), pack2(hs[10],hs[11]),
                                                                 pack2(hs[12],hs[13]), pack2(hs[14],hs[15]));
            *reinterpret_cast<uint4*>(&Bl[off]) = make_uint4(pack2(ls[0],ls[1]), pack2(ls[2],ls[3]),
                                                             pack2(ls[4],ls[5]), pack2(ls[6],ls[7]));
            *reinterpret_cast<uint4*>(&Bl[off + 8]) = make_uint4(pack2(ls[8],ls[9]), pack2(ls[10],ls[11]),
                                                                 pack2(ls[12],ls[13]), pack2(ls[14],ls[15]));
        }
        __syncthreads();
        short8 afh[MI], afl[MI], bfh[4], bfl[4];
        #pragma unroll
        for (int mi = 0; mi < MI; mi++){
            unsigned off = (wy * (MI * 16) + mi * 16 + l15) * SA + g * 8;
            afh[mi] = *reinterpret_cast<const short8*>(&Ah[off]);
            afl[mi] = *reinterpret_cast<const short8*>(&Al[off]);
        }
        #pragma unroll
        for (int ni = 0; ni < 4; ni++){
            unsigned off = (wx * 64 + ni * 16 + l15) * SA + g * 8;
            bfh[ni] = *reinterpret_cast<const short8*>(&Bh[off]);
            bfl[ni] = *reinterpret_cast<const short8*>(&Bl[off]);
        }
        #pragma unroll
        for (int mi = 0; mi < MI; mi++)
            #pragma unroll
            for (int ni = 0; ni < 4; ni++){
                acc[mi][ni] = __builtin_amdgcn_mfma_f32_16x16x32_bf16(afh[mi], bfh[ni], acc[mi][ni], 0, 0, 0);
                acc[mi][ni] = __builtin_amdgcn_mfma_f32_16x16x32_bf16(afh[mi], bfl[ni], acc[mi][ni], 0, 0, 0);
                acc[mi][ni] = __builtin_amdgcn_mfma_f32_16x16x32_bf16(afl[mi], bfh[ni], acc[mi][ni], 0, 0, 0);
            }
        __syncthreads();
    }
    float bv[4], lgv[4], lbv[4];
    #pragma unroll
    for (int ni = 0; ni < 4; ni++){
        int cc = bn + wx * 64 + ni * 16 + l15;
        bool ok = cc < N;
        bv[ni]  = (bias && ok) ? bias[cc] : 0.f;
        if (ACT >= 2){ lgv[ni] = ok ? lng[cc] : 1.f; lbv[ni] = ok ? lnb[cc] : 0.f; }
    }
    if (ACT >= 2){
        #pragma unroll
        for (int mi = 0; mi < MI; mi++)
            #pragma unroll
            for (int j = 0; j < 4; j++){
                float s = 0.f, s2 = 0.f;
                #pragma unroll
                for (int ni = 0; ni < 4; ni++){
                    float v = acc[mi][ni][j] + bv[ni];
                    s += v; s2 += v * v;
                }
                #pragma unroll
                for (int o = 1; o < 16; o <<= 1){
                    s += __shfl_xor(s, o); s2 += __shfl_xor(s2, o);
                }
                int row = wy * (MI * 16) + mi * 16 + g * 4 + j;
                if (l15 == 0){ rs1[wx][row] = s; rs2_[wx][row] = s2; }
            }
        __syncthreads();
        #pragma unroll
        for (int mi = 0; mi < MI; mi++)
            #pragma unroll
            for (int j = 0; j < 4; j++){
                int row = wy * (MI * 16) + mi * 16 + g * 4 + j;
                int rr = bm + row;
                if (rr >= M) continue;
                float S = rs1[0][row] + rs1[1][row];
                float S2 = rs2_[0][row] + rs2_[1][row];
                float mean = S / 128.f;
                float var = S2 / 128.f - mean * mean;
                float rsq = rsqrtf(fmaxf(var, 0.f) + 1e-5f);
                #pragma unroll
                for (int ni = 0; ni < 4; ni++){
                    int cc = bn + wx * 64 + ni * 16 + l15;
                    float v = acc[mi][ni][j] + bv[ni];
                    v = (v - mean) * rsq * lgv[ni] + lbv[ni];
                    if (ACT == 3) v = gelu_f(v);
                    C[(size_t)rr * ldc + cc] = v;
                }
            }
    } else {
        #pragma unroll
        for (int mi = 0; mi < MI; mi++)
            #pragma unroll
            for (int ni = 0; ni < 4; ni++){
                int cc = bn + wx * 64 + ni * 16 + l15;
                if (cc >= N) continue;
                #pragma unroll
                for (int j = 0; j < 4; j++){
                    int rr = bm + wy * (MI * 16) + mi * 16 + g * 4 + j;
                    if (rr >= M) continue;
                    float v = acc[mi][ni][j] + bv[ni];
                    if (ACT == 1) v = gelu_f(v);
                    C[(size_t)rr * ldc + cc] = v;
                }
            }
    }
}

// ---------------- narrow split-bf16 MFMA GEMM (BN=64) for small-N tails ------------
template<int ACT>
__global__ __launch_bounds__(256) void gemm_mfma(const float* __restrict__ A, int lda,
                                                 const float* __restrict__ B,
                                                 const float* __restrict__ bias,
                                                 float* __restrict__ C, int ldc,
                                                 int M, int N, int K, int NXB, int NYB){
    const int SA = 40;
    __shared__ __align__(16) unsigned short Ah[128 * SA], Al[128 * SA];
    __shared__ __align__(16) unsigned short Bh[64 * SA],  Bl[64 * SA];
    int bx, by;
    if (!gemm_decode(blockIdx.x, NXB, NYB, bx, by)) return;
    int tid = threadIdx.x;
    int lane = tid & 63, wid = tid >> 6;
    int wy = wid >> 1, wx = wid & 1;
    int bm = by * 128, bn = bx * 64;
    int l15 = lane & 15, g = lane >> 4;

    fv4 acc[4][2];
    #pragma unroll
    for (int i = 0; i < 4; i++)
        #pragma unroll
        for (int j = 0; j < 2; j++) acc[i][j] = (fv4){0.f,0.f,0.f,0.f};

    int am = tid >> 1;
    int aq = (tid & 1) * 4;
    bool arow_ok = (bm + am) < M;
    int bn_t = tid & 63;
    int bk8 = (tid >> 6) * 8;
    bool bcol_ok = (bn + bn_t) < N;

    int nK = (K + 31) / 32;
    for (int ks = 0; ks < nK; ks++){
        int k0 = ks * 32;
        const float* Ap = A + (size_t)(bm + am) * lda + k0;
        #pragma unroll
        for (int f = 0; f < 4; f++){
            int kq = aq + f;
            fv4 v = (fv4){0.f,0.f,0.f,0.f};
            if (arow_ok && (k0 + kq * 4 + 4) <= K)
                v = *reinterpret_cast<const fv4*>(Ap + kq * 4);
            unsigned short hs[4], ls[4];
            #pragma unroll
            for (int j = 0; j < 4; j++) bf16_split(v[j], hs[j], ls[j]);
            unsigned off = am * SA + kq * 4;
            *reinterpret_cast<uint2*>(&Ah[off]) = make_uint2(pack2(hs[0],hs[1]), pack2(hs[2],hs[3]));
            *reinterpret_cast<uint2*>(&Al[off]) = make_uint2(pack2(ls[0],ls[1]), pack2(ls[2],ls[3]));
        }
        {
            unsigned short hs[8], ls[8];
            #pragma unroll
            for (int j = 0; j < 8; j++){
                int kk = k0 + bk8 + j;
                float v = (bcol_ok && kk < K) ? B[(size_t)kk * N + bn + bn_t] : 0.f;
                bf16_split(v, hs[j], ls[j]);
            }
            unsigned off = bn_t * SA + bk8;
            *reinterpret_cast<uint4*>(&Bh[off]) = make_uint4(pack2(hs[0],hs[1]), pack2(hs[2],hs[3]),
                                                             pack2(hs[4],hs[5]), pack2(hs[6],hs[7]));
            *reinterpret_cast<uint4*>(&Bl[off]) = make_uint4(pack2(ls[0],ls[1]), pack2(ls[2],ls[3]),
                                                             pack2(ls[4],ls[5]), pack2(ls[6],ls[7]));
        }
        __syncthreads();
        short8 afh[4], afl[4], bfh[2], bfl[2];
        #pragma unroll
        for (int mi = 0; mi < 4; mi++){
            unsigned off = (wy * 64 + mi * 16 + l15) * SA + g * 8;
            afh[mi] = *reinterpret_cast<const short8*>(&Ah[off]);
            afl[mi] = *reinterpret_cast<const short8*>(&Al[off]);
        }
        #pragma unroll
        for (int ni = 0; ni < 2; ni++){
            unsigned off = (wx * 32 + ni * 16 + l15) * SA + g * 8;
            bfh[ni] = *reinterpret_cast<const short8*>(&Bh[off]);
            bfl[ni] = *reinterpret_cast<const short8*>(&Bl[off]);
        }
        #pragma unroll
        for (int mi = 0; mi < 4; mi++)
            #pragma unroll
            for (int ni = 0; ni < 2; ni++){
                acc[mi][ni] = __builtin_amdgcn_mfma_f32_16x16x32_bf16(afh[mi], bfh[ni], acc[mi][ni], 0, 0, 0);
                acc[mi][ni] = __builtin_amdgcn_mfma_f32_16x16x32_bf16(afh[mi], bfl[ni], acc[mi][ni], 0, 0, 0);
                acc[mi][ni] = __builtin_amdgcn_mfma_f32_16x16x32_bf16(afl[mi], bfh[ni], acc[mi][ni], 0, 0, 0);
            }
        __syncthreads();
    }
    #pragma unroll
    for (int mi = 0; mi < 4; mi++){
        #pragma unroll
        for (int ni = 0; ni < 2; ni++){
            int cc = bn + wx * 32 + ni * 16 + l15;
            if (cc >= N) continue;
            float bv = bias ? bias[cc] : 0.f;
            #pragma unroll
            for (int j = 0; j < 4; j++){
                int rr = bm + wy * 64 + mi * 16 + g * 4 + j;
                if (rr >= M) continue;
                float v = acc[mi][ni][j] + bv;
                if (ACT == 1) v = gelu_f(v);
                C[(size_t)rr * ldc + cc] = v;
            }
        }
    }
}

// ---------------- dt from p ----------------
__global__ __launch_bounds__(256) void dt_from_p(const float* __restrict__ p,
                                                 const float* __restrict__ w,
                                                 const float* __restrict__ dtb,
                                                 float* __restrict__ dtbT){
    __shared__ float wl[512];
    int tid = threadIdx.x;
    for (int i = tid; i < 512; i += 256){
        int k = i >> 2, h = i & 3;
        wl[i] = w[(size_t)k * 772 + 768 + h];
    }
    __syncthreads();
    int t = blockIdx.x * 64 + (tid >> 2);
    int h = tid & 3;
    if (t >= HW) return;
    const float* pr = p + (size_t)t * 128;
    float s = 0.f;
    for (int k = 0; k < 128; k += 4){
        fv4 v = *reinterpret_cast<const fv4*>(pr + k);
        s += v[0]*wl[k*4+h] + v[1]*wl[(k+1)*4+h] + v[2]*wl[(k+2)*4+h] + v[3]*wl[(k+3)*4+h];
    }
    s += dtb[h];
    dtbT[h * DTP + t] = (s > 20.f) ? s : log1pf(expf(s));
}

// ---------------- conv weight prepack ----------------
template<int IC, int OC, int NCHUNK>
__global__ void prep_w(const float* __restrict__ w, unsigned short* __restrict__ Wh,
                       unsigned short* __restrict__ Wl){
    const int KP = NCHUNK * 288;
    int idx = blockIdx.x * 256 + threadIdx.x;
    if (idx >= OC * KP) return;
    int o = idx / KP, k = idx % KP;
    int ch = k / 288, rest = k % 288, t = rest / 32, c = rest & 31;
    int ci = ch * 32 + c;
    float v = (ci < IC) ? w[((size_t)o * IC + ci) * 9 + t] : 0.f;
    unsigned short hs, ls;
    bf16_split(v, hs, ls);
    Wh[idx] = hs; Wl[idx] = ls;
}

// ---------------- MFMA direct conv 3x3 ----------------
template<int IC, int OC, int PAD, int NCHUNK, int NFRAG>
__global__ __launch_bounds__(256) void conv_mfma(const float* __restrict__ in,
                                                 int inH, int inW,
                                                 const unsigned short* __restrict__ Wh,
                                                 const unsigned short* __restrict__ Wl,
                                                 const float* __restrict__ bias,
                                                 float* __restrict__ out){
    const int KP = NCHUNK * 288;
    const int CST = 40;
    __shared__ __align__(16) unsigned short Xh[3 * 68 * CST], Xl[3 * 68 * CST];
    int y = blockIdx.y;
    int x0 = blockIdx.x * 64;
    int tid = threadIdx.x;
    int lane = tid & 63, wid = tid >> 6;
    int wy = wid >> 1, wx = wid & 1;
    int l15 = lane & 15, g = lane >> 4;

    fv4 acc[2][NFRAG];
    #pragma unroll
    for (int mi = 0; mi < 2; mi++)
        #pragma unroll
        for (int ni = 0; ni < NFRAG; ni++) acc[mi][ni] = (fv4){0.f,0.f,0.f,0.f};

    for (int ch = 0; ch < NCHUNK; ch++){
        int ci0 = ch * 32;
        if (ch > 0) __syncthreads();
        for (int e = tid; e < 3 * 68 * 8; e += 256){
            int qd = e & 7;
            int c  = (e >> 3) % 68;
            int r  = e / 544;
            int iy = y - PAD + r, ix = x0 - PAD + c;
            fv4 v = (fv4){0.f,0.f,0.f,0.f};
            if ((unsigned)iy < (unsigned)inH && (unsigned)ix < (unsigned)inW &&
                (ci0 + qd * 4 + 4) <= IC)
                v = *reinterpret_cast<const fv4*>(in + ((size_t)iy * inW + ix) * IC + ci0 + qd * 4);
            unsigned short hs[4], ls[4];
            #pragma unroll
            for (int j = 0; j < 4; j++) bf16_split(v[j], hs[j], ls[j]);
            unsigned off = (r * 68 + c) * CST + qd * 4;
            *reinterpret_cast<uint2*>(&Xh[off]) = make_uint2(pack2(hs[0],hs[1]), pack2(hs[2],hs[3]));
            *reinterpret_cast<uint2*>(&Xl[off]) = make_uint2(pack2(ls[0],ls[1]), pack2(ls[2],ls[3]));
        }
        __syncthreads();
        #pragma unroll
        for (int t = 0; t < 9; t++){
            int ky = t / 3, kx = t % 3;
            short8 ah[2], al[2], bh[NFRAG], bl[NFRAG];
            #pragma unroll
            for (int mi = 0; mi < 2; mi++){
                unsigned off = (ky * 68 + wy * 32 + mi * 16 + l15 + kx) * CST + g * 8;
                ah[mi] = *reinterpret_cast<const short8*>(&Xh[off]);
                al[mi] = *reinterpret_cast<const short8*>(&Xl[off]);
            }
            #pragma unroll
            for (int ni = 0; ni < NFRAG; ni++){
                int oc = wx * (16 * NFRAG) + ni * 16 + l15;
                size_t woff = (size_t)oc * KP + ch * 288 + t * 32 + g * 8;
                bh[ni] = *reinterpret_cast<const short8*>(&Wh[woff]);
                bl[ni] = *reinterpret_cast<const short8*>(&Wl[woff]);
            }
            #pragma unroll
            for (int mi = 0; mi < 2; mi++)
                #pragma unroll
                for (int ni = 0; ni < NFRAG; ni++){
                    acc[mi][ni] = __builtin_amdgcn_mfma_f32_16x16x32_bf16(ah[mi], bh[ni], acc[mi][ni], 0, 0, 0);
                    acc[mi][ni] = __builtin_amdgcn_mfma_f32_16x16x32_bf16(ah[mi], bl[ni], acc[mi][ni], 0, 0, 0);
                    acc[mi][ni] = __builtin_amdgcn_mfma_f32_16x16x32_bf16(al[mi], bh[ni], acc[mi][ni], 0, 0, 0);
                }
        }
    }
    #pragma unroll
    for (int mi = 0; mi < 2; mi++)
        #pragma unroll
        for (int ni = 0; ni < NFRAG; ni++){
            int oc = wx * (16 * NFRAG) + ni * 16 + l15;
            float bv = bias[oc];
            #pragma unroll
            for (int j = 0; j < 4; j++){
                int x = x0 + wy * 32 + mi * 16 + g * 4 + j;
                if (x >= CONVH) continue;
                out[((size_t)y * CONVH + x) * OC + oc] = gelu_f(acc[mi][ni][j] + bv);
            }
        }
}

// ---------------- adaptive pool ----------------
__global__ void pool_kernel(const float* __restrict__ c2, float* __restrict__ comb){
    int idx = blockIdx.x * 256 + threadIdx.x;
    if (idx >= HW * 64) return;
    int o = idx & 63;
    int pix = idx >> 6;
    int xo = pix % Wdim, yo = pix / Wdim;
    int ys = yo * CONVH / Hdim, ye = ((yo + 1) * CONVH + Hdim - 1) / Hdim;
    int xs = xo * CONVH / Wdim, xe = ((xo + 1) * CONVH + Wdim - 1) / Wdim;
    float s = 0.f;
    for (int yy = ys; yy < ye; yy++)
        for (int xx = xs; xx < xe; xx++)
            s += c2[((size_t)yy * CONVH + xx) * 64 + o];
    comb[(size_t)pix * 192 + 128 + o] = s / (float)((ye - ys) * (xe - xs));
}

// ---------------- conv1d + silu -> packed u32 ----------------
__global__ __launch_bounds__(256) void conv1d_tiled(const float* __restrict__ zx,
                                                    const float* __restrict__ w,
                                                    const float* __restrict__ b,
                                                    unsigned* __restrict__ xbcp){
    __shared__ float xs[67 * 128];
    __shared__ float wc[4 * 128];
    __shared__ float bc[128];
    int t0 = blockIdx.y * 64;
    int c0 = blockIdx.x * 128;
    int tid = threadIdx.x;
    for (int e = tid; e < 67 * 128; e += 256){
        int rr = e >> 7, cc = e & 127;
        int t = t0 - 3 + rr;
        xs[e] = (t >= 0 && t < HW) ? zx[(size_t)t * 772 + 256 + c0 + cc] : 0.f;
    }
    if (tid < 128){
        bc[tid] = b[c0 + tid];
        #pragma unroll
        for (int k = 0; k < 4; k++) wc[k * 128 + tid] = w[(c0 + tid) * 4 + k];
    }
    __syncthreads();
    for (int e = tid; e < 64 * 128; e += 256){
        int tt = e >> 7, cc = e & 127;
        if (t0 + tt >= HW) continue;
        float acc = bc[cc];
        #pragma unroll
        for (int k = 0; k < 4; k++) acc += xs[(tt + k) * 128 + cc] * wc[k * 128 + cc];
        xbcp[(size_t)(t0 + tt) * 512 + c0 + cc] = packsplit(silu_f(acc));
    }
}

// ---------------- chunk cumsum (wave 0) ----------------
__device__ __forceinline__ void chunk_cumsum_t(const float* __restrict__ dtbT, int t0, int Q,
                                               int h, const float* __restrict__ A_log,
                                               float* cum, float* dth){
    int tid = threadIdx.x;
    if (tid < 64){
        float d = (tid < Q) ? dtbT[h * DTP + t0 + tid] : 0.f;
        dth[tid] = d;
        float A = -expf(A_log[h]);
        float a = d * A;
        #pragma unroll
        for (int off = 1; off < 64; off <<= 1){
            float u = __shfl_up(a, off);
            if (tid >= off) a += u;
        }
        cum[tid] = a;
    }
    __syncthreads();
}

__device__ __forceinline__ bool ssd_decode(int bid, int& c, int& h){
    int m = bid & 7, rest = bid >> 3;
    h = rest & 3;
    c = (rest >> 2) * 8 + m;
    return c < NCH;
}

// ---------------- SSD phase A (MFMA, packed xbc in, bf16 S out) ----------------
__global__ __launch_bounds__(256) void ssd_phaseA(const unsigned* __restrict__ xbcp,
                                                  const float* __restrict__ dtbT,
                                                  const float* __restrict__ A_log,
                                                  unsigned short* __restrict__ Sb,
                                                  float* __restrict__ chunkT){
    __shared__ __align__(16) unsigned short BTh[128 * SP], BTl[128 * SP]; // B^T [n][s]
    __shared__ __align__(16) unsigned short XTh[64 * SP],  XTl[64 * SP];  // (Xw)^T [p][s]
    __shared__ float cum[64], dth[64], wln[64];
    int c, h;
    if (!ssd_decode(blockIdx.x, c, h)) return;
    int t0 = c * QC, Q = min(QC, HW - t0);
    int tid = threadIdx.x;
    chunk_cumsum_t(dtbT, t0, Q, h, A_log, cum, dth);
    float T = cum[Q - 1];
    if (tid == 0) chunkT[c * 4 + h] = T;
    if (tid < 64) wln[tid] = (tid < Q) ? __expf(T - cum[tid]) * dth[tid] : 0.f;
    __syncthreads();
    for (int e2 = tid; e2 < 4096; e2 += 256){
        int nn = e2 & 127, sp = e2 >> 7;
        int s0 = 2 * sp;
        unsigned v0 = (s0 < Q)     ? xbcp[(size_t)(t0 + s0) * 512 + 256 + nn] : 0u;
        unsigned v1 = (s0 + 1 < Q) ? xbcp[(size_t)(t0 + s0 + 1) * 512 + 256 + nn] : 0u;
        *reinterpret_cast<unsigned*>(&BTh[nn * SP + s0]) = pack2((unsigned short)(v0 >> 16), (unsigned short)(v1 >> 16));
        *reinterpret_cast<unsigned*>(&BTl[nn * SP + s0]) = pack2((unsigned short)(v0 & 0xFFFFu), (unsigned short)(v1 & 0xFFFFu));
    }
    for (int e2 = tid; e2 < 2048; e2 += 256){
        int pp = e2 & 63, sp = e2 >> 6;
        int s0 = 2 * sp;
        float v0 = (s0 < Q)     ? unpackf(xbcp[(size_t)(t0 + s0) * 512 + h * 64 + pp]) * wln[s0] : 0.f;
        float v1 = (s0 + 1 < Q) ? unpackf(xbcp[(size_t)(t0 + s0 + 1) * 512 + h * 64 + pp]) * wln[s0 + 1] : 0.f;
        unsigned short h0, l0, h1, l1;
        bf16_split(v0, h0, l0); bf16_split(v1, h1, l1);
        *reinterpret_cast<unsigned*>(&XTh[pp * SP + s0]) = pack2(h0, h1);
        *reinterpret_cast<unsigned*>(&XTl[pp * SP + s0]) = pack2(l0, l1);
    }
    __syncthreads();
    int lane = tid & 63, wid = tid >> 6;
    int wy = wid >> 1, wx = wid & 1;
    int l15 = lane & 15, g = lane >> 4;
    fv4 acc[2][4];
    #pragma unroll
    for (int mi = 0; mi < 2; mi++)
        #pragma unroll
        for (int ni = 0; ni < 4; ni++) acc[mi][ni] = (fv4){0.f,0.f,0.f,0.f};
    #pragma unroll
    for (int ks = 0; ks < 2; ks++){
        short8 ah[2], al[2], bh_[4], bl_[4];
        #pragma unroll
        for (int mi = 0; mi < 2; mi++){
            unsigned off = (wy * 32 + mi * 16 + l15) * SP + ks * 32 + g * 8;
            ah[mi] = *reinterpret_cast<const short8*>(&XTh[off]);
            al[mi] = *reinterpret_cast<const short8*>(&XTl[off]);
        }
        #pragma unroll
        for (int ni = 0; ni < 4; ni++){
            unsigned off = (wx * 64 + ni * 16 + l15) * SP + ks * 32 + g * 8;
            bh_[ni] = *reinterpret_cast<const short8*>(&BTh[off]);
            bl_[ni] = *reinterpret_cast<const short8*>(&BTl[off]);
        }
        #pragma unroll
        for (int mi = 0; mi < 2; mi++)
            #pragma unroll
            for (int ni = 0; ni < 4; ni++){
                acc[mi][ni] = __builtin_amdgcn_mfma_f32_16x16x32_bf16(ah[mi], bh_[ni], acc[mi][ni], 0, 0, 0);
                acc[mi][ni] = __builtin_amdgcn_mfma_f32_16x16x32_bf16(ah[mi], bl_[ni], acc[mi][ni], 0, 0, 0);
                acc[mi][ni] = __builtin_amdgcn_mfma_f32_16x16x32_bf16(al[mi], bh_[ni], acc[mi][ni], 0, 0, 0);
            }
    }
    size_t sb = (size_t)(c * 4 + h) * 8192;
    #pragma unroll
    for (int mi = 0; mi < 2; mi++)
        #pragma unroll
        for (int ni = 0; ni < 4; ni++)
            #pragma unroll
            for (int j = 0; j < 4; j++){
                int p = wy * 32 + mi * 16 + g * 4 + j;
                int n = wx * 64 + ni * 16 + l15;
                Sb[sb + p * 128 + n] = bf16rnd(acc[mi][ni][j]);
            }
}

// ---------------- SSD phase B: prefix over chunks (bf16 S) ----------------
__global__ __launch_bounds__(256) void ssd_phaseB(unsigned short* __restrict__ Sb,
                                                  const float* __restrict__ chunkT){
    __shared__ float e[NCH];
    int tid = threadIdx.x;
    int idx = blockIdx.x * 256 + tid;
    int h = idx >> 13, pn = idx & 8191;
    for (int c = tid; c < NCH; c += 256) e[c] = __expf(chunkT[c * 4 + h]);
    __syncthreads();
    #define ADDR_(cc) Sb[((size_t)((cc) * 4 + h)) * 8192 + pn]
    unsigned short r0 = ADDR_(0), r1 = ADDR_(1), r2 = ADDR_(2), r3 = ADDR_(3);
    float s = 0.f;
    int c = 0;
    for (; c + 8 <= NCH; c += 4){
        unsigned short n0 = ADDR_(c + 4), n1 = ADDR_(c + 5), n2 = ADDR_(c + 6), n3 = ADDR_(c + 7);
        ADDR_(c) = bf16rnd(s);     s = fmaf(s, e[c],     bf16f(r0));
        ADDR_(c + 1) = bf16rnd(s); s = fmaf(s, e[c + 1], bf16f(r1));
        ADDR_(c + 2) = bf16rnd(s); s = fmaf(s, e[c + 2], bf16f(r2));
        ADDR_(c + 3) = bf16rnd(s); s = fmaf(s, e[c + 3], bf16f(r3));
        r0 = n0; r1 = n1; r2 = n2; r3 = n3;
    }
    for (; c < NCH; c++){
        unsigned short nx = (c + 4 < NCH) ? ADDR_(c + 4) : (unsigned short)0;
        float loc = bf16f(r0); r0 = r1; r1 = r2; r2 = r3; r3 = nx;
        ADDR_(c) = bf16rnd(s);
        s = fmaf(s, e[c], loc);
    }
    #undef ADDR_
}

// ---------------- SSD phase C (MFMA, bf16 S direct, bf16 P, fused z-gating) --------
__global__ __launch_bounds__(256) void ssd_phaseC(const unsigned* __restrict__ xbcp,
                                                  const float* __restrict__ zx,
                                                  const float* __restrict__ dtbT,
                                                  const float* __restrict__ A_log,
                                                  const float* __restrict__ Dvec,
                                                  const unsigned short* __restrict__ Sb,
                                                  float* __restrict__ y){
    __shared__ __align__(16) unsigned short U0[64 * SP];                 // P bf16 [t][s]
    __shared__ __align__(16) unsigned short U1h[64 * SP], U1l[64 * SP];  // X^T [p][s]
    __shared__ float cum[64], dth[64];
    int c, h;
    if (!ssd_decode(blockIdx.x, c, h)) return;
    int t0 = c * QC, Q = min(QC, HW - t0);
    int tid = threadIdx.x;
    chunk_cumsum_t(dtbT, t0, Q, h, A_log, cum, dth);
    int lane = tid & 63, wid = tid >> 6;
    int wy = wid >> 1, wx = wid & 1;
    int l15 = lane & 15, g = lane >> 4;

    int trow[2], srow[2], prow[2];
    #pragma unroll
    for (int i = 0; i < 2; i++){
        trow[i] = min(t0 + wy * 32 + i * 16 + l15, HW - 1);
        srow[i] = min(t0 + wx * 32 + i * 16 + l15, HW - 1);
        prow[i] = wx * 32 + i * 16 + l15;
    }

    fv4 accG[2][2], accA[2][2];
    #pragma unroll
    for (int mi = 0; mi < 2; mi++)
        #pragma unroll
        for (int ni = 0; ni < 2; ni++){ accG[mi][ni] = (fv4){0.f,0.f,0.f,0.f}; accA[mi][ni] = (fv4){0.f,0.f,0.f,0.f}; }

    const unsigned short* Sbase = Sb + (size_t)(c * 4 + h) * 8192;
    #pragma unroll
    for (int k0 = 0; k0 < 128; k0 += 32){
        short8 ah[2], al[2], bh[2], bl[2], sh[2];
        #pragma unroll
        for (int mi = 0; mi < 2; mi++)
            unpack8(xbcp + (size_t)trow[mi] * 512 + 384 + k0 + g * 8, ah[mi], al[mi]);
        #pragma unroll
        for (int ni = 0; ni < 2; ni++){
            unpack8(xbcp + (size_t)srow[ni] * 512 + 256 + k0 + g * 8, bh[ni], bl[ni]);
            sh[ni] = *reinterpret_cast<const short8*>(Sbase + prow[ni] * 128 + k0 + g * 8);
        }
        #pragma unroll
        for (int mi = 0; mi < 2; mi++)
            #pragma unroll
            for (int ni = 0; ni < 2; ni++){
                accG[mi][ni] = __builtin_amdgcn_mfma_f32_16x16x32_bf16(ah[mi], bh[ni], accG[mi][ni], 0, 0, 0);
                accG[mi][ni] = __builtin_amdgcn_mfma_f32_16x16x32_bf16(ah[mi], bl[ni], accG[mi][ni], 0, 0, 0);
                accG[mi][ni] = __builtin_amdgcn_mfma_f32_16x16x32_bf16(al[mi], bh[ni], accG[mi][ni], 0, 0, 0);
                accA[mi][ni] = __builtin_amdgcn_mfma_f32_16x16x32_bf16(ah[mi], sh[ni], accA[mi][ni], 0, 0, 0);
                accA[mi][ni] = __builtin_amdgcn_mfma_f32_16x16x32_bf16(al[mi], sh[ni], accA[mi][ni], 0, 0, 0);
            }
    }
    // P = mask(G)*exp(cum_t-cum_s)*dt_s -> U0 (bf16)
    #pragma unroll
    for (int mi = 0; mi < 2; mi++)
        #pragma unroll
        for (int ni = 0; ni < 2; ni++)
            #pragma unroll
            for (int j = 0; j < 4; j++){
                int t = wy * 32 + mi * 16 + g * 4 + j;
                int s = wx * 32 + ni * 16 + l15;
                float pv = 0.f;
                if (s <= t && s < Q)
                    pv = accG[mi][ni][j] * __expf(cum[t] - cum[s]) * dth[s];
                U0[t * SP + s] = bf16rnd(pv);
            }
    // stage X^T [p][s] -> U1
    for (int e2 = tid; e2 < 2048; e2 += 256){
        int pp = e2 & 63, sp = e2 >> 6;
        int s0 = 2 * sp;
        unsigned v0 = (s0 < Q)     ? xbcp[(size_t)(t0 + s0) * 512 + h * 64 + pp] : 0u;
        unsigned v1 = (s0 + 1 < Q) ? xbcp[(size_t)(t0 + s0 + 1) * 512 + h * 64 + pp] : 0u;
        *reinterpret_cast<unsigned*>(&U1h[pp * SP + s0]) = pack2((unsigned short)(v0 >> 16), (unsigned short)(v1 >> 16));
        *reinterpret_cast<unsigned*>(&U1l[pp * SP + s0]) = pack2((unsigned short)(v0 & 0xFFFFu), (unsigned short)(v1 & 0xFFFFu));
    }
    __syncthreads();
    // Y = exp(cum_t)*accA + P @ X
    fv4 accY[2][2];
    #pragma unroll
    for (int mi = 0; mi < 2; mi++)
        #pragma unroll
        for (int ni = 0; ni < 2; ni++)
            #pragma unroll
            for (int j = 0; j < 4; j++){
                int t = wy * 32 + mi * 16 + g * 4 + j;
                accY[mi][ni][j] = __expf(cum[t]) * accA[mi][ni][j];
            }
    #pragma unroll
    for (int kk = 0; kk < 2; kk++){
        short8 ph[2], xh[2], xl[2];
        #pragma unroll
        for (int mi = 0; mi < 2; mi++){
            unsigned off = (wy * 32 + mi * 16 + l15) * SP + kk * 32 + g * 8;
            ph[mi] = *reinterpret_cast<const short8*>(&U0[off]);
        }
        #pragma unroll
        for (int ni = 0; ni < 2; ni++){
            unsigned off = (wx * 32 + ni * 16 + l15) * SP + kk * 32 + g * 8;
            xh[ni] = *reinterpret_cast<const short8*>(&U1h[off]);
            xl[ni] = *reinterpret_cast<const short8*>(&U1l[off]);
        }
        #pragma unroll
        for (int mi = 0; mi < 2; mi++)
            #pragma unroll
            for (int ni = 0; ni < 2; ni++){
                accY[mi][ni] = __builtin_amdgcn_mfma_f32_16x16x32_bf16(ph[mi], xh[ni], accY[mi][ni], 0, 0, 0);
                accY[mi][ni] = __builtin_amdgcn_mfma_f32_16x16x32_bf16(ph[mi], xl[ni], accY[mi][ni], 0, 0, 0);
            }
    }
    float Dh = Dvec[h];
    #pragma unroll
    for (int mi = 0; mi < 2; mi++)
        #pragma unroll
        for (int ni = 0; ni < 2; ni++)
            #pragma unroll
            for (int j = 0; j < 4; j++){
                int t = wy * 32 + mi * 16 + g * 4 + j;
                if (t >= Q) continue;
                int p = wx * 32 + ni * 16 + l15;
                float xv = unpackf(xbcp[(size_t)(t0 + t) * 512 + h * 64 + p]);
                float zv = zx[(size_t)(t0 + t) * 772 + h * 64 + p];
                y[(size_t)(t0 + t) * 256 + h * 64 + p] = (accY[mi][ni][j] + Dh * xv) * silu_f(zv);
            }
}

// ---------------- RMSNorm (gating already applied in phaseC) ----------------
__global__ void rms_kernel(float* __restrict__ y, const float* __restrict__ nw){
    int row = blockIdx.x, tid = threadIdx.x;
    float v = y[(size_t)row * 256 + tid];
    float s = v * v;
    __shared__ float r1[4];
    #pragma unroll
    for (int o = 32; o > 0; o >>= 1) s += __shfl_down(s, o);
    if ((tid & 63) == 0) r1[tid >> 6] = s;
    __syncthreads();
    float S = r1[0] + r1[1] + r1[2] + r1[3];
    float rs = rsqrtf(S / 256.f + 1e-5f);
    y[(size_t)row * 256 + tid] = v * rs * nw[tid];
}

extern "C" void kernel_launch(void* const* d_in, const int* in_sizes, int n_in,
                              void* d_out, int out_size, void* d_ws, size_t ws_size,
                              hipStream_t stream){
    (void)in_sizes; (void)n_in; (void)out_size; (void)ws_size;
    const float* x        = (const float*)d_in[0];
    const float* ln_pre_g = (const float*)d_in[1];
    const float* ln_pre_b = (const float*)d_in[2];
    const float* fe_w1    = (const float*)d_in[3];
    const float* fe_b1    = (const float*)d_in[4];
    const float* fe_w2    = (const float*)d_in[5];
    const float* fe_b2    = (const float*)d_in[6];
    const float* cv_w1    = (const float*)d_in[7];
    const float* cv_b1    = (const float*)d_in[8];
    const float* cv_w2    = (const float*)d_in[9];
    const float* cv_b2    = (const float*)d_in[10];
    const float* mp_w     = (const float*)d_in[11];
    const float* mp_b     = (const float*)d_in[12];
    const float* mp_ln_g  = (const float*)d_in[13];
    const float* mp_ln_b  = (const float*)d_in[14];
    const float* m_in_w   = (const float*)d_in[15];
    const float* m_conv_w = (const float*)d_in[16];
    const float* m_conv_b = (const float*)d_in[17];
    const float* m_dtb    = (const float*)d_in[18];
    const float* m_A_log  = (const float*)d_in[19];
    const float* m_D      = (const float*)d_in[20];
    const float* m_norm_w = (const float*)d_in[21];
    const float* m_out_w  = (const float*)d_in[22];
    const float* cls_ln_g = (const float*)d_in[23];
    const float* cls_ln_b = (const float*)d_in[24];
    const float* cls_w1   = (const float*)d_in[25];
    const float* cls_b1   = (const float*)d_in[26];
    const float* cls_w2   = (const float*)d_in[27];
    const float* cls_b2   = (const float*)d_in[28];
    const float* cls_w3   = (const float*)d_in[29];
    const float* cls_b3   = (const float*)d_in[30];

    float* ws   = (float*)d_ws;
    float* xn   = ws + OFF_XN;
    float* f1   = ws + OFF_F1;
    float* comb = ws + OFF_COMB;
    float* p    = ws + OFF_P;
    float* zx   = ws + OFF_ZX;
    unsigned* xbcp = (unsigned*)(ws + OFF_XBC);
    unsigned short* Sb = (unsigned short*)(ws + OFF_S);
    float* dtbT = ws + OFF_DT;
    float* chkT = ws + OFF_CT;
    float* c1h  = ws + OFF_XBC;                    // before xbcp live
    float* c2h  = ws + OFF_XBC + 691488;
    float* ybuf = ws + OFF_F1;
    float* cls0 = ws + OFF_XN;
    float* cls1 = ws + OFF_P;
    float* cls2 = ws + OFF_COMB + 2691200;
    unsigned short* W1h = (unsigned short*)(ws + OFF_W);
    unsigned short* W1l = (unsigned short*)(ws + OFF_W + 32256);
    unsigned short* W2h = (unsigned short*)(ws + OFF_W + 64512);
    unsigned short* W2l = (unsigned short*)(ws + OFF_W + 73728);

    // 0. conv weight prepack (tiny)
    prep_w<200, 32, 7><<<(32 * 2016 + 255) / 256, 256, 0, stream>>>(cv_w1, W1h, W1l);
    prep_w<32, 64, 1><<<(64 * 288 + 255) / 256, 256, 0, stream>>>(cv_w2, W2h, W2l);
    // 1. pre-LN
    ln_kernel<0><<<HW, 256, 0, stream>>>(x, ln_pre_g, ln_pre_b, xn, NBANDS);
    // 2-3. feature MLP (f -> comb[:, :128])
    gemm_mfma_w<1, 4><<<gemm_grid(2, 165), 256, 0, stream>>>(xn, 200, fe_w1, 256, fe_b1,
        (const float*)nullptr, (const float*)nullptr, f1, 256, HW, 256, 200, 2, 165);
    gemm_mfma_w<1, 2><<<gemm_grid(1, 329), 256, 0, stream>>>(f1, 256, fe_w2, 128, fe_b2,
        (const float*)nullptr, (const float*)nullptr, comb, 192, HW, 128, 256, 1, 329);
    // 4. conv1 (MFMA implicit-im2col): 200->32, pad 2
    conv_mfma<200, 32, 2, 7, 1><<<dim3(3, CONVH), 256, 0, stream>>>(xn, Hdim, Wdim, W1h, W1l, cv_b1, c1h);
    // 5. conv2 (MFMA): 32->64, pad 1
    conv_mfma<32, 64, 1, 1, 2><<<dim3(3, CONVH), 256, 0, stream>>>(c1h, CONVH, CONVH, W2h, W2l, cv_b2, c2h);
    // 6. adaptive pool -> comb[:, 128:192]
    pool_kernel<<<(HW * 64 + 255) / 256, 256, 0, stream>>>(c2h, comb);
    // 7. mid projection + fused LN + GELU -> p
    gemm_mfma_w<3, 2><<<gemm_grid(1, 329), 256, 0, stream>>>(comb, 192, mp_w, 128, mp_b,
        mp_ln_g, mp_ln_b, p, 128, HW, 128, 192, 1, 329);
    // 8. mamba in_proj (cols 0..768 only)
    gemm_mfma_w<0, 4><<<gemm_grid(6, 165), 256, 0, stream>>>(p, 128, m_in_w, 772,
        (const float*)nullptr, (const float*)nullptr, (const float*)nullptr,
        zx, 772, HW, 768, 128, 6, 165);
    // 9. dt from p
    dt_from_p<<<(HW + 63) / 64, 256, 0, stream>>>(p, m_in_w, m_dtb, dtbT);
    // 10. depthwise causal conv + silu -> packed u32
    conv1d_tiled<<<dim3(4, NCH), 256, 0, stream>>>(zx, m_conv_w, m_conv_b, xbcp);
    // 11-13. SSD chunked scan
    ssd_phaseA<<<SSD_GRID, 256, 0, stream>>>(xbcp, dtbT, m_A_log, Sb, chkT);
    ssd_phaseB<<<128, 256, 0, stream>>>(Sb, chkT);
    ssd_phaseC<<<SSD_GRID, 256, 0, stream>>>(xbcp, zx, dtbT, m_A_log, m_D, Sb, ybuf);
    // 14. RMSNorm (gating fused into phaseC)
    rms_kernel<<<HW, 256, 0, stream>>>(ybuf, m_norm_w);
    // 15. out proj + fused cls LN -> cls0
    gemm_mfma_w<2, 2><<<gemm_grid(1, 329), 256, 0, stream>>>(ybuf, 256, m_out_w, 128,
        (const float*)nullptr, cls_ln_g, cls_ln_b, cls0, 128, HW, 128, 256, 1, 329);
    // 16-18. classifier
    gemm_mfma_w<1, 2><<<gemm_grid(1, 329), 256, 0, stream>>>(cls0, 128, cls_w1, 128, cls_b1,
        (const float*)nullptr, (const float*)nullptr, cls1, 128, HW, 128, 128, 1, 329);
    gemm_mfma<1><<<gemm_grid(1, 165), 256, 0, stream>>>(cls1, 128, cls_w2, cls_b2, cls2, 64, HW, 64, 128, 1, 165);
    gemm_mfma<0><<<gemm_grid(1, 165), 256, 0, stream>>>(cls2, 64, cls_w3, cls_b3, (float*)d_out, 17, HW, 17, 64, 1, 165);
}